// Round 1
// baseline (828.921 us; speedup 1.0000x reference)
//
#include <hip/hip_runtime.h>
#include <stdint.h>

#define B_ 512
#define D_ 1024
#define M_ 32768

typedef _Float16 half8 __attribute__((ext_vector_type(8)));
typedef _Float16 half4 __attribute__((ext_vector_type(4)));
typedef float f32x4 __attribute__((ext_vector_type(4)));

// ---------- sortable key helpers (monotonic float <-> u32) ----------
__device__ __forceinline__ unsigned f2k(float f) {
    unsigned b = __float_as_uint(f);
    return (b & 0x80000000u) ? ~b : (b | 0x80000000u);
}
__device__ __forceinline__ float k2f(unsigned k) {
    unsigned b = (k & 0x80000000u) ? (k & 0x7FFFFFFFu) : ~k;
    return __uint_as_float(b);
}
// monotonic double -> u64 key
__device__ __forceinline__ unsigned long long d2k(double d) {
    unsigned long long b = (unsigned long long)__double_as_longlong(d);
    return (b & 0x8000000000000000ull) ? ~b : (b | 0x8000000000000000ull);
}

// ---------- async global->LDS (16B per lane, wave-uniform base + lane*16) ----------
__device__ __forceinline__ void gld16(const void* g, void* l) {
    __builtin_amdgcn_global_load_lds(
        (__attribute__((address_space(1))) void*)(uintptr_t)g,
        (__attribute__((address_space(3))) void*)(unsigned)(uintptr_t)l,
        16, 0, 0);
}

// ---------- split x: xc = (x - ib) * 2048 -> fp16 hi + fp16 residual*2048 ----------
__global__ __launch_bounds__(256) void split_x_k(
    const float* __restrict__ x, const float* __restrict__ ib,
    _Float16* __restrict__ xh, _Float16* __restrict__ xr)
{
    int i = blockIdx.x * 256 + threadIdx.x;   // float4 index, 131072 total
    float4 v = ((const float4*)x)[i];
    float4 bb = ((const float4*)ib)[i & 255];
    float a0 = (v.x - bb.x) * 2048.0f;
    float a1 = (v.y - bb.y) * 2048.0f;
    float a2 = (v.z - bb.z) * 2048.0f;
    float a3 = (v.w - bb.w) * 2048.0f;
    _Float16 h0 = (_Float16)a0, h1 = (_Float16)a1, h2 = (_Float16)a2, h3 = (_Float16)a3;
    _Float16 r0 = (_Float16)((a0 - (float)h0) * 2048.0f);
    _Float16 r1 = (_Float16)((a1 - (float)h1) * 2048.0f);
    _Float16 r2 = (_Float16)((a2 - (float)h2) * 2048.0f);
    _Float16 r3 = (_Float16)((a3 - (float)h3) * 2048.0f);
    half4 hv = {h0, h1, h2, h3};
    half4 rv = {r0, r1, r2, r3};
    ((half4*)xh)[i] = hv;
    ((half4*)xr)[i] = rv;
}

// ---------- split W_enc: w*2048 -> fp16 hi + fp16 residual*2048 ----------
__global__ __launch_bounds__(256) void split_w_k(
    const float* __restrict__ w, _Float16* __restrict__ wh, _Float16* __restrict__ wr)
{
    int i = blockIdx.x * 256 + threadIdx.x;   // float4 index, 8388608 total
    float4 v = ((const float4*)w)[i];
    float a0 = v.x * 2048.0f, a1 = v.y * 2048.0f, a2 = v.z * 2048.0f, a3 = v.w * 2048.0f;
    _Float16 h0 = (_Float16)a0, h1 = (_Float16)a1, h2 = (_Float16)a2, h3 = (_Float16)a3;
    _Float16 r0 = (_Float16)((a0 - (float)h0) * 2048.0f);
    _Float16 r1 = (_Float16)((a1 - (float)h1) * 2048.0f);
    _Float16 r2 = (_Float16)((a2 - (float)h2) * 2048.0f);
    _Float16 r3 = (_Float16)((a3 - (float)h3) * 2048.0f);
    half4 hv = {h0, h1, h2, h3};
    half4 rv = {r0, r1, r2, r3};
    ((half4*)wh)[i] = hv;
    ((half4*)wr)[i] = rv;
}

// ---------- encoder GEMM via MFMA fp16, double-word split ----------
__global__ __launch_bounds__(256) void enc_mfma(
    const _Float16* __restrict__ xhf, const _Float16* __restrict__ xrf,
    const _Float16* __restrict__ whf, const _Float16* __restrict__ wrf,
    const float* __restrict__ nb, float* __restrict__ preact)
{
    __shared__ alignas(16) _Float16 lAh[128 * 32];
    __shared__ alignas(16) _Float16 lAr[128 * 32];
    __shared__ alignas(16) _Float16 lBh[128 * 32];
    __shared__ alignas(16) _Float16 lBr[128 * 32];

    const int tid = threadIdx.x;
    const int lane = tid & 63;
    const int wv = tid >> 6;
    const int wvr = wv >> 1;
    const int wvc = wv & 1;
    const int i0 = blockIdx.y * 128;
    const int j0 = blockIdx.x * 128;
    const int ln15 = lane & 15;
    const int kq = (lane >> 4) * 8;

    f32x4 acc1[4][4], acc2[4][4];
#pragma unroll
    for (int r = 0; r < 4; ++r)
#pragma unroll
        for (int c = 0; c < 4; ++c) {
            acc1[r][c] = (f32x4){0.f, 0.f, 0.f, 0.f};
            acc2[r][c] = (f32x4){0.f, 0.f, 0.f, 0.f};
        }

    const int o0 = wv * 1024 + lane * 16;
    const int o1 = o0 + 4096;
    const int r0 = o0 >> 6, c0 = o0 & 63;
    const int r1 = o1 >> 6, c1 = o1 & 63;

    for (int k0 = 0; k0 < 1024; k0 += 32) {
        gld16((const char*)(xhf + (size_t)(i0 + r0) * 1024 + k0) + c0, (char*)lAh + o0);
        gld16((const char*)(xhf + (size_t)(i0 + r1) * 1024 + k0) + c1, (char*)lAh + o1);
        gld16((const char*)(xrf + (size_t)(i0 + r0) * 1024 + k0) + c0, (char*)lAr + o0);
        gld16((const char*)(xrf + (size_t)(i0 + r1) * 1024 + k0) + c1, (char*)lAr + o1);
        gld16((const char*)(whf + (size_t)(j0 + r0) * 1024 + k0) + c0, (char*)lBh + o0);
        gld16((const char*)(whf + (size_t)(j0 + r1) * 1024 + k0) + c1, (char*)lBh + o1);
        gld16((const char*)(wrf + (size_t)(j0 + r0) * 1024 + k0) + c0, (char*)lBr + o0);
        gld16((const char*)(wrf + (size_t)(j0 + r1) * 1024 + k0) + c1, (char*)lBr + o1);
        __syncthreads();

        half8 aH[4], aR[4], bH[4], bR[4];
#pragma unroll
        for (int r = 0; r < 4; ++r) {
            aH[r] = *(const half8*)&lAh[(wvr * 64 + r * 16 + ln15) * 32 + kq];
            aR[r] = *(const half8*)&lAr[(wvr * 64 + r * 16 + ln15) * 32 + kq];
            bH[r] = *(const half8*)&lBh[(wvc * 64 + r * 16 + ln15) * 32 + kq];
            bR[r] = *(const half8*)&lBr[(wvc * 64 + r * 16 + ln15) * 32 + kq];
        }
#pragma unroll
        for (int r = 0; r < 4; ++r)
#pragma unroll
            for (int c = 0; c < 4; ++c) {
                acc1[r][c] = __builtin_amdgcn_mfma_f32_16x16x32_f16(aH[r], bH[c], acc1[r][c], 0, 0, 0);
                acc2[r][c] = __builtin_amdgcn_mfma_f32_16x16x32_f16(aH[r], bR[c], acc2[r][c], 0, 0, 0);
                acc2[r][c] = __builtin_amdgcn_mfma_f32_16x16x32_f16(aR[r], bH[c], acc2[r][c], 0, 0, 0);
            }
        __syncthreads();
    }

    const float s1 = 0x1p-22f, s2 = 0x1p-33f;
#pragma unroll
    for (int c = 0; c < 4; ++c) {
        int n = j0 + wvc * 64 + c * 16 + ln15;
        float nbv = nb[n];
#pragma unroll
        for (int r = 0; r < 4; ++r) {
            int mb = i0 + wvr * 64 + r * 16 + (lane >> 4) * 4;
#pragma unroll
            for (int e = 0; e < 4; ++e)
                preact[(size_t)(mb + e) * M_ + n] = acc1[r][c][e] * s1 + acc2[r][c][e] * s2 + nbv;
        }
    }
}

// ---------- transpose W_dec [1024][32768] -> wdt [32768][1024] ----------
__global__ __launch_bounds__(256) void tr_k(const float* __restrict__ wdec,
                                            float* __restrict__ wdt)
{
    __shared__ float tile[32][33];
    int tx = threadIdx.x, ty = threadIdx.y;
    int x0 = blockIdx.x * 32;
    int y0 = blockIdx.y * 32;
#pragma unroll
    for (int j = 0; j < 32; j += 8)
        tile[ty + j][tx] = wdec[(size_t)(y0 + ty + j) * M_ + x0 + tx];
    __syncthreads();
#pragma unroll
    for (int j = 0; j < 32; j += 8)
        wdt[(size_t)(x0 + ty + j) * D_ + y0 + tx] = tile[tx][ty + j];
}

// ---------- fused dual top-k select (MFMA-order): top-128 unmasked + masked cands ----------
__global__ __launch_bounds__(256) void select_both(
    const float* __restrict__ preact, const int* __restrict__ steps,
    int* __restrict__ sel_idx, float* __restrict__ sel_val,
    int* __restrict__ auxcand)
{
    __shared__ unsigned histU[4096];
    __shared__ unsigned histM[4096];
    __shared__ unsigned coarse[256];
    __shared__ unsigned long long candU[512];
    __shared__ unsigned long long candM[512];
    __shared__ unsigned cntU, cntM, thrU, thrM;

    const int t = threadIdx.x;
    const int b = blockIdx.x;
    const float* row = preact + (size_t)b * M_;

    for (int i = t; i < 4096; i += 256) { histU[i] = 0; histM[i] = 0; }
    candU[t] = 0ULL; candU[t + 256] = 0ULL;
    candM[t] = 0ULL; candM[t + 256] = 0ULL;
    if (t == 0) { cntU = 0; cntM = 0; }
    __syncthreads();

    for (int m = t; m < M_; m += 256) {
        unsigned key = f2k(row[m]);
        atomicAdd(&histU[key >> 20], 1u);
        bool dead = (steps[m] + 1) > 256;
        atomicAdd(&histM[dead ? (key >> 20) : 2048u], 1u);
    }
    __syncthreads();

    { unsigned s = 0;
#pragma unroll
      for (int j = 0; j < 16; ++j) s += histU[t * 16 + j];
      coarse[t] = s; }
    __syncthreads();
    if (t == 0) {
        unsigned cum = 0; int cb = 0;
        for (int c = 255; c >= 0; --c) { if (cum + coarse[c] >= 128u) { cb = c; break; } cum += coarse[c]; }
        int tb = cb * 16;
        for (int f = cb * 16 + 15; f >= cb * 16; --f) { if (cum + histU[f] >= 128u) { tb = f; break; } cum += histU[f]; }
        thrU = (unsigned)tb;
    }
    __syncthreads();
    { unsigned s = 0;
#pragma unroll
      for (int j = 0; j < 16; ++j) s += histM[t * 16 + j];
      coarse[t] = s; }
    __syncthreads();
    if (t == 0) {
        unsigned cum = 0; int cb = 0;
        for (int c = 255; c >= 0; --c) { if (cum + coarse[c] >= 64u) { cb = c; break; } cum += coarse[c]; }
        int tb = cb * 16;
        for (int f = cb * 16 + 15; f >= cb * 16; --f) { if (cum + histM[f] >= 64u) { tb = f; break; } cum += histM[f]; }
        thrM = (unsigned)(tb > 0 ? tb - 1 : 0);   // one extra bin: margin for top-96 resolve superset
    }
    __syncthreads();

    const unsigned TU = thrU, TM = thrM;

    for (int m = t; m < M_; m += 256) {
        unsigned key = f2k(row[m]);
        if ((key >> 20) >= TU) {
            unsigned p = atomicAdd(&cntU, 1u);
            if (p < 512u) candU[p] = ((unsigned long long)key << 32) | (unsigned)(~m);
        }
        bool dead = (steps[m] + 1) > 256;
        if (dead && (key >> 20) >= TM) {
            unsigned p = atomicAdd(&cntM, 1u);
            if (p < 512u) candM[p] = ((unsigned long long)key << 32) | (unsigned)(~m);
        }
    }
    __syncthreads();

    for (unsigned kk = 2; kk <= 512; kk <<= 1) {
        for (unsigned j = kk >> 1; j > 0; j >>= 1) {
#pragma unroll
            for (int h = 0; h < 2; ++h) {
                unsigned i = (unsigned)t + (unsigned)h * 256u;
                unsigned ixj = i ^ j;
                if (ixj > i) {
                    bool desc = ((i & kk) == 0);
                    unsigned long long a = candU[i], c = candU[ixj];
                    if (desc ? (a < c) : (a > c)) { candU[i] = c; candU[ixj] = a; }
                    a = candM[i]; c = candM[ixj];
                    if (desc ? (a < c) : (a > c)) { candM[i] = c; candM[ixj] = a; }
                }
            }
            __syncthreads();
        }
    }

    if (t < 128) {
        unsigned long long c = candU[t];
        unsigned m = ~(unsigned)c;
        float v = k2f((unsigned)(c >> 32));
        sel_idx[b * 128 + t] = (int)m;
        sel_val[b * 128 + t] = v > 0.f ? v : 0.f;
    }
    if (t < 96) {
        unsigned long long c = candM[t];
        auxcand[b * 96 + t] = c ? (int)(~(unsigned)c) : -1;
    }
}

// ---------- exact resolve in FLOAT64: recompute candidate dots at f64 precision ----------
// The 32/33 (and 64/65 aux) boundary gap, min over 512 rows, is ~1e-5; any fp32
// summation order has ~2e-6 error vs the np float64 golden -> near-tie index flips.
// f64 accumulation (error ~1e-13) makes our ordering the true ordering, which the
// f64 reference also follows. Sort key = monotonic(f64) high 48 bits | (~m & 0xFFFF)
// (lowest-index-first on true ties, matching lax.top_k / np argsort).
__global__ __launch_bounds__(256) void resolve_k(
    const float* __restrict__ x, const float* __restrict__ ib,
    const float* __restrict__ wenc, const float* __restrict__ nb,
    const int* __restrict__ sel_idx, const int* __restrict__ auxcand,
    int* __restrict__ rec32_idx, float* __restrict__ rec32_val,
    float* __restrict__ out_tidx, float* __restrict__ out_tval,
    float* __restrict__ out_aidx, float* __restrict__ out_aval)
{
    __shared__ double xcs[1024];
    __shared__ unsigned long long kU[64];
    __shared__ unsigned long long kM[128];
    __shared__ float vU[64];
    __shared__ float vM[128];

    const int b = blockIdx.x, t = threadIdx.x;
    for (int d = t; d < 1024; d += 256)
        xcs[d] = (double)x[(size_t)b * 1024 + d] - (double)ib[d];
    if (t < 64)  { kU[t] = 0ULL; vU[t] = 0.f; }
    if (t < 128) { kM[t] = 0ULL; vM[t] = 0.f; }
    __syncthreads();

    int m = -1;
    if (t < 64) m = sel_idx[b * 128 + t];                 // full 64-wide margin over top-32
    else if (t >= 64 && t < 160) m = auxcand[b * 96 + (t - 64)];
    if (m >= 0) {
        const float* w = wenc + (size_t)m * 1024;
        double a0 = 0.0, a1 = 0.0, a2 = 0.0, a3 = 0.0;
        for (int d = 0; d < 1024; d += 4) {
            float4 wv = *(const float4*)(w + d);
            a0 = fma((double)wv.x, xcs[d + 0], a0);
            a1 = fma((double)wv.y, xcs[d + 1], a1);
            a2 = fma((double)wv.z, xcs[d + 2], a2);
            a3 = fma((double)wv.w, xcs[d + 3], a3);
        }
        double v = ((a0 + a1) + (a2 + a3)) + (double)nb[m];
        unsigned long long key = (d2k(v) & 0xFFFFFFFFFFFF0000ull)
                               | (unsigned long long)((~(unsigned)m) & 0xFFFFu);
        float vf = (float)v;
        if (t < 64) { kU[t] = key; vU[t] = vf; }
        else        { kM[t - 64] = key; vM[t - 64] = vf; }
    }
    __syncthreads();

    for (unsigned kk = 2; kk <= 128; kk <<= 1) {
        for (unsigned j = kk >> 1; j > 0; j >>= 1) {
            unsigned i = (unsigned)t, ixj = i ^ j;
            if (kk <= 64 && i < 64 && ixj > i) {
                bool desc = ((i & kk) == 0);
                unsigned long long a = kU[i], c = kU[ixj];
                if (desc ? (a < c) : (a > c)) {
                    kU[i] = c; kU[ixj] = a;
                    float fa = vU[i]; vU[i] = vU[ixj]; vU[ixj] = fa;
                }
            }
            if (i < 128 && ixj > i) {
                bool desc = ((i & kk) == 0);
                unsigned long long a = kM[i], c = kM[ixj];
                if (desc ? (a < c) : (a > c)) {
                    kM[i] = c; kM[ixj] = a;
                    float fa = vM[i]; vM[i] = vM[ixj]; vM[ixj] = fa;
                }
            }
            __syncthreads();
        }
    }

    if (t < 32) {
        unsigned mm = (~(unsigned)kU[t]) & 0xFFFFu;
        float v = vU[t];
        float rv = v > 0.f ? v : 0.f;
        rec32_idx[b * 32 + t] = (int)mm;
        rec32_val[b * 32 + t] = rv;
        out_tidx[b * 32 + t] = (float)mm;
        out_tval[b * 32 + t] = rv;
    }
    if (t < 64) {
        unsigned mm = (~(unsigned)kM[t]) & 0xFFFFu;
        float v = vM[t];
        out_aidx[b * 64 + t] = (float)mm;
        out_aval[b * 64 + t] = v > 0.f ? v : 0.f;
    }
}

// ---------- sparse decoder: multik from MFMA top-128, recon/mat from exact top-32 ----------
__global__ __launch_bounds__(256) void dec_k(
    const float* __restrict__ wdt, const int* __restrict__ sel_idx,
    const float* __restrict__ sel_val, const int* __restrict__ rec32_idx,
    const float* __restrict__ rec32_val, const float* __restrict__ ib,
    float* __restrict__ o_recon, float* __restrict__ o_multik,
    float* __restrict__ o_mat0, float* __restrict__ o_mat1)
{
    __shared__ int sidx[128];
    __shared__ float sval[128];
    __shared__ int ridx[32];
    __shared__ float rval[32];
    const int b = blockIdx.x, t = threadIdx.x;
    if (t < 128) { sidx[t] = sel_idx[b * 128 + t]; sval[t] = sel_val[b * 128 + t]; }
    if (t < 32)  { ridx[t] = rec32_idx[b * 32 + t]; rval[t] = rec32_val[b * 32 + t]; }
    __syncthreads();

    const int d = t * 4;
    float4 bias = *(const float4*)(ib + d);
    float4 mul = bias, rec = bias, m0 = bias, m1 = bias;

    for (int k = 0; k < 128; ++k) {
        float v = sval[k];
        float4 w = *(const float4*)(wdt + (size_t)sidx[k] * D_ + d);
        mul.x += v * w.x; mul.y += v * w.y; mul.z += v * w.z; mul.w += v * w.w;
    }
    for (int k = 0; k < 32; ++k) {
        int idx = ridx[k];
        float v = rval[k];
        float4 w = *(const float4*)(wdt + (size_t)idx * D_ + d);
        rec.x += v * w.x; rec.y += v * w.y; rec.z += v * w.z; rec.w += v * w.w;
        if (idx < 16384) {
            m1.x += v * w.x; m1.y += v * w.y; m1.z += v * w.z; m1.w += v * w.w;
            if (idx < 4096) {
                m0.x += v * w.x; m0.y += v * w.y; m0.z += v * w.z; m0.w += v * w.w;
            }
        }
    }
    size_t o = (size_t)b * D_ + d;
    *(float4*)(o_recon + o)  = rec;
    *(float4*)(o_multik + o) = mul;
    *(float4*)(o_mat0 + o)   = m0;
    *(float4*)(o_mat1 + o)   = m1;
}

extern "C" void kernel_launch(void* const* d_in, const int* in_sizes, int n_in,
                              void* d_out, int out_size, void* d_ws, size_t ws_size,
                              hipStream_t stream)
{
    const float* x     = (const float*)d_in[0];
    const float* wenc  = (const float*)d_in[1];
    const float* wdec  = (const float*)d_in[2];
    const float* ib    = (const float*)d_in[3];
    const float* nb    = (const float*)d_in[4];
    const int*   steps = (const int*)d_in[5];
    float* out = (float*)d_out;

    char* ws = (char*)d_ws;
    float*     preact  = (float*)ws;                              // [0, 64MB)
    _Float16*  whf     = (_Float16*)(ws + 67108864);              // [64MB, 128MB)
    _Float16*  wrf     = (_Float16*)(ws + 134217728);             // [128MB, 192MB)
    float*     wdt     = (float*)(ws + 67108864);                 // aliases whf/wrf (dead after GEMM)
    _Float16*  xhf     = (_Float16*)(ws + 201326592);             // [192MB, +1MB)
    _Float16*  xrf     = (_Float16*)(ws + 202375168);             // [193MB, +1MB)
    int*       auxcand = (int*)(ws + 201326592);                  // aliases xhf (dead after GEMM), 192KB
    int*       rec32_i = (int*)(ws + 201326592 + 262144);         // 64KB
    float*     rec32_v = (float*)(ws + 201326592 + 327680);       // 64KB
    int*       sel_idx = (int*)(ws + 203423744);                  // [194MB, +256KB)
    float*     sel_val = (float*)(ws + 203685888);                // +256KB

    float* out_recon  = out;
    float* out_multik = out + 524288;
    float* out_mat0   = out + 1048576;
    float* out_mat1   = out + 1572864;
    float* out_tidx   = out + 2097152;
    float* out_tval   = out + 2097152 + 16384;
    float* out_aidx   = out + 2097152 + 32768;
    float* out_aval   = out + 2097152 + 32768 + 32768;

    split_x_k<<<dim3(512), dim3(256), 0, stream>>>(x, ib, xhf, xrf);
    split_w_k<<<dim3(32768), dim3(256), 0, stream>>>(wenc, whf, wrf);
    enc_mfma<<<dim3(256, 4), dim3(256), 0, stream>>>(xhf, xrf, whf, wrf, nb, preact);
    tr_k<<<dim3(1024, 32), dim3(32, 8), 0, stream>>>(wdec, wdt);   // after enc (wdt aliases W splits)
    select_both<<<dim3(512), dim3(256), 0, stream>>>(preact, steps, sel_idx, sel_val, auxcand);
    resolve_k<<<dim3(512), dim3(256), 0, stream>>>(
        x, ib, wenc, nb, sel_idx, auxcand, rec32_i, rec32_v,
        out_tidx, out_tval, out_aidx, out_aval);
    dec_k<<<dim3(512), dim3(256), 0, stream>>>(
        wdt, sel_idx, sel_val, rec32_i, rec32_v, ib,
        out_recon, out_multik, out_mat0, out_mat1);
}

// Round 2
// 782.028 us; speedup vs baseline: 1.0600x; 1.0600x over previous
//
#include <hip/hip_runtime.h>
#include <stdint.h>

#define B_ 512
#define D_ 1024
#define M_ 32768

typedef _Float16 half8 __attribute__((ext_vector_type(8)));
typedef _Float16 half4 __attribute__((ext_vector_type(4)));
typedef float f32x4 __attribute__((ext_vector_type(4)));

// ---------- sortable key helpers (monotonic float <-> u32) ----------
__device__ __forceinline__ unsigned f2k(float f) {
    unsigned b = __float_as_uint(f);
    return (b & 0x80000000u) ? ~b : (b | 0x80000000u);
}
__device__ __forceinline__ float k2f(unsigned k) {
    unsigned b = (k & 0x80000000u) ? (k & 0x7FFFFFFFu) : ~k;
    return __uint_as_float(b);
}
// monotonic double -> u64 key
__device__ __forceinline__ unsigned long long d2k(double d) {
    unsigned long long b = (unsigned long long)__double_as_longlong(d);
    return (b & 0x8000000000000000ull) ? ~b : (b | 0x8000000000000000ull);
}

// ---------- async global->LDS (16B per lane, wave-uniform base + lane*16) ----------
__device__ __forceinline__ void gld16(const void* g, void* l) {
    __builtin_amdgcn_global_load_lds(
        (__attribute__((address_space(1))) void*)(uintptr_t)g,
        (__attribute__((address_space(3))) void*)(unsigned)(uintptr_t)l,
        16, 0, 0);
}

// ---------- split x: xc = (x - ib) * 2048 -> fp16 hi + fp16 residual*2048 ----------
__global__ __launch_bounds__(256) void split_x_k(
    const float* __restrict__ x, const float* __restrict__ ib,
    _Float16* __restrict__ xh, _Float16* __restrict__ xr)
{
    int i = blockIdx.x * 256 + threadIdx.x;   // float4 index, 131072 total
    float4 v = ((const float4*)x)[i];
    float4 bb = ((const float4*)ib)[i & 255];
    float a0 = (v.x - bb.x) * 2048.0f;
    float a1 = (v.y - bb.y) * 2048.0f;
    float a2 = (v.z - bb.z) * 2048.0f;
    float a3 = (v.w - bb.w) * 2048.0f;
    _Float16 h0 = (_Float16)a0, h1 = (_Float16)a1, h2 = (_Float16)a2, h3 = (_Float16)a3;
    _Float16 r0 = (_Float16)((a0 - (float)h0) * 2048.0f);
    _Float16 r1 = (_Float16)((a1 - (float)h1) * 2048.0f);
    _Float16 r2 = (_Float16)((a2 - (float)h2) * 2048.0f);
    _Float16 r3 = (_Float16)((a3 - (float)h3) * 2048.0f);
    half4 hv = {h0, h1, h2, h3};
    half4 rv = {r0, r1, r2, r3};
    ((half4*)xh)[i] = hv;
    ((half4*)xr)[i] = rv;
}

// ---------- split W_enc: w*2048 -> fp16 hi + fp16 residual*2048 ----------
__global__ __launch_bounds__(256) void split_w_k(
    const float* __restrict__ w, _Float16* __restrict__ wh, _Float16* __restrict__ wr)
{
    int i = blockIdx.x * 256 + threadIdx.x;   // float4 index, 8388608 total
    float4 v = ((const float4*)w)[i];
    float a0 = v.x * 2048.0f, a1 = v.y * 2048.0f, a2 = v.z * 2048.0f, a3 = v.w * 2048.0f;
    _Float16 h0 = (_Float16)a0, h1 = (_Float16)a1, h2 = (_Float16)a2, h3 = (_Float16)a3;
    _Float16 r0 = (_Float16)((a0 - (float)h0) * 2048.0f);
    _Float16 r1 = (_Float16)((a1 - (float)h1) * 2048.0f);
    _Float16 r2 = (_Float16)((a2 - (float)h2) * 2048.0f);
    _Float16 r3 = (_Float16)((a3 - (float)h3) * 2048.0f);
    half4 hv = {h0, h1, h2, h3};
    half4 rv = {r0, r1, r2, r3};
    ((half4*)wh)[i] = hv;
    ((half4*)wr)[i] = rv;
}

// ---------- encoder GEMM via MFMA fp16, double-word split ----------
// Round-2 restructure: double-buffered LDS + stage-ahead (counted-drain 2-phase),
// single barrier per K-step, XOR chunk swizzle (pre-swizzled global source,
// linear LDS dest) to kill the 8-way ds_read_b128 bank conflict.
// MFMA order / accumulator split / scales are UNCHANGED -> bit-identical output.
__global__ __launch_bounds__(256) void enc_mfma(
    const _Float16* __restrict__ xhf, const _Float16* __restrict__ xrf,
    const _Float16* __restrict__ whf, const _Float16* __restrict__ wrf,
    const float* __restrict__ nb, float* __restrict__ preact)
{
    // [buf][h/r][128 rows * 32 halfs]; 2*2*8KB * 2 (A,B) = 64 KiB
    __shared__ alignas(16) _Float16 lA[2][2][128 * 32];
    __shared__ alignas(16) _Float16 lB[2][2][128 * 32];

    const int tid = threadIdx.x;
    const int lane = tid & 63;
    const int wv = tid >> 6;
    const int wvr = wv >> 1;
    const int wvc = wv & 1;
    const int i0 = blockIdx.y * 128;
    const int j0 = blockIdx.x * 128;
    const int ln15 = lane & 15;
    const int kq = (lane >> 4) * 8;   // half index of 16B chunk within 64B row

    f32x4 acc1[4][4], acc2[4][4];
#pragma unroll
    for (int r = 0; r < 4; ++r)
#pragma unroll
        for (int c = 0; c < 4; ++c) {
            acc1[r][c] = (f32x4){0.f, 0.f, 0.f, 0.f};
            acc2[r][c] = (f32x4){0.f, 0.f, 0.f, 0.f};
        }

    // linear LDS dests (wave-uniform base + lane*16, required by global_load_lds)
    const int o0 = wv * 1024 + lane * 16;
    const int o1 = o0 + 4096;
    const int r0 = o0 >> 6, r1 = o1 >> 6;
    // pre-swizzled source byte-within-row: chunk ^= (row>>1)&3
    const int c0s = (o0 & 63) ^ (((r0 >> 1) & 3) << 4);
    const int c1s = (o1 & 63) ^ (((r1 >> 1) & 3) << 4);

    // per-frag swizzled read offsets (half index within row)
    const int rowA = wvr * 64 + ln15;          // + r*16 per frag
    const int rowB = wvc * 64 + ln15;

#define STAGE(k0, s)                                                                     \
    do {                                                                                 \
        gld16((const char*)(xhf + (size_t)(i0 + r0) * 1024 + (k0)) + c0s, (char*)lA[s][0] + o0); \
        gld16((const char*)(xhf + (size_t)(i0 + r1) * 1024 + (k0)) + c1s, (char*)lA[s][0] + o1); \
        gld16((const char*)(xrf + (size_t)(i0 + r0) * 1024 + (k0)) + c0s, (char*)lA[s][1] + o0); \
        gld16((const char*)(xrf + (size_t)(i0 + r1) * 1024 + (k0)) + c1s, (char*)lA[s][1] + o1); \
        gld16((const char*)(whf + (size_t)(j0 + r0) * 1024 + (k0)) + c0s, (char*)lB[s][0] + o0); \
        gld16((const char*)(whf + (size_t)(j0 + r1) * 1024 + (k0)) + c1s, (char*)lB[s][0] + o1); \
        gld16((const char*)(wrf + (size_t)(j0 + r0) * 1024 + (k0)) + c0s, (char*)lB[s][1] + o0); \
        gld16((const char*)(wrf + (size_t)(j0 + r1) * 1024 + (k0)) + c1s, (char*)lB[s][1] + o1); \
    } while (0)

    STAGE(0, 0);
    __syncthreads();

    int cur = 0;
    for (int k0 = 0; k0 < 1024; k0 += 32) {
        const int nxt = cur ^ 1;
        if (k0 + 32 < 1024) STAGE(k0 + 32, nxt);   // issue next tile BEFORE compute

        half8 aH[4], aR[4], bH[4], bR[4];
#pragma unroll
        for (int r = 0; r < 4; ++r) {
            const int ra = rowA + r * 16;
            const int rb = rowB + r * 16;
            const int ka = kq ^ (((ra >> 1) & 3) << 3);
            const int kb = kq ^ (((rb >> 1) & 3) << 3);
            aH[r] = *(const half8*)&lA[cur][0][ra * 32 + ka];
            aR[r] = *(const half8*)&lA[cur][1][ra * 32 + ka];
            bH[r] = *(const half8*)&lB[cur][0][rb * 32 + kb];
            bR[r] = *(const half8*)&lB[cur][1][rb * 32 + kb];
        }
#pragma unroll
        for (int r = 0; r < 4; ++r)
#pragma unroll
            for (int c = 0; c < 4; ++c) {
                acc1[r][c] = __builtin_amdgcn_mfma_f32_16x16x32_f16(aH[r], bH[c], acc1[r][c], 0, 0, 0);
                acc2[r][c] = __builtin_amdgcn_mfma_f32_16x16x32_f16(aH[r], bR[c], acc2[r][c], 0, 0, 0);
                acc2[r][c] = __builtin_amdgcn_mfma_f32_16x16x32_f16(aR[r], bH[c], acc2[r][c], 0, 0, 0);
            }
        // one barrier per K-step: drains lgkm (frag reads of cur done for all waves)
        // and vmcnt (stage of nxt landed) -- stage had the whole compute to fly.
        __syncthreads();
        cur = nxt;
    }
#undef STAGE

    const float s1 = 0x1p-22f, s2 = 0x1p-33f;
#pragma unroll
    for (int c = 0; c < 4; ++c) {
        int n = j0 + wvc * 64 + c * 16 + ln15;
        float nbv = nb[n];
#pragma unroll
        for (int r = 0; r < 4; ++r) {
            int mb = i0 + wvr * 64 + r * 16 + (lane >> 4) * 4;
#pragma unroll
            for (int e = 0; e < 4; ++e)
                preact[(size_t)(mb + e) * M_ + n] = acc1[r][c][e] * s1 + acc2[r][c][e] * s2 + nbv;
        }
    }
}

// ---------- transpose W_dec [1024][32768] -> wdt [32768][1024] ----------
__global__ __launch_bounds__(256) void tr_k(const float* __restrict__ wdec,
                                            float* __restrict__ wdt)
{
    __shared__ float tile[32][33];
    int tx = threadIdx.x, ty = threadIdx.y;
    int x0 = blockIdx.x * 32;
    int y0 = blockIdx.y * 32;
#pragma unroll
    for (int j = 0; j < 32; j += 8)
        tile[ty + j][tx] = wdec[(size_t)(y0 + ty + j) * M_ + x0 + tx];
    __syncthreads();
#pragma unroll
    for (int j = 0; j < 32; j += 8)
        wdt[(size_t)(x0 + ty + j) * D_ + y0 + tx] = tile[tx][ty + j];
}

// ---------- fused dual top-k select (MFMA-order): top-128 unmasked + masked cands ----------
__global__ __launch_bounds__(256) void select_both(
    const float* __restrict__ preact, const int* __restrict__ steps,
    int* __restrict__ sel_idx, float* __restrict__ sel_val,
    int* __restrict__ auxcand)
{
    __shared__ unsigned histU[4096];
    __shared__ unsigned histM[4096];
    __shared__ unsigned coarse[256];
    __shared__ unsigned long long candU[512];
    __shared__ unsigned long long candM[512];
    __shared__ unsigned cntU, cntM, thrU, thrM;

    const int t = threadIdx.x;
    const int b = blockIdx.x;
    const float* row = preact + (size_t)b * M_;

    for (int i = t; i < 4096; i += 256) { histU[i] = 0; histM[i] = 0; }
    candU[t] = 0ULL; candU[t + 256] = 0ULL;
    candM[t] = 0ULL; candM[t + 256] = 0ULL;
    if (t == 0) { cntU = 0; cntM = 0; }
    __syncthreads();

    for (int m = t; m < M_; m += 256) {
        unsigned key = f2k(row[m]);
        atomicAdd(&histU[key >> 20], 1u);
        bool dead = (steps[m] + 1) > 256;
        atomicAdd(&histM[dead ? (key >> 20) : 2048u], 1u);
    }
    __syncthreads();

    { unsigned s = 0;
#pragma unroll
      for (int j = 0; j < 16; ++j) s += histU[t * 16 + j];
      coarse[t] = s; }
    __syncthreads();
    if (t == 0) {
        unsigned cum = 0; int cb = 0;
        for (int c = 255; c >= 0; --c) { if (cum + coarse[c] >= 128u) { cb = c; break; } cum += coarse[c]; }
        int tb = cb * 16;
        for (int f = cb * 16 + 15; f >= cb * 16; --f) { if (cum + histU[f] >= 128u) { tb = f; break; } cum += histU[f]; }
        thrU = (unsigned)tb;
    }
    __syncthreads();
    { unsigned s = 0;
#pragma unroll
      for (int j = 0; j < 16; ++j) s += histM[t * 16 + j];
      coarse[t] = s; }
    __syncthreads();
    if (t == 0) {
        unsigned cum = 0; int cb = 0;
        for (int c = 255; c >= 0; --c) { if (cum + coarse[c] >= 64u) { cb = c; break; } cum += coarse[c]; }
        int tb = cb * 16;
        for (int f = cb * 16 + 15; f >= cb * 16; --f) { if (cum + histM[f] >= 64u) { tb = f; break; } cum += histM[f]; }
        thrM = (unsigned)(tb > 0 ? tb - 1 : 0);   // one extra bin: margin for top-96 resolve superset
    }
    __syncthreads();

    const unsigned TU = thrU, TM = thrM;

    for (int m = t; m < M_; m += 256) {
        unsigned key = f2k(row[m]);
        if ((key >> 20) >= TU) {
            unsigned p = atomicAdd(&cntU, 1u);
            if (p < 512u) candU[p] = ((unsigned long long)key << 32) | (unsigned)(~m);
        }
        bool dead = (steps[m] + 1) > 256;
        if (dead && (key >> 20) >= TM) {
            unsigned p = atomicAdd(&cntM, 1u);
            if (p < 512u) candM[p] = ((unsigned long long)key << 32) | (unsigned)(~m);
        }
    }
    __syncthreads();

    for (unsigned kk = 2; kk <= 512; kk <<= 1) {
        for (unsigned j = kk >> 1; j > 0; j >>= 1) {
#pragma unroll
            for (int h = 0; h < 2; ++h) {
                unsigned i = (unsigned)t + (unsigned)h * 256u;
                unsigned ixj = i ^ j;
                if (ixj > i) {
                    bool desc = ((i & kk) == 0);
                    unsigned long long a = candU[i], c = candU[ixj];
                    if (desc ? (a < c) : (a > c)) { candU[i] = c; candU[ixj] = a; }
                    a = candM[i]; c = candM[ixj];
                    if (desc ? (a < c) : (a > c)) { candM[i] = c; candM[ixj] = a; }
                }
            }
            __syncthreads();
        }
    }

    if (t < 128) {
        unsigned long long c = candU[t];
        unsigned m = ~(unsigned)c;
        float v = k2f((unsigned)(c >> 32));
        sel_idx[b * 128 + t] = (int)m;
        sel_val[b * 128 + t] = v > 0.f ? v : 0.f;
    }
    if (t < 96) {
        unsigned long long c = candM[t];
        auxcand[b * 96 + t] = c ? (int)(~(unsigned)c) : -1;
    }
}

// ---------- exact resolve in FLOAT64: recompute candidate dots at f64 precision ----------
__global__ __launch_bounds__(256) void resolve_k(
    const float* __restrict__ x, const float* __restrict__ ib,
    const float* __restrict__ wenc, const float* __restrict__ nb,
    const int* __restrict__ sel_idx, const int* __restrict__ auxcand,
    int* __restrict__ rec32_idx, float* __restrict__ rec32_val,
    float* __restrict__ out_tidx, float* __restrict__ out_tval,
    float* __restrict__ out_aidx, float* __restrict__ out_aval)
{
    __shared__ double xcs[1024];
    __shared__ unsigned long long kU[64];
    __shared__ unsigned long long kM[128];
    __shared__ float vU[64];
    __shared__ float vM[128];

    const int b = blockIdx.x, t = threadIdx.x;
    for (int d = t; d < 1024; d += 256)
        xcs[d] = (double)x[(size_t)b * 1024 + d] - (double)ib[d];
    if (t < 64)  { kU[t] = 0ULL; vU[t] = 0.f; }
    if (t < 128) { kM[t] = 0ULL; vM[t] = 0.f; }
    __syncthreads();

    int m = -1;
    if (t < 64) m = sel_idx[b * 128 + t];                 // full 64-wide margin over top-32
    else if (t >= 64 && t < 160) m = auxcand[b * 96 + (t - 64)];
    if (m >= 0) {
        const float* w = wenc + (size_t)m * 1024;
        double a0 = 0.0, a1 = 0.0, a2 = 0.0, a3 = 0.0;
        for (int d = 0; d < 1024; d += 4) {
            float4 wv = *(const float4*)(w + d);
            a0 = fma((double)wv.x, xcs[d + 0], a0);
            a1 = fma((double)wv.y, xcs[d + 1], a1);
            a2 = fma((double)wv.z, xcs[d + 2], a2);
            a3 = fma((double)wv.w, xcs[d + 3], a3);
        }
        double v = ((a0 + a1) + (a2 + a3)) + (double)nb[m];
        unsigned long long key = (d2k(v) & 0xFFFFFFFFFFFF0000ull)
                               | (unsigned long long)((~(unsigned)m) & 0xFFFFu);
        float vf = (float)v;
        if (t < 64) { kU[t] = key; vU[t] = vf; }
        else        { kM[t - 64] = key; vM[t - 64] = vf; }
    }
    __syncthreads();

    for (unsigned kk = 2; kk <= 128; kk <<= 1) {
        for (unsigned j = kk >> 1; j > 0; j >>= 1) {
            unsigned i = (unsigned)t, ixj = i ^ j;
            if (kk <= 64 && i < 64 && ixj > i) {
                bool desc = ((i & kk) == 0);
                unsigned long long a = kU[i], c = kU[ixj];
                if (desc ? (a < c) : (a > c)) {
                    kU[i] = c; kU[ixj] = a;
                    float fa = vU[i]; vU[i] = vU[ixj]; vU[ixj] = fa;
                }
            }
            if (i < 128 && ixj > i) {
                bool desc = ((i & kk) == 0);
                unsigned long long a = kM[i], c = kM[ixj];
                if (desc ? (a < c) : (a > c)) {
                    kM[i] = c; kM[ixj] = a;
                    float fa = vM[i]; vM[i] = vM[ixj]; vM[ixj] = fa;
                }
            }
            __syncthreads();
        }
    }

    if (t < 32) {
        unsigned mm = (~(unsigned)kU[t]) & 0xFFFFu;
        float v = vU[t];
        float rv = v > 0.f ? v : 0.f;
        rec32_idx[b * 32 + t] = (int)mm;
        rec32_val[b * 32 + t] = rv;
        out_tidx[b * 32 + t] = (float)mm;
        out_tval[b * 32 + t] = rv;
    }
    if (t < 64) {
        unsigned mm = (~(unsigned)kM[t]) & 0xFFFFu;
        float v = vM[t];
        out_aidx[b * 64 + t] = (float)mm;
        out_aval[b * 64 + t] = v > 0.f ? v : 0.f;
    }
}

// ---------- sparse decoder: multik from MFMA top-128, recon/mat from exact top-32 ----------
__global__ __launch_bounds__(256) void dec_k(
    const float* __restrict__ wdt, const int* __restrict__ sel_idx,
    const float* __restrict__ sel_val, const int* __restrict__ rec32_idx,
    const float* __restrict__ rec32_val, const float* __restrict__ ib,
    float* __restrict__ o_recon, float* __restrict__ o_multik,
    float* __restrict__ o_mat0, float* __restrict__ o_mat1)
{
    __shared__ int sidx[128];
    __shared__ float sval[128];
    __shared__ int ridx[32];
    __shared__ float rval[32];
    const int b = blockIdx.x, t = threadIdx.x;
    if (t < 128) { sidx[t] = sel_idx[b * 128 + t]; sval[t] = sel_val[b * 128 + t]; }
    if (t < 32)  { ridx[t] = rec32_idx[b * 32 + t]; rval[t] = rec32_val[b * 32 + t]; }
    __syncthreads();

    const int d = t * 4;
    float4 bias = *(const float4*)(ib + d);
    float4 mul = bias, rec = bias, m0 = bias, m1 = bias;

    for (int k = 0; k < 128; ++k) {
        float v = sval[k];
        float4 w = *(const float4*)(wdt + (size_t)sidx[k] * D_ + d);
        mul.x += v * w.x; mul.y += v * w.y; mul.z += v * w.z; mul.w += v * w.w;
    }
    for (int k = 0; k < 32; ++k) {
        int idx = ridx[k];
        float v = rval[k];
        float4 w = *(const float4*)(wdt + (size_t)idx * D_ + d);
        rec.x += v * w.x; rec.y += v * w.y; rec.z += v * w.z; rec.w += v * w.w;
        if (idx < 16384) {
            m1.x += v * w.x; m1.y += v * w.y; m1.z += v * w.z; m1.w += v * w.w;
            if (idx < 4096) {
                m0.x += v * w.x; m0.y += v * w.y; m0.z += v * w.z; m0.w += v * w.w;
            }
        }
    }
    size_t o = (size_t)b * D_ + d;
    *(float4*)(o_recon + o)  = rec;
    *(float4*)(o_multik + o) = mul;
    *(float4*)(o_mat0 + o)   = m0;
    *(float4*)(o_mat1 + o)   = m1;
}

extern "C" void kernel_launch(void* const* d_in, const int* in_sizes, int n_in,
                              void* d_out, int out_size, void* d_ws, size_t ws_size,
                              hipStream_t stream)
{
    const float* x     = (const float*)d_in[0];
    const float* wenc  = (const float*)d_in[1];
    const float* wdec  = (const float*)d_in[2];
    const float* ib    = (const float*)d_in[3];
    const float* nb    = (const float*)d_in[4];
    const int*   steps = (const int*)d_in[5];
    float* out = (float*)d_out;

    char* ws = (char*)d_ws;
    float*     preact  = (float*)ws;                              // [0, 64MB)
    _Float16*  whf     = (_Float16*)(ws + 67108864);              // [64MB, 128MB)
    _Float16*  wrf     = (_Float16*)(ws + 134217728);             // [128MB, 192MB)
    float*     wdt     = (float*)(ws + 67108864);                 // aliases whf/wrf (dead after GEMM)
    _Float16*  xhf     = (_Float16*)(ws + 201326592);             // [192MB, +1MB)
    _Float16*  xrf     = (_Float16*)(ws + 202375168);             // [193MB, +1MB)
    int*       auxcand = (int*)(ws + 201326592);                  // aliases xhf (dead after GEMM), 192KB
    int*       rec32_i = (int*)(ws + 201326592 + 262144);         // 64KB
    float*     rec32_v = (float*)(ws + 201326592 + 327680);       // 64KB
    int*       sel_idx = (int*)(ws + 203423744);                  // [194MB, +256KB)
    float*     sel_val = (float*)(ws + 203685888);                // +256KB

    float* out_recon  = out;
    float* out_multik = out + 524288;
    float* out_mat0   = out + 1048576;
    float* out_mat1   = out + 1572864;
    float* out_tidx   = out + 2097152;
    float* out_tval   = out + 2097152 + 16384;
    float* out_aidx   = out + 2097152 + 32768;
    float* out_aval   = out + 2097152 + 32768 + 32768;

    split_x_k<<<dim3(512), dim3(256), 0, stream>>>(x, ib, xhf, xrf);
    split_w_k<<<dim3(32768), dim3(256), 0, stream>>>(wenc, whf, wrf);
    enc_mfma<<<dim3(256, 4), dim3(256), 0, stream>>>(xhf, xrf, whf, wrf, nb, preact);
    tr_k<<<dim3(1024, 32), dim3(32, 8), 0, stream>>>(wdec, wdt);   // after enc (wdt aliases W splits)
    select_both<<<dim3(512), dim3(256), 0, stream>>>(preact, steps, sel_idx, sel_val, auxcand);
    resolve_k<<<dim3(512), dim3(256), 0, stream>>>(
        x, ib, wenc, nb, sel_idx, auxcand, rec32_i, rec32_v,
        out_tidx, out_tval, out_aidx, out_aval);
    dec_k<<<dim3(512), dim3(256), 0, stream>>>(
        wdt, sel_idx, sel_val, rec32_i, rec32_v, ib,
        out_recon, out_multik, out_mat0, out_mat1);
}

// Round 3
// 642.829 us; speedup vs baseline: 1.2895x; 1.2165x over previous
//
#include <hip/hip_runtime.h>
#include <stdint.h>

#define B_ 512
#define D_ 1024
#define M_ 32768

typedef _Float16 half8 __attribute__((ext_vector_type(8)));
typedef _Float16 half4 __attribute__((ext_vector_type(4)));
typedef float f32x4 __attribute__((ext_vector_type(4)));

// ---------- sortable key helpers (monotonic float <-> u32) ----------
__device__ __forceinline__ unsigned f2k(float f) {
    unsigned b = __float_as_uint(f);
    return (b & 0x80000000u) ? ~b : (b | 0x80000000u);
}
__device__ __forceinline__ float k2f(unsigned k) {
    unsigned b = (k & 0x80000000u) ? (k & 0x7FFFFFFFu) : ~k;
    return __uint_as_float(b);
}
// monotonic double -> u64 key
__device__ __forceinline__ unsigned long long d2k(double d) {
    unsigned long long b = (unsigned long long)__double_as_longlong(d);
    return (b & 0x8000000000000000ull) ? ~b : (b | 0x8000000000000000ull);
}

// ---------- async global->LDS (16B per lane, wave-uniform base + lane*16) ----------
__device__ __forceinline__ void gld16(const void* g, void* l) {
    __builtin_amdgcn_global_load_lds(
        (__attribute__((address_space(1))) void*)(uintptr_t)g,
        (__attribute__((address_space(3))) void*)(unsigned)(uintptr_t)l,
        16, 0, 0);
}

// ---------- split x: xc = (x - ib) * 2048 -> fp16 hi + fp16 residual*2048 ----------
__global__ __launch_bounds__(256) void split_x_k(
    const float* __restrict__ x, const float* __restrict__ ib,
    _Float16* __restrict__ xh, _Float16* __restrict__ xr)
{
    int i = blockIdx.x * 256 + threadIdx.x;   // float4 index, 131072 total
    float4 v = ((const float4*)x)[i];
    float4 bb = ((const float4*)ib)[i & 255];
    float a0 = (v.x - bb.x) * 2048.0f;
    float a1 = (v.y - bb.y) * 2048.0f;
    float a2 = (v.z - bb.z) * 2048.0f;
    float a3 = (v.w - bb.w) * 2048.0f;
    _Float16 h0 = (_Float16)a0, h1 = (_Float16)a1, h2 = (_Float16)a2, h3 = (_Float16)a3;
    _Float16 r0 = (_Float16)((a0 - (float)h0) * 2048.0f);
    _Float16 r1 = (_Float16)((a1 - (float)h1) * 2048.0f);
    _Float16 r2 = (_Float16)((a2 - (float)h2) * 2048.0f);
    _Float16 r3 = (_Float16)((a3 - (float)h3) * 2048.0f);
    half4 hv = {h0, h1, h2, h3};
    half4 rv = {r0, r1, r2, r3};
    ((half4*)xh)[i] = hv;
    ((half4*)xr)[i] = rv;
}

// ---------- split W_enc: w*2048 -> fp16 hi + fp16 residual*2048 ----------
__global__ __launch_bounds__(256) void split_w_k(
    const float* __restrict__ w, _Float16* __restrict__ wh, _Float16* __restrict__ wr)
{
    int i = blockIdx.x * 256 + threadIdx.x;   // float4 index, 8388608 total
    float4 v = ((const float4*)w)[i];
    float a0 = v.x * 2048.0f, a1 = v.y * 2048.0f, a2 = v.z * 2048.0f, a3 = v.w * 2048.0f;
    _Float16 h0 = (_Float16)a0, h1 = (_Float16)a1, h2 = (_Float16)a2, h3 = (_Float16)a3;
    _Float16 r0 = (_Float16)((a0 - (float)h0) * 2048.0f);
    _Float16 r1 = (_Float16)((a1 - (float)h1) * 2048.0f);
    _Float16 r2 = (_Float16)((a2 - (float)h2) * 2048.0f);
    _Float16 r3 = (_Float16)((a3 - (float)h3) * 2048.0f);
    half4 hv = {h0, h1, h2, h3};
    half4 rv = {r0, r1, r2, r3};
    ((half4*)wh)[i] = hv;
    ((half4*)wr)[i] = rv;
}

// ---------- encoder GEMM via MFMA fp16, double-word split ----------
// Double-buffered LDS + stage-ahead, single barrier per K-step, XOR chunk
// swizzle (pre-swizzled global source, linear LDS dest). Bit-identical output.
__global__ __launch_bounds__(256) void enc_mfma(
    const _Float16* __restrict__ xhf, const _Float16* __restrict__ xrf,
    const _Float16* __restrict__ whf, const _Float16* __restrict__ wrf,
    const float* __restrict__ nb, float* __restrict__ preact)
{
    __shared__ alignas(16) _Float16 lA[2][2][128 * 32];
    __shared__ alignas(16) _Float16 lB[2][2][128 * 32];

    const int tid = threadIdx.x;
    const int lane = tid & 63;
    const int wv = tid >> 6;
    const int wvr = wv >> 1;
    const int wvc = wv & 1;
    const int i0 = blockIdx.y * 128;
    const int j0 = blockIdx.x * 128;
    const int ln15 = lane & 15;
    const int kq = (lane >> 4) * 8;   // half index of 16B chunk within 64B row

    f32x4 acc1[4][4], acc2[4][4];
#pragma unroll
    for (int r = 0; r < 4; ++r)
#pragma unroll
        for (int c = 0; c < 4; ++c) {
            acc1[r][c] = (f32x4){0.f, 0.f, 0.f, 0.f};
            acc2[r][c] = (f32x4){0.f, 0.f, 0.f, 0.f};
        }

    const int o0 = wv * 1024 + lane * 16;
    const int o1 = o0 + 4096;
    const int r0 = o0 >> 6, r1 = o1 >> 6;
    const int c0s = (o0 & 63) ^ (((r0 >> 1) & 3) << 4);
    const int c1s = (o1 & 63) ^ (((r1 >> 1) & 3) << 4);

    const int rowA = wvr * 64 + ln15;
    const int rowB = wvc * 64 + ln15;

#define STAGE(k0, s)                                                                     \
    do {                                                                                 \
        gld16((const char*)(xhf + (size_t)(i0 + r0) * 1024 + (k0)) + c0s, (char*)lA[s][0] + o0); \
        gld16((const char*)(xhf + (size_t)(i0 + r1) * 1024 + (k0)) + c1s, (char*)lA[s][0] + o1); \
        gld16((const char*)(xrf + (size_t)(i0 + r0) * 1024 + (k0)) + c0s, (char*)lA[s][1] + o0); \
        gld16((const char*)(xrf + (size_t)(i0 + r1) * 1024 + (k0)) + c1s, (char*)lA[s][1] + o1); \
        gld16((const char*)(whf + (size_t)(j0 + r0) * 1024 + (k0)) + c0s, (char*)lB[s][0] + o0); \
        gld16((const char*)(whf + (size_t)(j0 + r1) * 1024 + (k0)) + c1s, (char*)lB[s][0] + o1); \
        gld16((const char*)(wrf + (size_t)(j0 + r0) * 1024 + (k0)) + c0s, (char*)lB[s][1] + o0); \
        gld16((const char*)(wrf + (size_t)(j0 + r1) * 1024 + (k0)) + c1s, (char*)lB[s][1] + o1); \
    } while (0)

    STAGE(0, 0);
    __syncthreads();

    int cur = 0;
    for (int k0 = 0; k0 < 1024; k0 += 32) {
        const int nxt = cur ^ 1;
        if (k0 + 32 < 1024) STAGE(k0 + 32, nxt);

        half8 aH[4], aR[4], bH[4], bR[4];
#pragma unroll
        for (int r = 0; r < 4; ++r) {
            const int ra = rowA + r * 16;
            const int rb = rowB + r * 16;
            const int ka = kq ^ (((ra >> 1) & 3) << 3);
            const int kb = kq ^ (((rb >> 1) & 3) << 3);
            aH[r] = *(const half8*)&lA[cur][0][ra * 32 + ka];
            aR[r] = *(const half8*)&lA[cur][1][ra * 32 + ka];
            bH[r] = *(const half8*)&lB[cur][0][rb * 32 + kb];
            bR[r] = *(const half8*)&lB[cur][1][rb * 32 + kb];
        }
#pragma unroll
        for (int r = 0; r < 4; ++r)
#pragma unroll
            for (int c = 0; c < 4; ++c) {
                acc1[r][c] = __builtin_amdgcn_mfma_f32_16x16x32_f16(aH[r], bH[c], acc1[r][c], 0, 0, 0);
                acc2[r][c] = __builtin_amdgcn_mfma_f32_16x16x32_f16(aH[r], bR[c], acc2[r][c], 0, 0, 0);
                acc2[r][c] = __builtin_amdgcn_mfma_f32_16x16x32_f16(aR[r], bH[c], acc2[r][c], 0, 0, 0);
            }
        __syncthreads();
        cur = nxt;
    }
#undef STAGE

    const float s1 = 0x1p-22f, s2 = 0x1p-33f;
#pragma unroll
    for (int c = 0; c < 4; ++c) {
        int n = j0 + wvc * 64 + c * 16 + ln15;
        float nbv = nb[n];
#pragma unroll
        for (int r = 0; r < 4; ++r) {
            int mb = i0 + wvr * 64 + r * 16 + (lane >> 4) * 4;
#pragma unroll
            for (int e = 0; e < 4; ++e)
                preact[(size_t)(mb + e) * M_ + n] = acc1[r][c][e] * s1 + acc2[r][c][e] * s2 + nbv;
        }
    }
}

// ---------- transpose W_dec [1024][32768] -> wdt [32768][1024] ----------
__global__ __launch_bounds__(256) void tr_k(const float* __restrict__ wdec,
                                            float* __restrict__ wdt)
{
    __shared__ float tile[32][33];
    int tx = threadIdx.x, ty = threadIdx.y;
    int x0 = blockIdx.x * 32;
    int y0 = blockIdx.y * 32;
#pragma unroll
    for (int j = 0; j < 32; j += 8)
        tile[ty + j][tx] = wdec[(size_t)(y0 + ty + j) * M_ + x0 + tx];
    __syncthreads();
#pragma unroll
    for (int j = 0; j < 32; j += 8)
        wdt[(size_t)(x0 + ty + j) * D_ + y0 + tx] = tile[tx][ty + j];
}

// ---------- fused dual top-k select, round-3 restructure ----------
// 1024 threads/block, float4 loads cached in registers (single memory pass),
// parallel suffix-scan thresholds, no dummy-bin histM atomics, 512+512
// thread-split bitonic. Candidate sets / thresholds / sort order identical
// to the round-2 version.
__global__ __launch_bounds__(1024, 4) void select_both(
    const float* __restrict__ preact, const int* __restrict__ steps,
    int* __restrict__ sel_idx, float* __restrict__ sel_val,
    int* __restrict__ auxcand)
{
    __shared__ unsigned histU[4096];
    __shared__ unsigned histM[4096];
    __shared__ unsigned coarseU[256];
    __shared__ unsigned coarseM[256];
    __shared__ unsigned long long candU[512];
    __shared__ unsigned long long candM[512];
    __shared__ unsigned cntU, cntM, thrU, thrM, cbU, cbM, cumU, cumM;

    const int t = threadIdx.x;
    const int b = blockIdx.x;
    const float* row = preact + (size_t)b * M_;

    for (int i = t; i < 4096; i += 1024) { histU[i] = 0; histM[i] = 0; }
    if (t < 512) { candU[t] = 0ULL; candM[t] = 0ULL; }
    if (t == 0) { cntU = 0; cntM = 0; }
    __syncthreads();

    // ---- dead mask first (retires int regs before value cache fills) ----
    unsigned deadmask = 0;
#pragma unroll
    for (int p = 0; p < 8; ++p) {
        int i = t + p * 1024;                     // int4 / float4 index
        int4 sv = ((const int4*)steps)[i];
        unsigned mbits = 0;
        if (sv.x + 1 > 256) mbits |= 1u;
        if (sv.y + 1 > 256) mbits |= 2u;
        if (sv.z + 1 > 256) mbits |= 4u;
        if (sv.w + 1 > 256) mbits |= 8u;
        deadmask |= mbits << (p * 4);
    }

    // ---- single memory pass: load row into registers + histogram ----
    float4 v[8];
#pragma unroll
    for (int p = 0; p < 8; ++p) {
        int i = t + p * 1024;
        v[p] = ((const float4*)row)[i];
        unsigned k0 = f2k(v[p].x) >> 20;
        unsigned k1 = f2k(v[p].y) >> 20;
        unsigned k2 = f2k(v[p].z) >> 20;
        unsigned k3 = f2k(v[p].w) >> 20;
        atomicAdd(&histU[k0], 1u);
        atomicAdd(&histU[k1], 1u);
        atomicAdd(&histU[k2], 1u);
        atomicAdd(&histU[k3], 1u);
        unsigned dm = deadmask >> (p * 4);
        if (dm & 1u) atomicAdd(&histM[k0], 1u);
        if (dm & 2u) atomicAdd(&histM[k1], 1u);
        if (dm & 4u) atomicAdd(&histM[k2], 1u);
        if (dm & 8u) atomicAdd(&histM[k3], 1u);
    }
    __syncthreads();

    // ---- coarse sums (U by threads 0-255, M by 256-511) ----
    if (t < 256) {
        unsigned s = 0;
#pragma unroll
        for (int j = 0; j < 16; ++j) s += histU[t * 16 + j];
        coarseU[t] = s;
    } else if (t < 512) {
        int c = t - 256;
        unsigned s = 0;
#pragma unroll
        for (int j = 0; j < 16; ++j) s += histM[c * 16 + j];
        coarseM[c] = s;
    }
    __syncthreads();

    // ---- joint Hillis-Steele suffix scan over both coarse arrays ----
    for (int off = 1; off < 256; off <<= 1) {
        unsigned xv = 0;
        if (t < 256)      xv = coarseU[t] + (t + off < 256 ? coarseU[t + off] : 0u);
        else if (t < 512) { int c = t - 256; xv = coarseM[c] + (c + off < 256 ? coarseM[c + off] : 0u); }
        __syncthreads();
        if (t < 256)      coarseU[t] = xv;
        else if (t < 512) coarseM[t - 256] = xv;
        __syncthreads();
    }

    // ---- find crossing bins (suffix >= K boundary) ----
    if (t < 256) {
        unsigned S = coarseU[t];
        unsigned Sn = (t < 255) ? coarseU[t + 1] : 0u;
        if (S >= 128u && (t == 255 || Sn < 128u)) { cbU = (unsigned)t; cumU = Sn; }
    } else if (t < 512) {
        int c = t - 256;
        unsigned S = coarseM[c];
        unsigned Sn = (c < 255) ? coarseM[c + 1] : 0u;
        if (S >= 64u && (c == 255 || Sn < 64u)) { cbM = (unsigned)c; cumM = Sn; }
        if (c == 0 && S < 64u) { cbM = 0u; cumM = Sn; }   // degenerate: <64 masked total
    }
    __syncthreads();

    // ---- fine scans (t==0 for U, t==64 for M run concurrently) ----
    if (t == 0) {
        unsigned cum = cumU;
        int base = (int)cbU * 16, tb = base;
        for (int f = base + 15; f >= base; --f) {
            unsigned h = histU[f];
            if (cum + h >= 128u) { tb = f; break; }
            cum += h;
        }
        thrU = (unsigned)tb;
    }
    if (t == 64) {
        unsigned cum = cumM;
        int base = (int)cbM * 16, tb = base;
        for (int f = base + 15; f >= base; --f) {
            unsigned h = histM[f];
            if (cum + h >= 64u) { tb = f; break; }
            cum += h;
        }
        thrM = (unsigned)(tb > 0 ? tb - 1 : 0);   // one extra bin: margin for top-96 superset
    }
    __syncthreads();

    const unsigned TU = thrU, TM = thrM;

    // ---- candidate collection straight from registers ----
#pragma unroll
    for (int p = 0; p < 8; ++p) {
        int i = t + p * 1024;
#pragma unroll
        for (int e = 0; e < 4; ++e) {
            float val = (e == 0) ? v[p].x : (e == 1) ? v[p].y : (e == 2) ? v[p].z : v[p].w;
            unsigned key = f2k(val);
            int m = i * 4 + e;
            if ((key >> 20) >= TU) {
                unsigned pz = atomicAdd(&cntU, 1u);
                if (pz < 512u) candU[pz] = ((unsigned long long)key << 32) | (unsigned)(~m);
            }
            if (((deadmask >> (p * 4 + e)) & 1u) && (key >> 20) >= TM) {
                unsigned pz = atomicAdd(&cntM, 1u);
                if (pz < 512u) candM[pz] = ((unsigned long long)key << 32) | (unsigned)(~m);
            }
        }
    }
    __syncthreads();

    // ---- bitonic sort: threads 0-511 -> candU, 512-1023 -> candM ----
    {
        unsigned long long* arr = (t < 512) ? candU : candM;
        const unsigned i = (unsigned)t & 511u;
        for (unsigned kk = 2; kk <= 512; kk <<= 1) {
            for (unsigned j = kk >> 1; j > 0; j >>= 1) {
                unsigned ixj = i ^ j;
                if (ixj > i) {
                    bool desc = ((i & kk) == 0);
                    unsigned long long a = arr[i], c = arr[ixj];
                    if (desc ? (a < c) : (a > c)) { arr[i] = c; arr[ixj] = a; }
                }
                __syncthreads();
            }
        }
    }

    if (t < 128) {
        unsigned long long c = candU[t];
        unsigned m = ~(unsigned)c;
        float vv = k2f((unsigned)(c >> 32));
        sel_idx[b * 128 + t] = (int)m;
        sel_val[b * 128 + t] = vv > 0.f ? vv : 0.f;
    }
    if (t < 96) {
        unsigned long long c = candM[t];
        auxcand[b * 96 + t] = c ? (int)(~(unsigned)c) : -1;
    }
}

// ---------- exact resolve in FLOAT64: recompute candidate dots at f64 precision ----------
__global__ __launch_bounds__(256) void resolve_k(
    const float* __restrict__ x, const float* __restrict__ ib,
    const float* __restrict__ wenc, const float* __restrict__ nb,
    const int* __restrict__ sel_idx, const int* __restrict__ auxcand,
    int* __restrict__ rec32_idx, float* __restrict__ rec32_val,
    float* __restrict__ out_tidx, float* __restrict__ out_tval,
    float* __restrict__ out_aidx, float* __restrict__ out_aval)
{
    __shared__ double xcs[1024];
    __shared__ unsigned long long kU[64];
    __shared__ unsigned long long kM[128];
    __shared__ float vU[64];
    __shared__ float vM[128];

    const int b = blockIdx.x, t = threadIdx.x;
    for (int d = t; d < 1024; d += 256)
        xcs[d] = (double)x[(size_t)b * 1024 + d] - (double)ib[d];
    if (t < 64)  { kU[t] = 0ULL; vU[t] = 0.f; }
    if (t < 128) { kM[t] = 0ULL; vM[t] = 0.f; }
    __syncthreads();

    int m = -1;
    if (t < 64) m = sel_idx[b * 128 + t];
    else if (t >= 64 && t < 160) m = auxcand[b * 96 + (t - 64)];
    if (m >= 0) {
        const float* w = wenc + (size_t)m * 1024;
        double a0 = 0.0, a1 = 0.0, a2 = 0.0, a3 = 0.0;
        for (int d = 0; d < 1024; d += 4) {
            float4 wv = *(const float4*)(w + d);
            a0 = fma((double)wv.x, xcs[d + 0], a0);
            a1 = fma((double)wv.y, xcs[d + 1], a1);
            a2 = fma((double)wv.z, xcs[d + 2], a2);
            a3 = fma((double)wv.w, xcs[d + 3], a3);
        }
        double v = ((a0 + a1) + (a2 + a3)) + (double)nb[m];
        unsigned long long key = (d2k(v) & 0xFFFFFFFFFFFF0000ull)
                               | (unsigned long long)((~(unsigned)m) & 0xFFFFu);
        float vf = (float)v;
        if (t < 64) { kU[t] = key; vU[t] = vf; }
        else        { kM[t - 64] = key; vM[t - 64] = vf; }
    }
    __syncthreads();

    for (unsigned kk = 2; kk <= 128; kk <<= 1) {
        for (unsigned j = kk >> 1; j > 0; j >>= 1) {
            unsigned i = (unsigned)t, ixj = i ^ j;
            if (kk <= 64 && i < 64 && ixj > i) {
                bool desc = ((i & kk) == 0);
                unsigned long long a = kU[i], c = kU[ixj];
                if (desc ? (a < c) : (a > c)) {
                    kU[i] = c; kU[ixj] = a;
                    float fa = vU[i]; vU[i] = vU[ixj]; vU[ixj] = fa;
                }
            }
            if (i < 128 && ixj > i) {
                bool desc = ((i & kk) == 0);
                unsigned long long a = kM[i], c = kM[ixj];
                if (desc ? (a < c) : (a > c)) {
                    kM[i] = c; kM[ixj] = a;
                    float fa = vM[i]; vM[i] = vM[ixj]; vM[ixj] = fa;
                }
            }
            __syncthreads();
        }
    }

    if (t < 32) {
        unsigned mm = (~(unsigned)kU[t]) & 0xFFFFu;
        float v = vU[t];
        float rv = v > 0.f ? v : 0.f;
        rec32_idx[b * 32 + t] = (int)mm;
        rec32_val[b * 32 + t] = rv;
        out_tidx[b * 32 + t] = (float)mm;
        out_tval[b * 32 + t] = rv;
    }
    if (t < 64) {
        unsigned mm = (~(unsigned)kM[t]) & 0xFFFFu;
        float v = vM[t];
        out_aidx[b * 64 + t] = (float)mm;
        out_aval[b * 64 + t] = v > 0.f ? v : 0.f;
    }
}

// ---------- sparse decoder: multik from MFMA top-128, recon/mat from exact top-32 ----------
__global__ __launch_bounds__(256) void dec_k(
    const float* __restrict__ wdt, const int* __restrict__ sel_idx,
    const float* __restrict__ sel_val, const int* __restrict__ rec32_idx,
    const float* __restrict__ rec32_val, const float* __restrict__ ib,
    float* __restrict__ o_recon, float* __restrict__ o_multik,
    float* __restrict__ o_mat0, float* __restrict__ o_mat1)
{
    __shared__ int sidx[128];
    __shared__ float sval[128];
    __shared__ int ridx[32];
    __shared__ float rval[32];
    const int b = blockIdx.x, t = threadIdx.x;
    if (t < 128) { sidx[t] = sel_idx[b * 128 + t]; sval[t] = sel_val[b * 128 + t]; }
    if (t < 32)  { ridx[t] = rec32_idx[b * 32 + t]; rval[t] = rec32_val[b * 32 + t]; }
    __syncthreads();

    const int d = t * 4;
    float4 bias = *(const float4*)(ib + d);
    float4 mul = bias, rec = bias, m0 = bias, m1 = bias;

    for (int k = 0; k < 128; ++k) {
        float v = sval[k];
        float4 w = *(const float4*)(wdt + (size_t)sidx[k] * D_ + d);
        mul.x += v * w.x; mul.y += v * w.y; mul.z += v * w.z; mul.w += v * w.w;
    }
    for (int k = 0; k < 32; ++k) {
        int idx = ridx[k];
        float v = rval[k];
        float4 w = *(const float4*)(wdt + (size_t)idx * D_ + d);
        rec.x += v * w.x; rec.y += v * w.y; rec.z += v * w.z; rec.w += v * w.w;
        if (idx < 16384) {
            m1.x += v * w.x; m1.y += v * w.y; m1.z += v * w.z; m1.w += v * w.w;
            if (idx < 4096) {
                m0.x += v * w.x; m0.y += v * w.y; m0.z += v * w.z; m0.w += v * w.w;
            }
        }
    }
    size_t o = (size_t)b * D_ + d;
    *(float4*)(o_recon + o)  = rec;
    *(float4*)(o_multik + o) = mul;
    *(float4*)(o_mat0 + o)   = m0;
    *(float4*)(o_mat1 + o)   = m1;
}

extern "C" void kernel_launch(void* const* d_in, const int* in_sizes, int n_in,
                              void* d_out, int out_size, void* d_ws, size_t ws_size,
                              hipStream_t stream)
{
    const float* x     = (const float*)d_in[0];
    const float* wenc  = (const float*)d_in[1];
    const float* wdec  = (const float*)d_in[2];
    const float* ib    = (const float*)d_in[3];
    const float* nb    = (const float*)d_in[4];
    const int*   steps = (const int*)d_in[5];
    float* out = (float*)d_out;

    char* ws = (char*)d_ws;
    float*     preact  = (float*)ws;                              // [0, 64MB)
    _Float16*  whf     = (_Float16*)(ws + 67108864);              // [64MB, 128MB)
    _Float16*  wrf     = (_Float16*)(ws + 134217728);             // [128MB, 192MB)
    float*     wdt     = (float*)(ws + 67108864);                 // aliases whf/wrf (dead after GEMM)
    _Float16*  xhf     = (_Float16*)(ws + 201326592);             // [192MB, +1MB)
    _Float16*  xrf     = (_Float16*)(ws + 202375168);             // [193MB, +1MB)
    int*       auxcand = (int*)(ws + 201326592);                  // aliases xhf (dead after GEMM), 192KB
    int*       rec32_i = (int*)(ws + 201326592 + 262144);         // 64KB
    float*     rec32_v = (float*)(ws + 201326592 + 327680);       // 64KB
    int*       sel_idx = (int*)(ws + 203423744);                  // [194MB, +256KB)
    float*     sel_val = (float*)(ws + 203685888);                // +256KB

    float* out_recon  = out;
    float* out_multik = out + 524288;
    float* out_mat0   = out + 1048576;
    float* out_mat1   = out + 1572864;
    float* out_tidx   = out + 2097152;
    float* out_tval   = out + 2097152 + 16384;
    float* out_aidx   = out + 2097152 + 32768;
    float* out_aval   = out + 2097152 + 32768 + 32768;

    split_x_k<<<dim3(512), dim3(256), 0, stream>>>(x, ib, xhf, xrf);
    split_w_k<<<dim3(32768), dim3(256), 0, stream>>>(wenc, whf, wrf);
    enc_mfma<<<dim3(256, 4), dim3(256), 0, stream>>>(xhf, xrf, whf, wrf, nb, preact);
    tr_k<<<dim3(1024, 32), dim3(32, 8), 0, stream>>>(wdec, wdt);   // after enc (wdt aliases W splits)
    select_both<<<dim3(512), dim3(1024), 0, stream>>>(preact, steps, sel_idx, sel_val, auxcand);
    resolve_k<<<dim3(512), dim3(256), 0, stream>>>(
        x, ib, wenc, nb, sel_idx, auxcand, rec32_i, rec32_v,
        out_tidx, out_tval, out_aidx, out_aval);
    dec_k<<<dim3(512), dim3(256), 0, stream>>>(
        wdt, sel_idx, sel_val, rec32_i, rec32_v, ib,
        out_recon, out_multik, out_mat0, out_mat1);
}

// Round 4
// 618.664 us; speedup vs baseline: 1.3399x; 1.0391x over previous
//
#include <hip/hip_runtime.h>
#include <stdint.h>

#define B_ 512
#define D_ 1024
#define M_ 32768

typedef _Float16 half8 __attribute__((ext_vector_type(8)));
typedef _Float16 half4 __attribute__((ext_vector_type(4)));
typedef float f32x4 __attribute__((ext_vector_type(4)));

// ---------- sortable key helpers (monotonic float <-> u32) ----------
__device__ __forceinline__ unsigned f2k(float f) {
    unsigned b = __float_as_uint(f);
    return (b & 0x80000000u) ? ~b : (b | 0x80000000u);
}
__device__ __forceinline__ float k2f(unsigned k) {
    unsigned b = (k & 0x80000000u) ? (k & 0x7FFFFFFFu) : ~k;
    return __uint_as_float(b);
}
// monotonic double -> u64 key
__device__ __forceinline__ unsigned long long d2k(double d) {
    unsigned long long b = (unsigned long long)__double_as_longlong(d);
    return (b & 0x8000000000000000ull) ? ~b : (b | 0x8000000000000000ull);
}

// ---------- async global->LDS (16B per lane, wave-uniform base + lane*16) ----------
__device__ __forceinline__ void gld16(const void* g, void* l) {
    __builtin_amdgcn_global_load_lds(
        (__attribute__((address_space(1))) void*)(uintptr_t)g,
        (__attribute__((address_space(3))) void*)(unsigned)(uintptr_t)l,
        16, 0, 0);
}

// ---------- split x: xc = (x - ib) * 2048 -> fp16 hi + fp16 residual*2048 ----------
__global__ __launch_bounds__(256) void split_x_k(
    const float* __restrict__ x, const float* __restrict__ ib,
    _Float16* __restrict__ xh, _Float16* __restrict__ xr)
{
    int i = blockIdx.x * 256 + threadIdx.x;   // float4 index, 131072 total
    float4 v = ((const float4*)x)[i];
    float4 bb = ((const float4*)ib)[i & 255];
    float a0 = (v.x - bb.x) * 2048.0f;
    float a1 = (v.y - bb.y) * 2048.0f;
    float a2 = (v.z - bb.z) * 2048.0f;
    float a3 = (v.w - bb.w) * 2048.0f;
    _Float16 h0 = (_Float16)a0, h1 = (_Float16)a1, h2 = (_Float16)a2, h3 = (_Float16)a3;
    _Float16 r0 = (_Float16)((a0 - (float)h0) * 2048.0f);
    _Float16 r1 = (_Float16)((a1 - (float)h1) * 2048.0f);
    _Float16 r2 = (_Float16)((a2 - (float)h2) * 2048.0f);
    _Float16 r3 = (_Float16)((a3 - (float)h3) * 2048.0f);
    half4 hv = {h0, h1, h2, h3};
    half4 rv = {r0, r1, r2, r3};
    ((half4*)xh)[i] = hv;
    ((half4*)xr)[i] = rv;
}

// ---------- split W_enc: w*2048 -> fp16 hi + fp16 residual*2048 ----------
__global__ __launch_bounds__(256) void split_w_k(
    const float* __restrict__ w, _Float16* __restrict__ wh, _Float16* __restrict__ wr)
{
    int i = blockIdx.x * 256 + threadIdx.x;   // float4 index, 8388608 total
    float4 v = ((const float4*)w)[i];
    float a0 = v.x * 2048.0f, a1 = v.y * 2048.0f, a2 = v.z * 2048.0f, a3 = v.w * 2048.0f;
    _Float16 h0 = (_Float16)a0, h1 = (_Float16)a1, h2 = (_Float16)a2, h3 = (_Float16)a3;
    _Float16 r0 = (_Float16)((a0 - (float)h0) * 2048.0f);
    _Float16 r1 = (_Float16)((a1 - (float)h1) * 2048.0f);
    _Float16 r2 = (_Float16)((a2 - (float)h2) * 2048.0f);
    _Float16 r3 = (_Float16)((a3 - (float)h3) * 2048.0f);
    half4 hv = {h0, h1, h2, h3};
    half4 rv = {r0, r1, r2, r3};
    ((half4*)wh)[i] = hv;
    ((half4*)wr)[i] = rv;
}

// ---------- encoder GEMM via MFMA fp16, double-word split ----------
// Round-4: T3+T4 counted-vmcnt 2-deep pipeline (raw s_barrier, vmcnt(8) mid-loop,
// never drain-to-0 in steady state) + XCD-aware bijective block swizzle
// (a W j-tile's 4 i-blocks land on the same XCD's L2).
// MFMA order / operands unchanged -> bit-identical output vs round-3.
__global__ __launch_bounds__(256) void enc_mfma(
    const _Float16* __restrict__ xhf, const _Float16* __restrict__ xrf,
    const _Float16* __restrict__ whf, const _Float16* __restrict__ wrf,
    const float* __restrict__ nb, float* __restrict__ preact)
{
    __shared__ alignas(16) _Float16 lA[2][2][128 * 32];
    __shared__ alignas(16) _Float16 lB[2][2][128 * 32];

    const int tid = threadIdx.x;
    const int lane = tid & 63;
    const int wv = tid >> 6;
    const int wvr = wv >> 1;
    const int wvc = wv & 1;

    // XCD swizzle: bid in [0,1024); xcd = bid&7 owns j-tiles [xcd*32, xcd*32+32);
    // the 4 i-blocks of one j-tile are bids {q, q+8, q+16, q+24} -> same XCD.
    const int bid = blockIdx.x;
    const int lb = bid >> 3;
    const int j0 = ((bid & 7) * 32 + (lb >> 2)) * 128;
    const int i0 = (lb & 3) * 128;

    const int ln15 = lane & 15;
    const int kq = (lane >> 4) * 8;   // half index of 16B chunk within 64B row

    f32x4 acc1[4][4], acc2[4][4];
#pragma unroll
    for (int r = 0; r < 4; ++r)
#pragma unroll
        for (int c = 0; c < 4; ++c) {
            acc1[r][c] = (f32x4){0.f, 0.f, 0.f, 0.f};
            acc2[r][c] = (f32x4){0.f, 0.f, 0.f, 0.f};
        }

    const int o0 = wv * 1024 + lane * 16;
    const int o1 = o0 + 4096;
    const int r0 = o0 >> 6, r1 = o1 >> 6;
    const int c0s = (o0 & 63) ^ (((r0 >> 1) & 3) << 4);
    const int c1s = (o1 & 63) ^ (((r1 >> 1) & 3) << 4);

    const int rowA = wvr * 64 + ln15;
    const int rowB = wvc * 64 + ln15;

#define STAGE(k0, s)                                                                     \
    do {                                                                                 \
        gld16((const char*)(xhf + (size_t)(i0 + r0) * 1024 + (k0)) + c0s, (char*)lA[s][0] + o0); \
        gld16((const char*)(xhf + (size_t)(i0 + r1) * 1024 + (k0)) + c1s, (char*)lA[s][0] + o1); \
        gld16((const char*)(xrf + (size_t)(i0 + r0) * 1024 + (k0)) + c0s, (char*)lA[s][1] + o0); \
        gld16((const char*)(xrf + (size_t)(i0 + r1) * 1024 + (k0)) + c1s, (char*)lA[s][1] + o1); \
        gld16((const char*)(whf + (size_t)(j0 + r0) * 1024 + (k0)) + c0s, (char*)lB[s][0] + o0); \
        gld16((const char*)(whf + (size_t)(j0 + r1) * 1024 + (k0)) + c1s, (char*)lB[s][0] + o1); \
        gld16((const char*)(wrf + (size_t)(j0 + r0) * 1024 + (k0)) + c0s, (char*)lB[s][1] + o0); \
        gld16((const char*)(wrf + (size_t)(j0 + r1) * 1024 + (k0)) + c1s, (char*)lB[s][1] + o1); \
    } while (0)

    // prologue: 2 tiles in flight (16 loads); wait oldest 8 -> buf0 ready
    STAGE(0, 0);
    STAGE(32, 1);
    asm volatile("s_waitcnt vmcnt(8)" ::: "memory");
    __builtin_amdgcn_s_barrier();

    int cur = 0;
    for (int k0 = 0; k0 < 1024; k0 += 32) {
        // invariant: buf[cur] ready & visible; loads for k0+32 in flight (8)
        half8 aH[4], aR[4], bH[4], bR[4];
#pragma unroll
        for (int r = 0; r < 4; ++r) {
            const int ra = rowA + r * 16;
            const int rb = rowB + r * 16;
            const int ka = kq ^ (((ra >> 1) & 3) << 3);
            const int kb = kq ^ (((rb >> 1) & 3) << 3);
            aH[r] = *(const half8*)&lA[cur][0][ra * 32 + ka];
            aR[r] = *(const half8*)&lA[cur][1][ra * 32 + ka];
            bH[r] = *(const half8*)&lB[cur][0][rb * 32 + kb];
            bR[r] = *(const half8*)&lB[cur][1][rb * 32 + kb];
        }
#pragma unroll
        for (int r = 0; r < 4; ++r)
#pragma unroll
            for (int c = 0; c < 4; ++c) {
                acc1[r][c] = __builtin_amdgcn_mfma_f32_16x16x32_f16(aH[r], bH[c], acc1[r][c], 0, 0, 0);
                acc2[r][c] = __builtin_amdgcn_mfma_f32_16x16x32_f16(aH[r], bR[c], acc2[r][c], 0, 0, 0);
                acc2[r][c] = __builtin_amdgcn_mfma_f32_16x16x32_f16(aR[r], bH[c], acc2[r][c], 0, 0, 0);
            }
        // all waves done reading buf[cur] (frag reads drained per-wave)
        asm volatile("s_waitcnt lgkmcnt(0)" ::: "memory");
        __builtin_amdgcn_s_barrier();

        if (k0 + 64 < 1024) {
            STAGE(k0 + 64, cur);                                   // overwrite cur (16 in flight)
            asm volatile("s_waitcnt vmcnt(8)" ::: "memory");       // k0+32's loads landed
        } else {
            asm volatile("s_waitcnt vmcnt(0)" ::: "memory");       // tail drain
        }
        __builtin_amdgcn_s_barrier();                              // buf[cur^1] ready for all
        cur ^= 1;
    }
#undef STAGE

    const float s1 = 0x1p-22f, s2 = 0x1p-33f;
#pragma unroll
    for (int c = 0; c < 4; ++c) {
        int n = j0 + wvc * 64 + c * 16 + ln15;
        float nbv = nb[n];
#pragma unroll
        for (int r = 0; r < 4; ++r) {
            int mb = i0 + wvr * 64 + r * 16 + (lane >> 4) * 4;
#pragma unroll
            for (int e = 0; e < 4; ++e)
                preact[(size_t)(mb + e) * M_ + n] = acc1[r][c][e] * s1 + acc2[r][c][e] * s2 + nbv;
        }
    }
}

// ---------- transpose W_dec [1024][32768] -> wdt [32768][1024] ----------
__global__ __launch_bounds__(256) void tr_k(const float* __restrict__ wdec,
                                            float* __restrict__ wdt)
{
    __shared__ float tile[32][33];
    int tx = threadIdx.x, ty = threadIdx.y;
    int x0 = blockIdx.x * 32;
    int y0 = blockIdx.y * 32;
#pragma unroll
    for (int j = 0; j < 32; j += 8)
        tile[ty + j][tx] = wdec[(size_t)(y0 + ty + j) * M_ + x0 + tx];
    __syncthreads();
#pragma unroll
    for (int j = 0; j < 32; j += 8)
        wdt[(size_t)(x0 + ty + j) * D_ + y0 + tx] = tile[tx][ty + j];
}

// ---------- fused dual top-k select (1024 thr, single pass, reg value cache) ----------
__global__ __launch_bounds__(1024, 4) void select_both(
    const float* __restrict__ preact, const int* __restrict__ steps,
    int* __restrict__ sel_idx, float* __restrict__ sel_val,
    int* __restrict__ auxcand)
{
    __shared__ unsigned histU[4096];
    __shared__ unsigned histM[4096];
    __shared__ unsigned coarseU[256];
    __shared__ unsigned coarseM[256];
    __shared__ unsigned long long candU[512];
    __shared__ unsigned long long candM[512];
    __shared__ unsigned cntU, cntM, thrU, thrM, cbU, cbM, cumU, cumM;

    const int t = threadIdx.x;
    const int b = blockIdx.x;
    const float* row = preact + (size_t)b * M_;

    for (int i = t; i < 4096; i += 1024) { histU[i] = 0; histM[i] = 0; }
    if (t < 512) { candU[t] = 0ULL; candM[t] = 0ULL; }
    if (t == 0) { cntU = 0; cntM = 0; }
    __syncthreads();

    // ---- dead mask ----
    unsigned deadmask = 0;
#pragma unroll
    for (int p = 0; p < 8; ++p) {
        int i = t + p * 1024;                     // int4 / float4 index
        int4 sv = ((const int4*)steps)[i];
        unsigned mbits = 0;
        if (sv.x + 1 > 256) mbits |= 1u;
        if (sv.y + 1 > 256) mbits |= 2u;
        if (sv.z + 1 > 256) mbits |= 4u;
        if (sv.w + 1 > 256) mbits |= 8u;
        deadmask |= mbits << (p * 4);
    }

    // ---- single memory pass: load row into registers + histogram ----
    float4 v[8];
#pragma unroll
    for (int p = 0; p < 8; ++p) {
        int i = t + p * 1024;
        v[p] = ((const float4*)row)[i];
        unsigned k0 = f2k(v[p].x) >> 20;
        unsigned k1 = f2k(v[p].y) >> 20;
        unsigned k2 = f2k(v[p].z) >> 20;
        unsigned k3 = f2k(v[p].w) >> 20;
        atomicAdd(&histU[k0], 1u);
        atomicAdd(&histU[k1], 1u);
        atomicAdd(&histU[k2], 1u);
        atomicAdd(&histU[k3], 1u);
        unsigned dm = deadmask >> (p * 4);
        if (dm & 1u) atomicAdd(&histM[k0], 1u);
        if (dm & 2u) atomicAdd(&histM[k1], 1u);
        if (dm & 4u) atomicAdd(&histM[k2], 1u);
        if (dm & 8u) atomicAdd(&histM[k3], 1u);
    }
    __syncthreads();

    // ---- coarse sums (U by threads 0-255, M by 256-511) ----
    if (t < 256) {
        unsigned s = 0;
#pragma unroll
        for (int j = 0; j < 16; ++j) s += histU[t * 16 + j];
        coarseU[t] = s;
    } else if (t < 512) {
        int c = t - 256;
        unsigned s = 0;
#pragma unroll
        for (int j = 0; j < 16; ++j) s += histM[c * 16 + j];
        coarseM[c] = s;
    }
    __syncthreads();

    // ---- joint Hillis-Steele suffix scan over both coarse arrays ----
    for (int off = 1; off < 256; off <<= 1) {
        unsigned xv = 0;
        if (t < 256)      xv = coarseU[t] + (t + off < 256 ? coarseU[t + off] : 0u);
        else if (t < 512) { int c = t - 256; xv = coarseM[c] + (c + off < 256 ? coarseM[c + off] : 0u); }
        __syncthreads();
        if (t < 256)      coarseU[t] = xv;
        else if (t < 512) coarseM[t - 256] = xv;
        __syncthreads();
    }

    // ---- find crossing bins (suffix >= K boundary) ----
    if (t < 256) {
        unsigned S = coarseU[t];
        unsigned Sn = (t < 255) ? coarseU[t + 1] : 0u;
        if (S >= 128u && (t == 255 || Sn < 128u)) { cbU = (unsigned)t; cumU = Sn; }
    } else if (t < 512) {
        int c = t - 256;
        unsigned S = coarseM[c];
        unsigned Sn = (c < 255) ? coarseM[c + 1] : 0u;
        if (S >= 64u && (c == 255 || Sn < 64u)) { cbM = (unsigned)c; cumM = Sn; }
        if (c == 0 && S < 64u) { cbM = 0u; cumM = Sn; }   // degenerate: <64 masked total
    }
    __syncthreads();

    // ---- fine scans (t==0 for U, t==64 for M run concurrently) ----
    if (t == 0) {
        unsigned cum = cumU;
        int base = (int)cbU * 16, tb = base;
        for (int f = base + 15; f >= base; --f) {
            unsigned h = histU[f];
            if (cum + h >= 128u) { tb = f; break; }
            cum += h;
        }
        thrU = (unsigned)tb;
    }
    if (t == 64) {
        unsigned cum = cumM;
        int base = (int)cbM * 16, tb = base;
        for (int f = base + 15; f >= base; --f) {
            unsigned h = histM[f];
            if (cum + h >= 64u) { tb = f; break; }
            cum += h;
        }
        thrM = (unsigned)(tb > 0 ? tb - 1 : 0);   // one extra bin: margin for top-96 superset
    }
    __syncthreads();

    const unsigned TU = thrU, TM = thrM;

    // ---- candidate collection straight from registers ----
#pragma unroll
    for (int p = 0; p < 8; ++p) {
        int i = t + p * 1024;
#pragma unroll
        for (int e = 0; e < 4; ++e) {
            float val = (e == 0) ? v[p].x : (e == 1) ? v[p].y : (e == 2) ? v[p].z : v[p].w;
            unsigned key = f2k(val);
            int m = i * 4 + e;
            if ((key >> 20) >= TU) {
                unsigned pz = atomicAdd(&cntU, 1u);
                if (pz < 512u) candU[pz] = ((unsigned long long)key << 32) | (unsigned)(~m);
            }
            if (((deadmask >> (p * 4 + e)) & 1u) && (key >> 20) >= TM) {
                unsigned pz = atomicAdd(&cntM, 1u);
                if (pz < 512u) candM[pz] = ((unsigned long long)key << 32) | (unsigned)(~m);
            }
        }
    }
    __syncthreads();

    // ---- bitonic sort: threads 0-511 -> candU, 512-1023 -> candM ----
    {
        unsigned long long* arr = (t < 512) ? candU : candM;
        const unsigned i = (unsigned)t & 511u;
        for (unsigned kk = 2; kk <= 512; kk <<= 1) {
            for (unsigned j = kk >> 1; j > 0; j >>= 1) {
                unsigned ixj = i ^ j;
                if (ixj > i) {
                    bool desc = ((i & kk) == 0);
                    unsigned long long a = arr[i], c = arr[ixj];
                    if (desc ? (a < c) : (a > c)) { arr[i] = c; arr[ixj] = a; }
                }
                __syncthreads();
            }
        }
    }

    if (t < 128) {
        unsigned long long c = candU[t];
        unsigned m = ~(unsigned)c;
        float vv = k2f((unsigned)(c >> 32));
        sel_idx[b * 128 + t] = (int)m;
        sel_val[b * 128 + t] = vv > 0.f ? vv : 0.f;
    }
    if (t < 96) {
        unsigned long long c = candM[t];
        auxcand[b * 96 + t] = c ? (int)(~(unsigned)c) : -1;
    }
}

// ---------- exact resolve in FLOAT64: recompute candidate dots at f64 precision ----------
__global__ __launch_bounds__(256) void resolve_k(
    const float* __restrict__ x, const float* __restrict__ ib,
    const float* __restrict__ wenc, const float* __restrict__ nb,
    const int* __restrict__ sel_idx, const int* __restrict__ auxcand,
    int* __restrict__ rec32_idx, float* __restrict__ rec32_val,
    float* __restrict__ out_tidx, float* __restrict__ out_tval,
    float* __restrict__ out_aidx, float* __restrict__ out_aval)
{
    __shared__ double xcs[1024];
    __shared__ unsigned long long kU[64];
    __shared__ unsigned long long kM[128];
    __shared__ float vU[64];
    __shared__ float vM[128];

    const int b = blockIdx.x, t = threadIdx.x;
    for (int d = t; d < 1024; d += 256)
        xcs[d] = (double)x[(size_t)b * 1024 + d] - (double)ib[d];
    if (t < 64)  { kU[t] = 0ULL; vU[t] = 0.f; }
    if (t < 128) { kM[t] = 0ULL; vM[t] = 0.f; }
    __syncthreads();

    int m = -1;
    if (t < 64) m = sel_idx[b * 128 + t];
    else if (t >= 64 && t < 160) m = auxcand[b * 96 + (t - 64)];
    if (m >= 0) {
        const float* w = wenc + (size_t)m * 1024;
        double a0 = 0.0, a1 = 0.0, a2 = 0.0, a3 = 0.0;
        for (int d = 0; d < 1024; d += 4) {
            float4 wv = *(const float4*)(w + d);
            a0 = fma((double)wv.x, xcs[d + 0], a0);
            a1 = fma((double)wv.y, xcs[d + 1], a1);
            a2 = fma((double)wv.z, xcs[d + 2], a2);
            a3 = fma((double)wv.w, xcs[d + 3], a3);
        }
        double v = ((a0 + a1) + (a2 + a3)) + (double)nb[m];
        unsigned long long key = (d2k(v) & 0xFFFFFFFFFFFF0000ull)
                               | (unsigned long long)((~(unsigned)m) & 0xFFFFu);
        float vf = (float)v;
        if (t < 64) { kU[t] = key; vU[t] = vf; }
        else        { kM[t - 64] = key; vM[t - 64] = vf; }
    }
    __syncthreads();

    for (unsigned kk = 2; kk <= 128; kk <<= 1) {
        for (unsigned j = kk >> 1; j > 0; j >>= 1) {
            unsigned i = (unsigned)t, ixj = i ^ j;
            if (kk <= 64 && i < 64 && ixj > i) {
                bool desc = ((i & kk) == 0);
                unsigned long long a = kU[i], c = kU[ixj];
                if (desc ? (a < c) : (a > c)) {
                    kU[i] = c; kU[ixj] = a;
                    float fa = vU[i]; vU[i] = vU[ixj]; vU[ixj] = fa;
                }
            }
            if (i < 128 && ixj > i) {
                bool desc = ((i & kk) == 0);
                unsigned long long a = kM[i], c = kM[ixj];
                if (desc ? (a < c) : (a > c)) {
                    kM[i] = c; kM[ixj] = a;
                    float fa = vM[i]; vM[i] = vM[ixj]; vM[ixj] = fa;
                }
            }
            __syncthreads();
        }
    }

    if (t < 32) {
        unsigned mm = (~(unsigned)kU[t]) & 0xFFFFu;
        float v = vU[t];
        float rv = v > 0.f ? v : 0.f;
        rec32_idx[b * 32 + t] = (int)mm;
        rec32_val[b * 32 + t] = rv;
        out_tidx[b * 32 + t] = (float)mm;
        out_tval[b * 32 + t] = rv;
    }
    if (t < 64) {
        unsigned mm = (~(unsigned)kM[t]) & 0xFFFFu;
        float v = vM[t];
        out_aidx[b * 64 + t] = (float)mm;
        out_aval[b * 64 + t] = v > 0.f ? v : 0.f;
    }
}

// ---------- sparse decoder: multik from MFMA top-128, recon/mat from exact top-32 ----------
__global__ __launch_bounds__(256) void dec_k(
    const float* __restrict__ wdt, const int* __restrict__ sel_idx,
    const float* __restrict__ sel_val, const int* __restrict__ rec32_idx,
    const float* __restrict__ rec32_val, const float* __restrict__ ib,
    float* __restrict__ o_recon, float* __restrict__ o_multik,
    float* __restrict__ o_mat0, float* __restrict__ o_mat1)
{
    __shared__ int sidx[128];
    __shared__ float sval[128];
    __shared__ int ridx[32];
    __shared__ float rval[32];
    const int b = blockIdx.x, t = threadIdx.x;
    if (t < 128) { sidx[t] = sel_idx[b * 128 + t]; sval[t] = sel_val[b * 128 + t]; }
    if (t < 32)  { ridx[t] = rec32_idx[b * 32 + t]; rval[t] = rec32_val[b * 32 + t]; }
    __syncthreads();

    const int d = t * 4;
    float4 bias = *(const float4*)(ib + d);
    float4 mul = bias, rec = bias, m0 = bias, m1 = bias;

    for (int k = 0; k < 128; ++k) {
        float v = sval[k];
        float4 w = *(const float4*)(wdt + (size_t)sidx[k] * D_ + d);
        mul.x += v * w.x; mul.y += v * w.y; mul.z += v * w.z; mul.w += v * w.w;
    }
    for (int k = 0; k < 32; ++k) {
        int idx = ridx[k];
        float v = rval[k];
        float4 w = *(const float4*)(wdt + (size_t)idx * D_ + d);
        rec.x += v * w.x; rec.y += v * w.y; rec.z += v * w.z; rec.w += v * w.w;
        if (idx < 16384) {
            m1.x += v * w.x; m1.y += v * w.y; m1.z += v * w.z; m1.w += v * w.w;
            if (idx < 4096) {
                m0.x += v * w.x; m0.y += v * w.y; m0.z += v * w.z; m0.w += v * w.w;
            }
        }
    }
    size_t o = (size_t)b * D_ + d;
    *(float4*)(o_recon + o)  = rec;
    *(float4*)(o_multik + o) = mul;
    *(float4*)(o_mat0 + o)   = m0;
    *(float4*)(o_mat1 + o)   = m1;
}

extern "C" void kernel_launch(void* const* d_in, const int* in_sizes, int n_in,
                              void* d_out, int out_size, void* d_ws, size_t ws_size,
                              hipStream_t stream)
{
    const float* x     = (const float*)d_in[0];
    const float* wenc  = (const float*)d_in[1];
    const float* wdec  = (const float*)d_in[2];
    const float* ib    = (const float*)d_in[3];
    const float* nb    = (const float*)d_in[4];
    const int*   steps = (const int*)d_in[5];
    float* out = (float*)d_out;

    char* ws = (char*)d_ws;
    float*     preact  = (float*)ws;                              // [0, 64MB)
    _Float16*  whf     = (_Float16*)(ws + 67108864);              // [64MB, 128MB)
    _Float16*  wrf     = (_Float16*)(ws + 134217728);             // [128MB, 192MB)
    float*     wdt     = (float*)(ws + 67108864);                 // aliases whf/wrf (dead after GEMM)
    _Float16*  xhf     = (_Float16*)(ws + 201326592);             // [192MB, +1MB)
    _Float16*  xrf     = (_Float16*)(ws + 202375168);             // [193MB, +1MB)
    int*       auxcand = (int*)(ws + 201326592);                  // aliases xhf (dead after GEMM), 192KB
    int*       rec32_i = (int*)(ws + 201326592 + 262144);         // 64KB
    float*     rec32_v = (float*)(ws + 201326592 + 327680);       // 64KB
    int*       sel_idx = (int*)(ws + 203423744);                  // [194MB, +256KB)
    float*     sel_val = (float*)(ws + 203685888);                // +256KB

    float* out_recon  = out;
    float* out_multik = out + 524288;
    float* out_mat0   = out + 1048576;
    float* out_mat1   = out + 1572864;
    float* out_tidx   = out + 2097152;
    float* out_tval   = out + 2097152 + 16384;
    float* out_aidx   = out + 2097152 + 32768;
    float* out_aval   = out + 2097152 + 32768 + 32768;

    split_x_k<<<dim3(512), dim3(256), 0, stream>>>(x, ib, xhf, xrf);
    split_w_k<<<dim3(32768), dim3(256), 0, stream>>>(wenc, whf, wrf);
    enc_mfma<<<dim3(1024), dim3(256), 0, stream>>>(xhf, xrf, whf, wrf, nb, preact);
    tr_k<<<dim3(1024, 32), dim3(32, 8), 0, stream>>>(wdec, wdt);   // after enc (wdt aliases W splits)
    select_both<<<dim3(512), dim3(1024), 0, stream>>>(preact, steps, sel_idx, sel_val, auxcand);
    resolve_k<<<dim3(512), dim3(256), 0, stream>>>(
        x, ib, wenc, nb, sel_idx, auxcand, rec32_i, rec32_v,
        out_tidx, out_tval, out_aidx, out_aval);
    dec_k<<<dim3(512), dim3(256), 0, stream>>>(
        wdt, sel_idx, sel_val, rec32_i, rec32_v, ib,
        out_recon, out_multik, out_mat0, out_mat1);
}

// Round 5
// 605.273 us; speedup vs baseline: 1.3695x; 1.0221x over previous
//
#include <hip/hip_runtime.h>
#include <stdint.h>

#define B_ 512
#define D_ 1024
#define M_ 32768

typedef _Float16 half8 __attribute__((ext_vector_type(8)));
typedef _Float16 half4 __attribute__((ext_vector_type(4)));
typedef float f32x4 __attribute__((ext_vector_type(4)));

// ---------- sortable key helpers (monotonic float <-> u32) ----------
__device__ __forceinline__ unsigned f2k(float f) {
    unsigned b = __float_as_uint(f);
    return (b & 0x80000000u) ? ~b : (b | 0x80000000u);
}
__device__ __forceinline__ float k2f(unsigned k) {
    unsigned b = (k & 0x80000000u) ? (k & 0x7FFFFFFFu) : ~k;
    return __uint_as_float(b);
}
// monotonic double -> u64 key
__device__ __forceinline__ unsigned long long d2k(double d) {
    unsigned long long b = (unsigned long long)__double_as_longlong(d);
    return (b & 0x8000000000000000ull) ? ~b : (b | 0x8000000000000000ull);
}

// ---------- async global->LDS (16B per lane, wave-uniform base + lane*16) ----------
__device__ __forceinline__ void gld16(const void* g, void* l) {
    __builtin_amdgcn_global_load_lds(
        (__attribute__((address_space(1))) void*)(uintptr_t)g,
        (__attribute__((address_space(3))) void*)(unsigned)(uintptr_t)l,
        16, 0, 0);
}

// ---------- split x: xc = (x - ib) * 2048 -> fp16 hi + fp16 residual*2048 ----------
__global__ __launch_bounds__(256) void split_x_k(
    const float* __restrict__ x, const float* __restrict__ ib,
    _Float16* __restrict__ xh, _Float16* __restrict__ xr)
{
    int i = blockIdx.x * 256 + threadIdx.x;   // float4 index, 131072 total
    float4 v = ((const float4*)x)[i];
    float4 bb = ((const float4*)ib)[i & 255];
    float a0 = (v.x - bb.x) * 2048.0f;
    float a1 = (v.y - bb.y) * 2048.0f;
    float a2 = (v.z - bb.z) * 2048.0f;
    float a3 = (v.w - bb.w) * 2048.0f;
    _Float16 h0 = (_Float16)a0, h1 = (_Float16)a1, h2 = (_Float16)a2, h3 = (_Float16)a3;
    _Float16 r0 = (_Float16)((a0 - (float)h0) * 2048.0f);
    _Float16 r1 = (_Float16)((a1 - (float)h1) * 2048.0f);
    _Float16 r2 = (_Float16)((a2 - (float)h2) * 2048.0f);
    _Float16 r3 = (_Float16)((a3 - (float)h3) * 2048.0f);
    half4 hv = {h0, h1, h2, h3};
    half4 rv = {r0, r1, r2, r3};
    ((half4*)xh)[i] = hv;
    ((half4*)xr)[i] = rv;
}

// ---------- split W_enc: w*2048 -> fp16 hi + fp16 residual*2048 ----------
__global__ __launch_bounds__(256) void split_w_k(
    const float* __restrict__ w, _Float16* __restrict__ wh, _Float16* __restrict__ wr)
{
    int i = blockIdx.x * 256 + threadIdx.x;   // float4 index, 8388608 total
    float4 v = ((const float4*)w)[i];
    float a0 = v.x * 2048.0f, a1 = v.y * 2048.0f, a2 = v.z * 2048.0f, a3 = v.w * 2048.0f;
    _Float16 h0 = (_Float16)a0, h1 = (_Float16)a1, h2 = (_Float16)a2, h3 = (_Float16)a3;
    _Float16 r0 = (_Float16)((a0 - (float)h0) * 2048.0f);
    _Float16 r1 = (_Float16)((a1 - (float)h1) * 2048.0f);
    _Float16 r2 = (_Float16)((a2 - (float)h2) * 2048.0f);
    _Float16 r3 = (_Float16)((a3 - (float)h3) * 2048.0f);
    half4 hv = {h0, h1, h2, h3};
    half4 rv = {r0, r1, r2, r3};
    ((half4*)wh)[i] = hv;
    ((half4*)wr)[i] = rv;
}

// ---------- encoder GEMM via MFMA fp16, double-word split ----------
// Round-5: 128x64 tile (acc 64 regs/wave, LDS 48KB) -> 3 blocks/CU so the
// counted-vmcnt pipeline has cross-block TLP to hide residual latency.
// K-loop order / MFMA sequence per output element unchanged -> bit-identical.
__global__ __launch_bounds__(256, 3) void enc_mfma(
    const _Float16* __restrict__ xhf, const _Float16* __restrict__ xrf,
    const _Float16* __restrict__ whf, const _Float16* __restrict__ wrf,
    const float* __restrict__ nb, float* __restrict__ preact)
{
    __shared__ alignas(16) _Float16 lA[2][2][128 * 32];   // 8 KB per [s][hr]
    __shared__ alignas(16) _Float16 lB[2][2][64 * 32];    // 4 KB per [s][hr]

    const int tid = threadIdx.x;
    const int lane = tid & 63;
    const int wv = tid >> 6;
    const int wvr = wv >> 1;          // 0..1 -> M half (64 rows)
    const int wvc = wv & 1;           // 0..1 -> N half (32 cols)

    // XCD swizzle: 2048 blocks; xcd = bid&7 owns 64 consecutive j-tiles.
    // The 4 i-blocks of one j-tile are bids {x+8*(4j), x+8*(4j+1), ...} ->
    // same XCD, temporally adjacent -> W slab L2-resident.
    const int bid = blockIdx.x;
    const int lb = bid >> 3;                      // [0,256)
    const int j0 = ((bid & 7) * 64 + (lb >> 2)) * 64;
    const int i0 = (lb & 3) * 128;

    const int ln15 = lane & 15;
    const int kq = (lane >> 4) * 8;   // half index of 16B chunk within 64B row

    f32x4 acc1[4][2], acc2[4][2];
#pragma unroll
    for (int r = 0; r < 4; ++r)
#pragma unroll
        for (int c = 0; c < 2; ++c) {
            acc1[r][c] = (f32x4){0.f, 0.f, 0.f, 0.f};
            acc2[r][c] = (f32x4){0.f, 0.f, 0.f, 0.f};
        }

    // A staging: 8 KB per array -> 2 rounds; B staging: 4 KB -> 1 round.
    const int o0 = tid * 16;                // [0,4096)
    const int o1 = o0 + 4096;               // [4096,8192)
    const int rA0 = o0 >> 6, rA1 = o1 >> 6; // [0,64), [64,128)
    const int cA0s = (o0 & 63) ^ (((rA0 >> 1) & 3) << 4);
    const int cA1s = (o1 & 63) ^ (((rA1 >> 1) & 3) << 4);
    const int rB0 = o0 >> 6;                // [0,64)
    const int cB0s = (o0 & 63) ^ (((rB0 >> 1) & 3) << 4);

    const int rowA = wvr * 64 + ln15;
    const int rowB = wvc * 32 + ln15;

#define STAGE(k0, s)                                                                     \
    do {                                                                                 \
        gld16((const char*)(xhf + (size_t)(i0 + rA0) * 1024 + (k0)) + cA0s, (char*)lA[s][0] + o0); \
        gld16((const char*)(xhf + (size_t)(i0 + rA1) * 1024 + (k0)) + cA1s, (char*)lA[s][0] + o1); \
        gld16((const char*)(xrf + (size_t)(i0 + rA0) * 1024 + (k0)) + cA0s, (char*)lA[s][1] + o0); \
        gld16((const char*)(xrf + (size_t)(i0 + rA1) * 1024 + (k0)) + cA1s, (char*)lA[s][1] + o1); \
        gld16((const char*)(whf + (size_t)(j0 + rB0) * 1024 + (k0)) + cB0s, (char*)lB[s][0] + o0); \
        gld16((const char*)(wrf + (size_t)(j0 + rB0) * 1024 + (k0)) + cB0s, (char*)lB[s][1] + o0); \
    } while (0)

    // prologue: 2 tiles in flight (12 loads); wait oldest 6 -> buf0 ready
    STAGE(0, 0);
    STAGE(32, 1);
    asm volatile("s_waitcnt vmcnt(6)" ::: "memory");
    __builtin_amdgcn_s_barrier();

    int cur = 0;
    for (int k0 = 0; k0 < 1024; k0 += 32) {
        // invariant: buf[cur] ready & visible; loads for k0+32 in flight (6)
        half8 aH[4], aR[4], bH[2], bR[2];
#pragma unroll
        for (int r = 0; r < 4; ++r) {
            const int ra = rowA + r * 16;
            const int ka = kq ^ (((ra >> 1) & 3) << 3);
            aH[r] = *(const half8*)&lA[cur][0][ra * 32 + ka];
            aR[r] = *(const half8*)&lA[cur][1][ra * 32 + ka];
        }
#pragma unroll
        for (int c = 0; c < 2; ++c) {
            const int rb = rowB + c * 16;
            const int kb = kq ^ (((rb >> 1) & 3) << 3);
            bH[c] = *(const half8*)&lB[cur][0][rb * 32 + kb];
            bR[c] = *(const half8*)&lB[cur][1][rb * 32 + kb];
        }
#pragma unroll
        for (int r = 0; r < 4; ++r)
#pragma unroll
            for (int c = 0; c < 2; ++c) {
                acc1[r][c] = __builtin_amdgcn_mfma_f32_16x16x32_f16(aH[r], bH[c], acc1[r][c], 0, 0, 0);
                acc2[r][c] = __builtin_amdgcn_mfma_f32_16x16x32_f16(aH[r], bR[c], acc2[r][c], 0, 0, 0);
                acc2[r][c] = __builtin_amdgcn_mfma_f32_16x16x32_f16(aR[r], bH[c], acc2[r][c], 0, 0, 0);
            }
        // all waves done reading buf[cur]
        asm volatile("s_waitcnt lgkmcnt(0)" ::: "memory");
        __builtin_amdgcn_s_barrier();

        if (k0 + 64 < 1024) {
            STAGE(k0 + 64, cur);                                   // overwrite cur (12 in flight)
            asm volatile("s_waitcnt vmcnt(6)" ::: "memory");       // k0+32's loads landed
        } else {
            asm volatile("s_waitcnt vmcnt(0)" ::: "memory");       // tail drain
        }
        __builtin_amdgcn_s_barrier();                              // buf[cur^1] ready for all
        cur ^= 1;
    }
#undef STAGE

    const float s1 = 0x1p-22f, s2 = 0x1p-33f;
#pragma unroll
    for (int c = 0; c < 2; ++c) {
        int n = j0 + wvc * 32 + c * 16 + ln15;
        float nbv = nb[n];
#pragma unroll
        for (int r = 0; r < 4; ++r) {
            int mb = i0 + wvr * 64 + r * 16 + (lane >> 4) * 4;
#pragma unroll
            for (int e = 0; e < 4; ++e)
                preact[(size_t)(mb + e) * M_ + n] = acc1[r][c][e] * s1 + acc2[r][c][e] * s2 + nbv;
        }
    }
}

// ---------- transpose W_dec [1024][32768] -> wdt [32768][1024] ----------
__global__ __launch_bounds__(256) void tr_k(const float* __restrict__ wdec,
                                            float* __restrict__ wdt)
{
    __shared__ float tile[32][33];
    int tx = threadIdx.x, ty = threadIdx.y;
    int x0 = blockIdx.x * 32;
    int y0 = blockIdx.y * 32;
#pragma unroll
    for (int j = 0; j < 32; j += 8)
        tile[ty + j][tx] = wdec[(size_t)(y0 + ty + j) * M_ + x0 + tx];
    __syncthreads();
#pragma unroll
    for (int j = 0; j < 32; j += 8)
        wdt[(size_t)(x0 + ty + j) * D_ + y0 + tx] = tile[tx][ty + j];
}

// ---------- fused dual top-k select (1024 thr, single pass, reg value cache) ----------
__global__ __launch_bounds__(1024, 4) void select_both(
    const float* __restrict__ preact, const int* __restrict__ steps,
    int* __restrict__ sel_idx, float* __restrict__ sel_val,
    int* __restrict__ auxcand)
{
    __shared__ unsigned histU[4096];
    __shared__ unsigned histM[4096];
    __shared__ unsigned coarseU[256];
    __shared__ unsigned coarseM[256];
    __shared__ unsigned long long candU[512];
    __shared__ unsigned long long candM[512];
    __shared__ unsigned cntU, cntM, thrU, thrM, cbU, cbM, cumU, cumM;

    const int t = threadIdx.x;
    const int b = blockIdx.x;
    const float* row = preact + (size_t)b * M_;

    for (int i = t; i < 4096; i += 1024) { histU[i] = 0; histM[i] = 0; }
    if (t < 512) { candU[t] = 0ULL; candM[t] = 0ULL; }
    if (t == 0) { cntU = 0; cntM = 0; }
    __syncthreads();

    // ---- dead mask ----
    unsigned deadmask = 0;
#pragma unroll
    for (int p = 0; p < 8; ++p) {
        int i = t + p * 1024;                     // int4 / float4 index
        int4 sv = ((const int4*)steps)[i];
        unsigned mbits = 0;
        if (sv.x + 1 > 256) mbits |= 1u;
        if (sv.y + 1 > 256) mbits |= 2u;
        if (sv.z + 1 > 256) mbits |= 4u;
        if (sv.w + 1 > 256) mbits |= 8u;
        deadmask |= mbits << (p * 4);
    }

    // ---- single memory pass: load row into registers + histogram ----
    float4 v[8];
#pragma unroll
    for (int p = 0; p < 8; ++p) {
        int i = t + p * 1024;
        v[p] = ((const float4*)row)[i];
        unsigned k0 = f2k(v[p].x) >> 20;
        unsigned k1 = f2k(v[p].y) >> 20;
        unsigned k2 = f2k(v[p].z) >> 20;
        unsigned k3 = f2k(v[p].w) >> 20;
        atomicAdd(&histU[k0], 1u);
        atomicAdd(&histU[k1], 1u);
        atomicAdd(&histU[k2], 1u);
        atomicAdd(&histU[k3], 1u);
        unsigned dm = deadmask >> (p * 4);
        if (dm & 1u) atomicAdd(&histM[k0], 1u);
        if (dm & 2u) atomicAdd(&histM[k1], 1u);
        if (dm & 4u) atomicAdd(&histM[k2], 1u);
        if (dm & 8u) atomicAdd(&histM[k3], 1u);
    }
    __syncthreads();

    // ---- coarse sums (U by threads 0-255, M by 256-511) ----
    if (t < 256) {
        unsigned s = 0;
#pragma unroll
        for (int j = 0; j < 16; ++j) s += histU[t * 16 + j];
        coarseU[t] = s;
    } else if (t < 512) {
        int c = t - 256;
        unsigned s = 0;
#pragma unroll
        for (int j = 0; j < 16; ++j) s += histM[c * 16 + j];
        coarseM[c] = s;
    }
    __syncthreads();

    // ---- joint Hillis-Steele suffix scan over both coarse arrays ----
    for (int off = 1; off < 256; off <<= 1) {
        unsigned xv = 0;
        if (t < 256)      xv = coarseU[t] + (t + off < 256 ? coarseU[t + off] : 0u);
        else if (t < 512) { int c = t - 256; xv = coarseM[c] + (c + off < 256 ? coarseM[c + off] : 0u); }
        __syncthreads();
        if (t < 256)      coarseU[t] = xv;
        else if (t < 512) coarseM[t - 256] = xv;
        __syncthreads();
    }

    // ---- find crossing bins (suffix >= K boundary) ----
    if (t < 256) {
        unsigned S = coarseU[t];
        unsigned Sn = (t < 255) ? coarseU[t + 1] : 0u;
        if (S >= 128u && (t == 255 || Sn < 128u)) { cbU = (unsigned)t; cumU = Sn; }
    } else if (t < 512) {
        int c = t - 256;
        unsigned S = coarseM[c];
        unsigned Sn = (c < 255) ? coarseM[c + 1] : 0u;
        if (S >= 64u && (c == 255 || Sn < 64u)) { cbM = (unsigned)c; cumM = Sn; }
        if (c == 0 && S < 64u) { cbM = 0u; cumM = Sn; }   // degenerate: <64 masked total
    }
    __syncthreads();

    // ---- fine scans (t==0 for U, t==64 for M run concurrently) ----
    if (t == 0) {
        unsigned cum = cumU;
        int base = (int)cbU * 16, tb = base;
        for (int f = base + 15; f >= base; --f) {
            unsigned h = histU[f];
            if (cum + h >= 128u) { tb = f; break; }
            cum += h;
        }
        thrU = (unsigned)tb;
    }
    if (t == 64) {
        unsigned cum = cumM;
        int base = (int)cbM * 16, tb = base;
        for (int f = base + 15; f >= base; --f) {
            unsigned h = histM[f];
            if (cum + h >= 64u) { tb = f; break; }
            cum += h;
        }
        thrM = (unsigned)(tb > 0 ? tb - 1 : 0);   // one extra bin: margin for top-96 superset
    }
    __syncthreads();

    const unsigned TU = thrU, TM = thrM;

    // ---- candidate collection straight from registers ----
#pragma unroll
    for (int p = 0; p < 8; ++p) {
        int i = t + p * 1024;
#pragma unroll
        for (int e = 0; e < 4; ++e) {
            float val = (e == 0) ? v[p].x : (e == 1) ? v[p].y : (e == 2) ? v[p].z : v[p].w;
            unsigned key = f2k(val);
            int m = i * 4 + e;
            if ((key >> 20) >= TU) {
                unsigned pz = atomicAdd(&cntU, 1u);
                if (pz < 512u) candU[pz] = ((unsigned long long)key << 32) | (unsigned)(~m);
            }
            if (((deadmask >> (p * 4 + e)) & 1u) && (key >> 20) >= TM) {
                unsigned pz = atomicAdd(&cntM, 1u);
                if (pz < 512u) candM[pz] = ((unsigned long long)key << 32) | (unsigned)(~m);
            }
        }
    }
    __syncthreads();

    // ---- bitonic sort: threads 0-511 -> candU, 512-1023 -> candM ----
    {
        unsigned long long* arr = (t < 512) ? candU : candM;
        const unsigned i = (unsigned)t & 511u;
        for (unsigned kk = 2; kk <= 512; kk <<= 1) {
            for (unsigned j = kk >> 1; j > 0; j >>= 1) {
                unsigned ixj = i ^ j;
                if (ixj > i) {
                    bool desc = ((i & kk) == 0);
                    unsigned long long a = arr[i], c = arr[ixj];
                    if (desc ? (a < c) : (a > c)) { arr[i] = c; arr[ixj] = a; }
                }
                __syncthreads();
            }
        }
    }

    if (t < 128) {
        unsigned long long c = candU[t];
        unsigned m = ~(unsigned)c;
        float vv = k2f((unsigned)(c >> 32));
        sel_idx[b * 128 + t] = (int)m;
        sel_val[b * 128 + t] = vv > 0.f ? vv : 0.f;
    }
    if (t < 96) {
        unsigned long long c = candM[t];
        auxcand[b * 96 + t] = c ? (int)(~(unsigned)c) : -1;
    }
}

// ---------- exact resolve in FLOAT64: recompute candidate dots at f64 precision ----------
__global__ __launch_bounds__(256) void resolve_k(
    const float* __restrict__ x, const float* __restrict__ ib,
    const float* __restrict__ wenc, const float* __restrict__ nb,
    const int* __restrict__ sel_idx, const int* __restrict__ auxcand,
    int* __restrict__ rec32_idx, float* __restrict__ rec32_val,
    float* __restrict__ out_tidx, float* __restrict__ out_tval,
    float* __restrict__ out_aidx, float* __restrict__ out_aval)
{
    __shared__ double xcs[1024];
    __shared__ unsigned long long kU[64];
    __shared__ unsigned long long kM[128];
    __shared__ float vU[64];
    __shared__ float vM[128];

    const int b = blockIdx.x, t = threadIdx.x;
    for (int d = t; d < 1024; d += 256)
        xcs[d] = (double)x[(size_t)b * 1024 + d] - (double)ib[d];
    if (t < 64)  { kU[t] = 0ULL; vU[t] = 0.f; }
    if (t < 128) { kM[t] = 0ULL; vM[t] = 0.f; }
    __syncthreads();

    int m = -1;
    if (t < 64) m = sel_idx[b * 128 + t];
    else if (t >= 64 && t < 160) m = auxcand[b * 96 + (t - 64)];
    if (m >= 0) {
        const float* w = wenc + (size_t)m * 1024;
        double a0 = 0.0, a1 = 0.0, a2 = 0.0, a3 = 0.0;
        for (int d = 0; d < 1024; d += 4) {
            float4 wv = *(const float4*)(w + d);
            a0 = fma((double)wv.x, xcs[d + 0], a0);
            a1 = fma((double)wv.y, xcs[d + 1], a1);
            a2 = fma((double)wv.z, xcs[d + 2], a2);
            a3 = fma((double)wv.w, xcs[d + 3], a3);
        }
        double v = ((a0 + a1) + (a2 + a3)) + (double)nb[m];
        unsigned long long key = (d2k(v) & 0xFFFFFFFFFFFF0000ull)
                               | (unsigned long long)((~(unsigned)m) & 0xFFFFu);
        float vf = (float)v;
        if (t < 64) { kU[t] = key; vU[t] = vf; }
        else        { kM[t - 64] = key; vM[t - 64] = vf; }
    }
    __syncthreads();

    for (unsigned kk = 2; kk <= 128; kk <<= 1) {
        for (unsigned j = kk >> 1; j > 0; j >>= 1) {
            unsigned i = (unsigned)t, ixj = i ^ j;
            if (kk <= 64 && i < 64 && ixj > i) {
                bool desc = ((i & kk) == 0);
                unsigned long long a = kU[i], c = kU[ixj];
                if (desc ? (a < c) : (a > c)) {
                    kU[i] = c; kU[ixj] = a;
                    float fa = vU[i]; vU[i] = vU[ixj]; vU[ixj] = fa;
                }
            }
            if (i < 128 && ixj > i) {
                bool desc = ((i & kk) == 0);
                unsigned long long a = kM[i], c = kM[ixj];
                if (desc ? (a < c) : (a > c)) {
                    kM[i] = c; kM[ixj] = a;
                    float fa = vM[i]; vM[i] = vM[ixj]; vM[ixj] = fa;
                }
            }
            __syncthreads();
        }
    }

    if (t < 32) {
        unsigned mm = (~(unsigned)kU[t]) & 0xFFFFu;
        float v = vU[t];
        float rv = v > 0.f ? v : 0.f;
        rec32_idx[b * 32 + t] = (int)mm;
        rec32_val[b * 32 + t] = rv;
        out_tidx[b * 32 + t] = (float)mm;
        out_tval[b * 32 + t] = rv;
    }
    if (t < 64) {
        unsigned mm = (~(unsigned)kM[t]) & 0xFFFFu;
        float v = vM[t];
        out_aidx[b * 64 + t] = (float)mm;
        out_aval[b * 64 + t] = v > 0.f ? v : 0.f;
    }
}

// ---------- sparse decoder: multik from MFMA top-128, recon/mat from exact top-32 ----------
__global__ __launch_bounds__(256) void dec_k(
    const float* __restrict__ wdt, const int* __restrict__ sel_idx,
    const float* __restrict__ sel_val, const int* __restrict__ rec32_idx,
    const float* __restrict__ rec32_val, const float* __restrict__ ib,
    float* __restrict__ o_recon, float* __restrict__ o_multik,
    float* __restrict__ o_mat0, float* __restrict__ o_mat1)
{
    __shared__ int sidx[128];
    __shared__ float sval[128];
    __shared__ int ridx[32];
    __shared__ float rval[32];
    const int b = blockIdx.x, t = threadIdx.x;
    if (t < 128) { sidx[t] = sel_idx[b * 128 + t]; sval[t] = sel_val[b * 128 + t]; }
    if (t < 32)  { ridx[t] = rec32_idx[b * 32 + t]; rval[t] = rec32_val[b * 32 + t]; }
    __syncthreads();

    const int d = t * 4;
    float4 bias = *(const float4*)(ib + d);
    float4 mul = bias, rec = bias, m0 = bias, m1 = bias;

    for (int k = 0; k < 128; ++k) {
        float v = sval[k];
        float4 w = *(const float4*)(wdt + (size_t)sidx[k] * D_ + d);
        mul.x += v * w.x; mul.y += v * w.y; mul.z += v * w.z; mul.w += v * w.w;
    }
    for (int k = 0; k < 32; ++k) {
        int idx = ridx[k];
        float v = rval[k];
        float4 w = *(const float4*)(wdt + (size_t)idx * D_ + d);
        rec.x += v * w.x; rec.y += v * w.y; rec.z += v * w.z; rec.w += v * w.w;
        if (idx < 16384) {
            m1.x += v * w.x; m1.y += v * w.y; m1.z += v * w.z; m1.w += v * w.w;
            if (idx < 4096) {
                m0.x += v * w.x; m0.y += v * w.y; m0.z += v * w.z; m0.w += v * w.w;
            }
        }
    }
    size_t o = (size_t)b * D_ + d;
    *(float4*)(o_recon + o)  = rec;
    *(float4*)(o_multik + o) = mul;
    *(float4*)(o_mat0 + o)   = m0;
    *(float4*)(o_mat1 + o)   = m1;
}

extern "C" void kernel_launch(void* const* d_in, const int* in_sizes, int n_in,
                              void* d_out, int out_size, void* d_ws, size_t ws_size,
                              hipStream_t stream)
{
    const float* x     = (const float*)d_in[0];
    const float* wenc  = (const float*)d_in[1];
    const float* wdec  = (const float*)d_in[2];
    const float* ib    = (const float*)d_in[3];
    const float* nb    = (const float*)d_in[4];
    const int*   steps = (const int*)d_in[5];
    float* out = (float*)d_out;

    char* ws = (char*)d_ws;
    float*     preact  = (float*)ws;                              // [0, 64MB)
    _Float16*  whf     = (_Float16*)(ws + 67108864);              // [64MB, 128MB)
    _Float16*  wrf     = (_Float16*)(ws + 134217728);             // [128MB, 192MB)
    float*     wdt     = (float*)(ws + 67108864);                 // aliases whf/wrf (dead after GEMM)
    _Float16*  xhf     = (_Float16*)(ws + 201326592);             // [192MB, +1MB)
    _Float16*  xrf     = (_Float16*)(ws + 202375168);             // [193MB, +1MB)
    int*       auxcand = (int*)(ws + 201326592);                  // aliases xhf (dead after GEMM), 192KB
    int*       rec32_i = (int*)(ws + 201326592 + 262144);         // 64KB
    float*     rec32_v = (float*)(ws + 201326592 + 327680);       // 64KB
    int*       sel_idx = (int*)(ws + 203423744);                  // [194MB, +256KB)
    float*     sel_val = (float*)(ws + 203685888);                // +256KB

    float* out_recon  = out;
    float* out_multik = out + 524288;
    float* out_mat0   = out + 1048576;
    float* out_mat1   = out + 1572864;
    float* out_tidx   = out + 2097152;
    float* out_tval   = out + 2097152 + 16384;
    float* out_aidx   = out + 2097152 + 32768;
    float* out_aval   = out + 2097152 + 32768 + 32768;

    split_x_k<<<dim3(512), dim3(256), 0, stream>>>(x, ib, xhf, xrf);
    split_w_k<<<dim3(32768), dim3(256), 0, stream>>>(wenc, whf, wrf);
    enc_mfma<<<dim3(2048), dim3(256), 0, stream>>>(xhf, xrf, whf, wrf, nb, preact);
    tr_k<<<dim3(1024, 32), dim3(32, 8), 0, stream>>>(wdec, wdt);   // after enc (wdt aliases W splits)
    select_both<<<dim3(512), dim3(1024), 0, stream>>>(preact, steps, sel_idx, sel_val, auxcand);
    resolve_k<<<dim3(512), dim3(256), 0, stream>>>(
        x, ib, wenc, nb, sel_idx, auxcand, rec32_i, rec32_v,
        out_tidx, out_tval, out_aidx, out_aval);
    dec_k<<<dim3(512), dim3(256), 0, stream>>>(
        wdt, sel_idx, sel_val, rec32_i, rec32_v, ib,
        out_recon, out_multik, out_mat0, out_mat1);
}

// Round 6
// 591.509 us; speedup vs baseline: 1.4014x; 1.0233x over previous
//
#include <hip/hip_runtime.h>
#include <stdint.h>

#define B_ 512
#define D_ 1024
#define M_ 32768

typedef _Float16 half8 __attribute__((ext_vector_type(8)));
typedef _Float16 half4 __attribute__((ext_vector_type(4)));
typedef float f32x4 __attribute__((ext_vector_type(4)));

// ---------- sortable key helpers (monotonic float <-> u32) ----------
__device__ __forceinline__ unsigned f2k(float f) {
    unsigned b = __float_as_uint(f);
    return (b & 0x80000000u) ? ~b : (b | 0x80000000u);
}
__device__ __forceinline__ float k2f(unsigned k) {
    unsigned b = (k & 0x80000000u) ? (k & 0x7FFFFFFFu) : ~k;
    return __uint_as_float(b);
}
// monotonic double -> u64 key
__device__ __forceinline__ unsigned long long d2k(double d) {
    unsigned long long b = (unsigned long long)__double_as_longlong(d);
    return (b & 0x8000000000000000ull) ? ~b : (b | 0x8000000000000000ull);
}

// ---------- async global->LDS (16B per lane, wave-uniform base + lane*16) ----------
__device__ __forceinline__ void gld16(const void* g, void* l) {
    __builtin_amdgcn_global_load_lds(
        (__attribute__((address_space(1))) void*)(uintptr_t)g,
        (__attribute__((address_space(3))) void*)(unsigned)(uintptr_t)l,
        16, 0, 0);
}

// ---------- split x: xc = (x - ib) * 2048 -> fp16 hi + fp16 residual*2048 ----------
__global__ __launch_bounds__(256) void split_x_k(
    const float* __restrict__ x, const float* __restrict__ ib,
    _Float16* __restrict__ xh, _Float16* __restrict__ xr)
{
    int i = blockIdx.x * 256 + threadIdx.x;   // float4 index, 131072 total
    float4 v = ((const float4*)x)[i];
    float4 bb = ((const float4*)ib)[i & 255];
    float a0 = (v.x - bb.x) * 2048.0f;
    float a1 = (v.y - bb.y) * 2048.0f;
    float a2 = (v.z - bb.z) * 2048.0f;
    float a3 = (v.w - bb.w) * 2048.0f;
    _Float16 h0 = (_Float16)a0, h1 = (_Float16)a1, h2 = (_Float16)a2, h3 = (_Float16)a3;
    _Float16 r0 = (_Float16)((a0 - (float)h0) * 2048.0f);
    _Float16 r1 = (_Float16)((a1 - (float)h1) * 2048.0f);
    _Float16 r2 = (_Float16)((a2 - (float)h2) * 2048.0f);
    _Float16 r3 = (_Float16)((a3 - (float)h3) * 2048.0f);
    half4 hv = {h0, h1, h2, h3};
    half4 rv = {r0, r1, r2, r3};
    ((half4*)xh)[i] = hv;
    ((half4*)xr)[i] = rv;
}

// ---------- encoder GEMM via MFMA fp16, double-word split ----------
// Round-6: split_w fused away. B (W_enc) staged fp32 -> regs -> convert ->
// swizzled ds_write (T14 issue-early/write-late). The convert replicates the
// old split_w_k ops exactly; MFMA order unchanged -> bit-identical output.
// asm barriers pin VMEM issue order so vmcnt(4) drains {A(k+1), B(k+2)}
// while A(k+2) stays in flight (never drain-to-0 mid-loop).
__global__ __launch_bounds__(256, 3) void enc_mfma(
    const _Float16* __restrict__ xhf, const _Float16* __restrict__ xrf,
    const float* __restrict__ wenc, const float* __restrict__ nb,
    float* __restrict__ preact)
{
    __shared__ alignas(16) _Float16 lA[2][2][128 * 32];   // 8 KB per [s][hr]
    __shared__ alignas(16) _Float16 lB[2][2][64 * 32];    // 4 KB per [s][hr]

    const int tid = threadIdx.x;
    const int lane = tid & 63;
    const int wv = tid >> 6;
    const int wvr = wv >> 1;          // 0..1 -> M half (64 rows)
    const int wvc = wv & 1;           // 0..1 -> N half (32 cols)

    // XCD swizzle: 2048 blocks; xcd = bid&7 owns 64 consecutive j-tiles;
    // a j-tile's 4 i-blocks are temporally adjacent on the same XCD.
    const int bid = blockIdx.x;
    const int lb = bid >> 3;                      // [0,256)
    const int j0 = ((bid & 7) * 64 + (lb >> 2)) * 64;
    const int i0 = (lb & 3) * 128;

    const int ln15 = lane & 15;
    const int kq = (lane >> 4) * 8;   // half index of 16B chunk within 64B row

    f32x4 acc1[4][2], acc2[4][2];
#pragma unroll
    for (int r = 0; r < 4; ++r)
#pragma unroll
        for (int c = 0; c < 2; ++c) {
            acc1[r][c] = (f32x4){0.f, 0.f, 0.f, 0.f};
            acc2[r][c] = (f32x4){0.f, 0.f, 0.f, 0.f};
        }

    // A staging (gld16): 2 rounds of 4KB each
    const int o0 = tid * 16;                // [0,4096)
    const int o1 = o0 + 4096;               // [4096,8192)
    const int rA0 = o0 >> 6, rA1 = o1 >> 6; // [0,64), [64,128)
    const int cA0s = (o0 & 63) ^ (((rA0 >> 1) & 3) << 4);
    const int cA1s = (o1 & 63) ^ (((rA1 >> 1) & 3) << 4);

    // B staging (reg): thread -> (row rW, floats [c8, c8+8))
    const int rW = tid >> 2;                 // [0,64)
    const int c8 = (tid & 3) * 8;            // half/float index within 32-wide k
    const int c8s = c8 ^ (((rW >> 1) & 3) << 3);   // swizzled half index

    const int rowA = wvr * 64 + ln15;
    const int rowB = wvc * 32 + ln15;

#define STAGEA(k0, s)                                                                      \
    do {                                                                                   \
        gld16((const char*)(xhf + (size_t)(i0 + rA0) * 1024 + (k0)) + cA0s, (char*)lA[s][0] + o0); \
        gld16((const char*)(xhf + (size_t)(i0 + rA1) * 1024 + (k0)) + cA1s, (char*)lA[s][0] + o1); \
        gld16((const char*)(xrf + (size_t)(i0 + rA0) * 1024 + (k0)) + cA0s, (char*)lA[s][1] + o0); \
        gld16((const char*)(xrf + (size_t)(i0 + rA1) * 1024 + (k0)) + cA1s, (char*)lA[s][1] + o1); \
    } while (0)

#define LOADB(k0)                                                                          \
    do {                                                                                   \
        const float* wp = wenc + (size_t)(j0 + rW) * 1024 + (k0) + c8;                     \
        wv0 = *(const float4*)wp;                                                          \
        wv1 = *(const float4*)(wp + 4);                                                    \
    } while (0)

#define CVT1(idx, f)                                                                       \
    do { float a_ = (f) * 2048.0f; _Float16 h_ = (_Float16)a_;                             \
         bh[idx] = h_; br[idx] = (_Float16)((a_ - (float)h_) * 2048.0f); } while (0)

#define WRITEB(s)                                                                          \
    do {                                                                                   \
        half8 bh, br;                                                                      \
        CVT1(0, wv0.x); CVT1(1, wv0.y); CVT1(2, wv0.z); CVT1(3, wv0.w);                    \
        CVT1(4, wv1.x); CVT1(5, wv1.y); CVT1(6, wv1.z); CVT1(7, wv1.w);                    \
        *(half8*)&lB[s][0][rW * 32 + c8s] = bh;                                            \
        *(half8*)&lB[s][1][rW * 32 + c8s] = br;                                            \
    } while (0)

    float4 wv0, wv1;
    // ---- prologue: tiles 0,1 ----
    LOADB(0);
    asm volatile("s_waitcnt vmcnt(0)" ::: "memory");
    WRITEB(0);
    STAGEA(0, 0);
    LOADB(32);
    STAGEA(32, 1);
    asm volatile("s_waitcnt vmcnt(4)" ::: "memory");   // drains A(0) + B(32) regs; A(32) flying
    WRITEB(1);
    asm volatile("s_waitcnt lgkmcnt(0)" ::: "memory");
    __builtin_amdgcn_s_barrier();

    int cur = 0;
    for (int k0 = 0; k0 < 1024; k0 += 32) {
        // phase A: issue B reg-loads for tile k+2 (fly under MFMA)
        if (k0 + 64 < 1024) LOADB(k0 + 64);

        // phase B: frag reads (cur) + MFMA
        half8 aH[4], aR[4], bH[2], bR[2];
#pragma unroll
        for (int r = 0; r < 4; ++r) {
            const int ra = rowA + r * 16;
            const int ka = kq ^ (((ra >> 1) & 3) << 3);
            aH[r] = *(const half8*)&lA[cur][0][ra * 32 + ka];
            aR[r] = *(const half8*)&lA[cur][1][ra * 32 + ka];
        }
#pragma unroll
        for (int c = 0; c < 2; ++c) {
            const int rb = rowB + c * 16;
            const int kb = kq ^ (((rb >> 1) & 3) << 3);
            bH[c] = *(const half8*)&lB[cur][0][rb * 32 + kb];
            bR[c] = *(const half8*)&lB[cur][1][rb * 32 + kb];
        }
#pragma unroll
        for (int r = 0; r < 4; ++r)
#pragma unroll
            for (int c = 0; c < 2; ++c) {
                acc1[r][c] = __builtin_amdgcn_mfma_f32_16x16x32_f16(aH[r], bH[c], acc1[r][c], 0, 0, 0);
                acc2[r][c] = __builtin_amdgcn_mfma_f32_16x16x32_f16(aH[r], bR[c], acc2[r][c], 0, 0, 0);
                acc2[r][c] = __builtin_amdgcn_mfma_f32_16x16x32_f16(aR[r], bH[c], acc2[r][c], 0, 0, 0);
            }

        if (k0 + 32 < 1024) {
            // barrier1: all waves done reading buf[cur]
            asm volatile("s_waitcnt lgkmcnt(0)" ::: "memory");
            __builtin_amdgcn_s_barrier();

            // phase C: restage cur with tile k+2
            if (k0 + 64 < 1024) {
                STAGEA(k0 + 64, cur);                              // +4 glds (order pinned by barriers)
                asm volatile("s_waitcnt vmcnt(4)" ::: "memory");   // drain A(k+1) glds + B(k+2) regs
                WRITEB(cur);                                       // convert + swizzled ds_write
            } else {
                asm volatile("s_waitcnt vmcnt(0)" ::: "memory");   // tail: drain A(k+1)
            }
            asm volatile("s_waitcnt lgkmcnt(0)" ::: "memory");
            __builtin_amdgcn_s_barrier();                          // buf[cur^1] ready for all
        }
        cur ^= 1;
    }
#undef STAGEA
#undef LOADB
#undef CVT1
#undef WRITEB

    const float s1 = 0x1p-22f, s2 = 0x1p-33f;
#pragma unroll
    for (int c = 0; c < 2; ++c) {
        int n = j0 + wvc * 32 + c * 16 + ln15;
        float nbv = nb[n];
#pragma unroll
        for (int r = 0; r < 4; ++r) {
            int mb = i0 + wvr * 64 + r * 16 + (lane >> 4) * 4;
#pragma unroll
            for (int e = 0; e < 4; ++e)
                preact[(size_t)(mb + e) * M_ + n] = acc1[r][c][e] * s1 + acc2[r][c][e] * s2 + nbv;
        }
    }
}

// ---------- transpose W_dec [1024][32768] -> wdt [32768][1024] ----------
__global__ __launch_bounds__(256) void tr_k(const float* __restrict__ wdec,
                                            float* __restrict__ wdt)
{
    __shared__ float tile[32][33];
    int tx = threadIdx.x, ty = threadIdx.y;
    int x0 = blockIdx.x * 32;
    int y0 = blockIdx.y * 32;
#pragma unroll
    for (int j = 0; j < 32; j += 8)
        tile[ty + j][tx] = wdec[(size_t)(y0 + ty + j) * M_ + x0 + tx];
    __syncthreads();
#pragma unroll
    for (int j = 0; j < 32; j += 8)
        wdt[(size_t)(x0 + ty + j) * D_ + y0 + tx] = tile[tx][ty + j];
}

// ---------- fused dual top-k select (1024 thr, single pass, reg value cache) ----------
// Round-6: bitonic stages with j<64 are intra-wave (lane i and i^j share a
// 64-chunk) -> wave-lockstep + lgkmcnt(0) replaces __syncthreads there.
__global__ __launch_bounds__(1024, 4) void select_both(
    const float* __restrict__ preact, const int* __restrict__ steps,
    int* __restrict__ sel_idx, float* __restrict__ sel_val,
    int* __restrict__ auxcand)
{
    __shared__ unsigned histU[4096];
    __shared__ unsigned histM[4096];
    __shared__ unsigned coarseU[256];
    __shared__ unsigned coarseM[256];
    __shared__ unsigned long long candU[512];
    __shared__ unsigned long long candM[512];
    __shared__ unsigned cntU, cntM, thrU, thrM, cbU, cbM, cumU, cumM;

    const int t = threadIdx.x;
    const int b = blockIdx.x;
    const float* row = preact + (size_t)b * M_;

    for (int i = t; i < 4096; i += 1024) { histU[i] = 0; histM[i] = 0; }
    if (t < 512) { candU[t] = 0ULL; candM[t] = 0ULL; }
    if (t == 0) { cntU = 0; cntM = 0; }
    __syncthreads();

    // ---- dead mask ----
    unsigned deadmask = 0;
#pragma unroll
    for (int p = 0; p < 8; ++p) {
        int i = t + p * 1024;                     // int4 / float4 index
        int4 sv = ((const int4*)steps)[i];
        unsigned mbits = 0;
        if (sv.x + 1 > 256) mbits |= 1u;
        if (sv.y + 1 > 256) mbits |= 2u;
        if (sv.z + 1 > 256) mbits |= 4u;
        if (sv.w + 1 > 256) mbits |= 8u;
        deadmask |= mbits << (p * 4);
    }

    // ---- single memory pass: load row into registers + histogram ----
    float4 v[8];
#pragma unroll
    for (int p = 0; p < 8; ++p) {
        int i = t + p * 1024;
        v[p] = ((const float4*)row)[i];
        unsigned k0 = f2k(v[p].x) >> 20;
        unsigned k1 = f2k(v[p].y) >> 20;
        unsigned k2 = f2k(v[p].z) >> 20;
        unsigned k3 = f2k(v[p].w) >> 20;
        atomicAdd(&histU[k0], 1u);
        atomicAdd(&histU[k1], 1u);
        atomicAdd(&histU[k2], 1u);
        atomicAdd(&histU[k3], 1u);
        unsigned dm = deadmask >> (p * 4);
        if (dm & 1u) atomicAdd(&histM[k0], 1u);
        if (dm & 2u) atomicAdd(&histM[k1], 1u);
        if (dm & 4u) atomicAdd(&histM[k2], 1u);
        if (dm & 8u) atomicAdd(&histM[k3], 1u);
    }
    __syncthreads();

    // ---- coarse sums (U by threads 0-255, M by 256-511) ----
    if (t < 256) {
        unsigned s = 0;
#pragma unroll
        for (int j = 0; j < 16; ++j) s += histU[t * 16 + j];
        coarseU[t] = s;
    } else if (t < 512) {
        int c = t - 256;
        unsigned s = 0;
#pragma unroll
        for (int j = 0; j < 16; ++j) s += histM[c * 16 + j];
        coarseM[c] = s;
    }
    __syncthreads();

    // ---- joint Hillis-Steele suffix scan over both coarse arrays ----
    for (int off = 1; off < 256; off <<= 1) {
        unsigned xv = 0;
        if (t < 256)      xv = coarseU[t] + (t + off < 256 ? coarseU[t + off] : 0u);
        else if (t < 512) { int c = t - 256; xv = coarseM[c] + (c + off < 256 ? coarseM[c + off] : 0u); }
        __syncthreads();
        if (t < 256)      coarseU[t] = xv;
        else if (t < 512) coarseM[t - 256] = xv;
        __syncthreads();
    }

    // ---- find crossing bins (suffix >= K boundary) ----
    if (t < 256) {
        unsigned S = coarseU[t];
        unsigned Sn = (t < 255) ? coarseU[t + 1] : 0u;
        if (S >= 128u && (t == 255 || Sn < 128u)) { cbU = (unsigned)t; cumU = Sn; }
    } else if (t < 512) {
        int c = t - 256;
        unsigned S = coarseM[c];
        unsigned Sn = (c < 255) ? coarseM[c + 1] : 0u;
        if (S >= 64u && (c == 255 || Sn < 64u)) { cbM = (unsigned)c; cumM = Sn; }
        if (c == 0 && S < 64u) { cbM = 0u; cumM = Sn; }   // degenerate: <64 masked total
    }
    __syncthreads();

    // ---- fine scans (t==0 for U, t==64 for M run concurrently) ----
    if (t == 0) {
        unsigned cum = cumU;
        int base = (int)cbU * 16, tb = base;
        for (int f = base + 15; f >= base; --f) {
            unsigned h = histU[f];
            if (cum + h >= 128u) { tb = f; break; }
            cum += h;
        }
        thrU = (unsigned)tb;
    }
    if (t == 64) {
        unsigned cum = cumM;
        int base = (int)cbM * 16, tb = base;
        for (int f = base + 15; f >= base; --f) {
            unsigned h = histM[f];
            if (cum + h >= 64u) { tb = f; break; }
            cum += h;
        }
        thrM = (unsigned)(tb > 0 ? tb - 1 : 0);   // one extra bin: margin for top-96 superset
    }
    __syncthreads();

    const unsigned TU = thrU, TM = thrM;

    // ---- candidate collection straight from registers ----
#pragma unroll
    for (int p = 0; p < 8; ++p) {
        int i = t + p * 1024;
#pragma unroll
        for (int e = 0; e < 4; ++e) {
            float val = (e == 0) ? v[p].x : (e == 1) ? v[p].y : (e == 2) ? v[p].z : v[p].w;
            unsigned key = f2k(val);
            int m = i * 4 + e;
            if ((key >> 20) >= TU) {
                unsigned pz = atomicAdd(&cntU, 1u);
                if (pz < 512u) candU[pz] = ((unsigned long long)key << 32) | (unsigned)(~m);
            }
            if (((deadmask >> (p * 4 + e)) & 1u) && (key >> 20) >= TM) {
                unsigned pz = atomicAdd(&cntM, 1u);
                if (pz < 512u) candM[pz] = ((unsigned long long)key << 32) | (unsigned)(~m);
            }
        }
    }
    __syncthreads();

    // ---- bitonic sort: threads 0-511 -> candU, 512-1023 -> candM ----
    // j<64 exchanges stay within one wave's 64-chunk: lgkmcnt(0) suffices.
    {
        unsigned long long* arr = (t < 512) ? candU : candM;
        const unsigned i = (unsigned)t & 511u;
        for (unsigned kk = 2; kk <= 512; kk <<= 1) {
            for (unsigned j = kk >> 1; j > 0; j >>= 1) {
                unsigned ixj = i ^ j;
                if (ixj > i) {
                    bool desc = ((i & kk) == 0);
                    unsigned long long a = arr[i], c = arr[ixj];
                    if (desc ? (a < c) : (a > c)) { arr[i] = c; arr[ixj] = a; }
                }
                unsigned nj = (j > 1) ? (j >> 1) : ((kk << 1) <= 512u ? kk : 0u);
                if (j >= 64 || nj >= 64) __syncthreads();
                else asm volatile("s_waitcnt lgkmcnt(0)" ::: "memory");
            }
        }
    }
    __syncthreads();   // candM written by waves 8-15, read below by waves 0-1

    if (t < 128) {
        unsigned long long c = candU[t];
        unsigned m = ~(unsigned)c;
        float vv = k2f((unsigned)(c >> 32));
        sel_idx[b * 128 + t] = (int)m;
        sel_val[b * 128 + t] = vv > 0.f ? vv : 0.f;
    }
    if (t < 96) {
        unsigned long long c = candM[t];
        auxcand[b * 96 + t] = c ? (int)(~(unsigned)c) : -1;
    }
}

// ---------- exact resolve in FLOAT64: recompute candidate dots at f64 precision ----------
__global__ __launch_bounds__(256) void resolve_k(
    const float* __restrict__ x, const float* __restrict__ ib,
    const float* __restrict__ wenc, const float* __restrict__ nb,
    const int* __restrict__ sel_idx, const int* __restrict__ auxcand,
    int* __restrict__ rec32_idx, float* __restrict__ rec32_val,
    float* __restrict__ out_tidx, float* __restrict__ out_tval,
    float* __restrict__ out_aidx, float* __restrict__ out_aval)
{
    __shared__ double xcs[1024];
    __shared__ unsigned long long kU[64];
    __shared__ unsigned long long kM[128];
    __shared__ float vU[64];
    __shared__ float vM[128];

    const int b = blockIdx.x, t = threadIdx.x;
    for (int d = t; d < 1024; d += 256)
        xcs[d] = (double)x[(size_t)b * 1024 + d] - (double)ib[d];
    if (t < 64)  { kU[t] = 0ULL; vU[t] = 0.f; }
    if (t < 128) { kM[t] = 0ULL; vM[t] = 0.f; }
    __syncthreads();

    int m = -1;
    if (t < 64) m = sel_idx[b * 128 + t];
    else if (t >= 64 && t < 160) m = auxcand[b * 96 + (t - 64)];
    if (m >= 0) {
        const float* w = wenc + (size_t)m * 1024;
        double a0 = 0.0, a1 = 0.0, a2 = 0.0, a3 = 0.0;
        for (int d = 0; d < 1024; d += 4) {
            float4 wv = *(const float4*)(w + d);
            a0 = fma((double)wv.x, xcs[d + 0], a0);
            a1 = fma((double)wv.y, xcs[d + 1], a1);
            a2 = fma((double)wv.z, xcs[d + 2], a2);
            a3 = fma((double)wv.w, xcs[d + 3], a3);
        }
        double v = ((a0 + a1) + (a2 + a3)) + (double)nb[m];
        unsigned long long key = (d2k(v) & 0xFFFFFFFFFFFF0000ull)
                               | (unsigned long long)((~(unsigned)m) & 0xFFFFu);
        float vf = (float)v;
        if (t < 64) { kU[t] = key; vU[t] = vf; }
        else        { kM[t - 64] = key; vM[t - 64] = vf; }
    }
    __syncthreads();

    for (unsigned kk = 2; kk <= 128; kk <<= 1) {
        for (unsigned j = kk >> 1; j > 0; j >>= 1) {
            unsigned i = (unsigned)t, ixj = i ^ j;
            if (kk <= 64 && i < 64 && ixj > i) {
                bool desc = ((i & kk) == 0);
                unsigned long long a = kU[i], c = kU[ixj];
                if (desc ? (a < c) : (a > c)) {
                    kU[i] = c; kU[ixj] = a;
                    float fa = vU[i]; vU[i] = vU[ixj]; vU[ixj] = fa;
                }
            }
            if (i < 128 && ixj > i) {
                bool desc = ((i & kk) == 0);
                unsigned long long a = kM[i], c = kM[ixj];
                if (desc ? (a < c) : (a > c)) {
                    kM[i] = c; kM[ixj] = a;
                    float fa = vM[i]; vM[i] = vM[ixj]; vM[ixj] = fa;
                }
            }
            __syncthreads();
        }
    }

    if (t < 32) {
        unsigned mm = (~(unsigned)kU[t]) & 0xFFFFu;
        float v = vU[t];
        float rv = v > 0.f ? v : 0.f;
        rec32_idx[b * 32 + t] = (int)mm;
        rec32_val[b * 32 + t] = rv;
        out_tidx[b * 32 + t] = (float)mm;
        out_tval[b * 32 + t] = rv;
    }
    if (t < 64) {
        unsigned mm = (~(unsigned)kM[t]) & 0xFFFFu;
        float v = vM[t];
        out_aidx[b * 64 + t] = (float)mm;
        out_aval[b * 64 + t] = v > 0.f ? v : 0.f;
    }
}

// ---------- sparse decoder: multik from MFMA top-128, recon/mat from exact top-32 ----------
__global__ __launch_bounds__(256) void dec_k(
    const float* __restrict__ wdt, const int* __restrict__ sel_idx,
    const float* __restrict__ sel_val, const int* __restrict__ rec32_idx,
    const float* __restrict__ rec32_val, const float* __restrict__ ib,
    float* __restrict__ o_recon, float* __restrict__ o_multik,
    float* __restrict__ o_mat0, float* __restrict__ o_mat1)
{
    __shared__ int sidx[128];
    __shared__ float sval[128];
    __shared__ int ridx[32];
    __shared__ float rval[32];
    const int b = blockIdx.x, t = threadIdx.x;
    if (t < 128) { sidx[t] = sel_idx[b * 128 + t]; sval[t] = sel_val[b * 128 + t]; }
    if (t < 32)  { ridx[t] = rec32_idx[b * 32 + t]; rval[t] = rec32_val[b * 32 + t]; }
    __syncthreads();

    const int d = t * 4;
    float4 bias = *(const float4*)(ib + d);
    float4 mul = bias, rec = bias, m0 = bias, m1 = bias;

    for (int k = 0; k < 128; ++k) {
        float v = sval[k];
        float4 w = *(const float4*)(wdt + (size_t)sidx[k] * D_ + d);
        mul.x += v * w.x; mul.y += v * w.y; mul.z += v * w.z; mul.w += v * w.w;
    }
    for (int k = 0; k < 32; ++k) {
        int idx = ridx[k];
        float v = rval[k];
        float4 w = *(const float4*)(wdt + (size_t)idx * D_ + d);
        rec.x += v * w.x; rec.y += v * w.y; rec.z += v * w.z; rec.w += v * w.w;
        if (idx < 16384) {
            m1.x += v * w.x; m1.y += v * w.y; m1.z += v * w.z; m1.w += v * w.w;
            if (idx < 4096) {
                m0.x += v * w.x; m0.y += v * w.y; m0.z += v * w.z; m0.w += v * w.w;
            }
        }
    }
    size_t o = (size_t)b * D_ + d;
    *(float4*)(o_recon + o)  = rec;
    *(float4*)(o_multik + o) = mul;
    *(float4*)(o_mat0 + o)   = m0;
    *(float4*)(o_mat1 + o)   = m1;
}

extern "C" void kernel_launch(void* const* d_in, const int* in_sizes, int n_in,
                              void* d_out, int out_size, void* d_ws, size_t ws_size,
                              hipStream_t stream)
{
    const float* x     = (const float*)d_in[0];
    const float* wenc  = (const float*)d_in[1];
    const float* wdec  = (const float*)d_in[2];
    const float* ib    = (const float*)d_in[3];
    const float* nb    = (const float*)d_in[4];
    const int*   steps = (const int*)d_in[5];
    float* out = (float*)d_out;

    char* ws = (char*)d_ws;
    float*     preact  = (float*)ws;                              // [0, 64MB)
    float*     wdt     = (float*)(ws + 67108864);                 // [64MB, 192MB)
    _Float16*  xhf     = (_Float16*)(ws + 201326592);             // [192MB, +1MB)
    _Float16*  xrf     = (_Float16*)(ws + 202375168);             // [193MB, +1MB)
    int*       auxcand = (int*)(ws + 201326592 + 2097152);        // 192KB (after xr)
    int*       rec32_i = (int*)(ws + 201326592 + 2097152 + 262144);
    float*     rec32_v = (float*)(ws + 201326592 + 2097152 + 327680);
    int*       sel_idx = (int*)(ws + 206569472);                  // +256KB
    float*     sel_val = (float*)(ws + 206831616);                // +256KB

    float* out_recon  = out;
    float* out_multik = out + 524288;
    float* out_mat0   = out + 1048576;
    float* out_mat1   = out + 1572864;
    float* out_tidx   = out + 2097152;
    float* out_tval   = out + 2097152 + 16384;
    float* out_aidx   = out + 2097152 + 32768;
    float* out_aval   = out + 2097152 + 32768 + 32768;

    split_x_k<<<dim3(512), dim3(256), 0, stream>>>(x, ib, xhf, xrf);
    enc_mfma<<<dim3(2048), dim3(256), 0, stream>>>(xhf, xrf, wenc, nb, preact);
    tr_k<<<dim3(1024, 32), dim3(32, 8), 0, stream>>>(wdec, wdt);
    select_both<<<dim3(512), dim3(1024), 0, stream>>>(preact, steps, sel_idx, sel_val, auxcand);
    resolve_k<<<dim3(512), dim3(256), 0, stream>>>(
        x, ib, wenc, nb, sel_idx, auxcand, rec32_i, rec32_v,
        out_tidx, out_tval, out_aidx, out_aval);
    dec_k<<<dim3(512), dim3(256), 0, stream>>>(
        wdt, sel_idx, sel_val, rec32_i, rec32_v, ib,
        out_recon, out_multik, out_mat0, out_mat1);
}

// Round 7
// 566.793 us; speedup vs baseline: 1.4625x; 1.0436x over previous
//
#include <hip/hip_runtime.h>
#include <stdint.h>

#define B_ 512
#define D_ 1024
#define M_ 32768

typedef _Float16 half8 __attribute__((ext_vector_type(8)));
typedef _Float16 half4 __attribute__((ext_vector_type(4)));
typedef float f32x4 __attribute__((ext_vector_type(4)));

// ---------- sortable key helpers (monotonic float <-> u32) ----------
__device__ __forceinline__ unsigned f2k(float f) {
    unsigned b = __float_as_uint(f);
    return (b & 0x80000000u) ? ~b : (b | 0x80000000u);
}
__device__ __forceinline__ float k2f(unsigned k) {
    unsigned b = (k & 0x80000000u) ? (k & 0x7FFFFFFFu) : ~k;
    return __uint_as_float(b);
}
// monotonic double -> u64 key
__device__ __forceinline__ unsigned long long d2k(double d) {
    unsigned long long b = (unsigned long long)__double_as_longlong(d);
    return (b & 0x8000000000000000ull) ? ~b : (b | 0x8000000000000000ull);
}

// ---------- async global->LDS (16B per lane, wave-uniform base + lane*16) ----------
__device__ __forceinline__ void gld16(const void* g, void* l) {
    __builtin_amdgcn_global_load_lds(
        (__attribute__((address_space(1))) void*)(uintptr_t)g,
        (__attribute__((address_space(3))) void*)(unsigned)(uintptr_t)l,
        16, 0, 0);
}

// ---------- split x: xc = (x - ib) * 2048 -> fp16 hi only (residual term dropped) ----------
__global__ __launch_bounds__(256) void split_x_k(
    const float* __restrict__ x, const float* __restrict__ ib,
    _Float16* __restrict__ xh)
{
    int i = blockIdx.x * 256 + threadIdx.x;   // float4 index, 131072 total
    float4 v = ((const float4*)x)[i];
    float4 bb = ((const float4*)ib)[i & 255];
    float a0 = (v.x - bb.x) * 2048.0f;
    float a1 = (v.y - bb.y) * 2048.0f;
    float a2 = (v.z - bb.z) * 2048.0f;
    float a3 = (v.w - bb.w) * 2048.0f;
    half4 hv = {(_Float16)a0, (_Float16)a1, (_Float16)a2, (_Float16)a3};
    ((half4*)xh)[i] = hv;
}

// ---------- encoder GEMM via MFMA fp16 ----------
// Round-7: drop the A-residual MFMA (error ~1.3e-4 in preact, vs candidate
// margins ~0.04-0.12 and f64-exact resolve of all index outputs). 2 MFMAs per
// step (hi*hi + hi*resB), A staging halved (xh only), LDS 32KB, 4 blocks/CU.
// W_enc split fused in (fp32 -> regs -> convert -> swizzled ds_write).
__global__ __launch_bounds__(256, 4) void enc_mfma(
    const _Float16* __restrict__ xhf,
    const float* __restrict__ wenc, const float* __restrict__ nb,
    float* __restrict__ preact)
{
    __shared__ alignas(16) _Float16 lA[2][128 * 32];      // 8 KB per buf
    __shared__ alignas(16) _Float16 lB[2][2][64 * 32];    // 4 KB per [s][hr]

    const int tid = threadIdx.x;
    const int lane = tid & 63;
    const int wv = tid >> 6;
    const int wvr = wv >> 1;          // 0..1 -> M half (64 rows)
    const int wvc = wv & 1;           // 0..1 -> N half (32 cols)

    // XCD swizzle: 2048 blocks; xcd = bid&7 owns 64 consecutive j-tiles;
    // a j-tile's 4 i-blocks are temporally adjacent on the same XCD.
    const int bid = blockIdx.x;
    const int lb = bid >> 3;                      // [0,256)
    const int j0 = ((bid & 7) * 64 + (lb >> 2)) * 64;
    const int i0 = (lb & 3) * 128;

    const int ln15 = lane & 15;
    const int kq = (lane >> 4) * 8;   // half index of 16B chunk within 64B row

    f32x4 acc1[4][2], acc2[4][2];
#pragma unroll
    for (int r = 0; r < 4; ++r)
#pragma unroll
        for (int c = 0; c < 2; ++c) {
            acc1[r][c] = (f32x4){0.f, 0.f, 0.f, 0.f};
            acc2[r][c] = (f32x4){0.f, 0.f, 0.f, 0.f};
        }

    // A staging (gld16): 2 rounds of 4KB each
    const int o0 = tid * 16;                // [0,4096)
    const int o1 = o0 + 4096;               // [4096,8192)
    const int rA0 = o0 >> 6, rA1 = o1 >> 6; // [0,64), [64,128)
    const int cA0s = (o0 & 63) ^ (((rA0 >> 1) & 3) << 4);
    const int cA1s = (o1 & 63) ^ (((rA1 >> 1) & 3) << 4);

    // B staging (reg): thread -> (row rW, floats [c8, c8+8))
    const int rW = tid >> 2;                 // [0,64)
    const int c8 = (tid & 3) * 8;            // half/float index within 32-wide k
    const int c8s = c8 ^ (((rW >> 1) & 3) << 3);   // swizzled half index

    const int rowA = wvr * 64 + ln15;
    const int rowB = wvc * 32 + ln15;

#define STAGEA(k0, s)                                                                      \
    do {                                                                                   \
        gld16((const char*)(xhf + (size_t)(i0 + rA0) * 1024 + (k0)) + cA0s, (char*)lA[s] + o0); \
        gld16((const char*)(xhf + (size_t)(i0 + rA1) * 1024 + (k0)) + cA1s, (char*)lA[s] + o1); \
    } while (0)

#define LOADB(k0)                                                                          \
    do {                                                                                   \
        const float* wp = wenc + (size_t)(j0 + rW) * 1024 + (k0) + c8;                     \
        wv0 = *(const float4*)wp;                                                          \
        wv1 = *(const float4*)(wp + 4);                                                    \
    } while (0)

#define CVT1(idx, f)                                                                       \
    do { float a_ = (f) * 2048.0f; _Float16 h_ = (_Float16)a_;                             \
         bh[idx] = h_; br[idx] = (_Float16)((a_ - (float)h_) * 2048.0f); } while (0)

#define WRITEB(s)                                                                          \
    do {                                                                                   \
        half8 bh, br;                                                                      \
        CVT1(0, wv0.x); CVT1(1, wv0.y); CVT1(2, wv0.z); CVT1(3, wv0.w);                    \
        CVT1(4, wv1.x); CVT1(5, wv1.y); CVT1(6, wv1.z); CVT1(7, wv1.w);                    \
        *(half8*)&lB[s][0][rW * 32 + c8s] = bh;                                            \
        *(half8*)&lB[s][1][rW * 32 + c8s] = br;                                            \
    } while (0)

    float4 wv0, wv1;
    // ---- prologue: tiles 0,1 ----
    LOADB(0);
    asm volatile("s_waitcnt vmcnt(0)" ::: "memory");
    WRITEB(0);
    STAGEA(0, 0);
    LOADB(32);
    STAGEA(32, 1);
    asm volatile("s_waitcnt vmcnt(2)" ::: "memory");   // drains A(0)+B(32) regs; A(32) flying
    WRITEB(1);
    asm volatile("s_waitcnt lgkmcnt(0)" ::: "memory");
    __builtin_amdgcn_s_barrier();

    int cur = 0;
    for (int k0 = 0; k0 < 1024; k0 += 32) {
        // phase A: issue B reg-loads for tile k+2 (fly under MFMA)
        if (k0 + 64 < 1024) LOADB(k0 + 64);

        // phase B: frag reads (cur) + MFMA
        half8 aH[4], bH[2], bR[2];
#pragma unroll
        for (int r = 0; r < 4; ++r) {
            const int ra = rowA + r * 16;
            const int ka = kq ^ (((ra >> 1) & 3) << 3);
            aH[r] = *(const half8*)&lA[cur][ra * 32 + ka];
        }
#pragma unroll
        for (int c = 0; c < 2; ++c) {
            const int rb = rowB + c * 16;
            const int kb = kq ^ (((rb >> 1) & 3) << 3);
            bH[c] = *(const half8*)&lB[cur][0][rb * 32 + kb];
            bR[c] = *(const half8*)&lB[cur][1][rb * 32 + kb];
        }
#pragma unroll
        for (int r = 0; r < 4; ++r)
#pragma unroll
            for (int c = 0; c < 2; ++c) {
                acc1[r][c] = __builtin_amdgcn_mfma_f32_16x16x32_f16(aH[r], bH[c], acc1[r][c], 0, 0, 0);
                acc2[r][c] = __builtin_amdgcn_mfma_f32_16x16x32_f16(aH[r], bR[c], acc2[r][c], 0, 0, 0);
            }

        if (k0 + 32 < 1024) {
            // barrier1: all waves done reading buf[cur]
            asm volatile("s_waitcnt lgkmcnt(0)" ::: "memory");
            __builtin_amdgcn_s_barrier();

            // phase C: restage cur with tile k+2
            if (k0 + 64 < 1024) {
                STAGEA(k0 + 64, cur);                              // +2 glds (order pinned by barriers)
                asm volatile("s_waitcnt vmcnt(2)" ::: "memory");   // drain A(k+1) glds + B(k+2) regs
                WRITEB(cur);                                       // convert + swizzled ds_write
            } else {
                asm volatile("s_waitcnt vmcnt(0)" ::: "memory");   // tail: drain A(k+1)
            }
            asm volatile("s_waitcnt lgkmcnt(0)" ::: "memory");
            __builtin_amdgcn_s_barrier();                          // buf[cur^1] ready for all
        }
        cur ^= 1;
    }
#undef STAGEA
#undef LOADB
#undef CVT1
#undef WRITEB

    const float s1 = 0x1p-22f, s2 = 0x1p-33f;
#pragma unroll
    for (int c = 0; c < 2; ++c) {
        int n = j0 + wvc * 32 + c * 16 + ln15;
        float nbv = nb[n];
#pragma unroll
        for (int r = 0; r < 4; ++r) {
            int mb = i0 + wvr * 64 + r * 16 + (lane >> 4) * 4;
#pragma unroll
            for (int e = 0; e < 4; ++e)
                preact[(size_t)(mb + e) * M_ + n] = acc1[r][c][e] * s1 + acc2[r][c][e] * s2 + nbv;
        }
    }
}

// ---------- transpose W_dec [1024][32768] -> wdt [32768][1024] ----------
__global__ __launch_bounds__(256) void tr_k(const float* __restrict__ wdec,
                                            float* __restrict__ wdt)
{
    __shared__ float tile[32][33];
    int tx = threadIdx.x, ty = threadIdx.y;
    int x0 = blockIdx.x * 32;
    int y0 = blockIdx.y * 32;
#pragma unroll
    for (int j = 0; j < 32; j += 8)
        tile[ty + j][tx] = wdec[(size_t)(y0 + ty + j) * M_ + x0 + tx];
    __syncthreads();
#pragma unroll
    for (int j = 0; j < 32; j += 8)
        wdt[(size_t)(x0 + ty + j) * D_ + y0 + tx] = tile[tx][ty + j];
}

// ---------- fused dual top-k select (1024 thr, single pass, reg value cache) ----------
__global__ __launch_bounds__(1024, 4) void select_both(
    const float* __restrict__ preact, const int* __restrict__ steps,
    int* __restrict__ sel_idx, float* __restrict__ sel_val,
    int* __restrict__ auxcand)
{
    __shared__ unsigned histU[4096];
    __shared__ unsigned histM[4096];
    __shared__ unsigned coarseU[256];
    __shared__ unsigned coarseM[256];
    __shared__ unsigned long long candU[512];
    __shared__ unsigned long long candM[512];
    __shared__ unsigned cntU, cntM, thrU, thrM, cbU, cbM, cumU, cumM;

    const int t = threadIdx.x;
    const int b = blockIdx.x;
    const float* row = preact + (size_t)b * M_;

    for (int i = t; i < 4096; i += 1024) { histU[i] = 0; histM[i] = 0; }
    if (t < 512) { candU[t] = 0ULL; candM[t] = 0ULL; }
    if (t == 0) { cntU = 0; cntM = 0; }
    __syncthreads();

    // ---- dead mask ----
    unsigned deadmask = 0;
#pragma unroll
    for (int p = 0; p < 8; ++p) {
        int i = t + p * 1024;                     // int4 / float4 index
        int4 sv = ((const int4*)steps)[i];
        unsigned mbits = 0;
        if (sv.x + 1 > 256) mbits |= 1u;
        if (sv.y + 1 > 256) mbits |= 2u;
        if (sv.z + 1 > 256) mbits |= 4u;
        if (sv.w + 1 > 256) mbits |= 8u;
        deadmask |= mbits << (p * 4);
    }

    // ---- single memory pass: load row into registers + histogram ----
    float4 v[8];
#pragma unroll
    for (int p = 0; p < 8; ++p) {
        int i = t + p * 1024;
        v[p] = ((const float4*)row)[i];
        unsigned k0 = f2k(v[p].x) >> 20;
        unsigned k1 = f2k(v[p].y) >> 20;
        unsigned k2 = f2k(v[p].z) >> 20;
        unsigned k3 = f2k(v[p].w) >> 20;
        atomicAdd(&histU[k0], 1u);
        atomicAdd(&histU[k1], 1u);
        atomicAdd(&histU[k2], 1u);
        atomicAdd(&histU[k3], 1u);
        unsigned dm = deadmask >> (p * 4);
        if (dm & 1u) atomicAdd(&histM[k0], 1u);
        if (dm & 2u) atomicAdd(&histM[k1], 1u);
        if (dm & 4u) atomicAdd(&histM[k2], 1u);
        if (dm & 8u) atomicAdd(&histM[k3], 1u);
    }
    __syncthreads();

    // ---- coarse sums (U by threads 0-255, M by 256-511) ----
    if (t < 256) {
        unsigned s = 0;
#pragma unroll
        for (int j = 0; j < 16; ++j) s += histU[t * 16 + j];
        coarseU[t] = s;
    } else if (t < 512) {
        int c = t - 256;
        unsigned s = 0;
#pragma unroll
        for (int j = 0; j < 16; ++j) s += histM[c * 16 + j];
        coarseM[c] = s;
    }
    __syncthreads();

    // ---- joint Hillis-Steele suffix scan over both coarse arrays ----
    for (int off = 1; off < 256; off <<= 1) {
        unsigned xv = 0;
        if (t < 256)      xv = coarseU[t] + (t + off < 256 ? coarseU[t + off] : 0u);
        else if (t < 512) { int c = t - 256; xv = coarseM[c] + (c + off < 256 ? coarseM[c + off] : 0u); }
        __syncthreads();
        if (t < 256)      coarseU[t] = xv;
        else if (t < 512) coarseM[t - 256] = xv;
        __syncthreads();
    }

    // ---- find crossing bins (suffix >= K boundary) ----
    if (t < 256) {
        unsigned S = coarseU[t];
        unsigned Sn = (t < 255) ? coarseU[t + 1] : 0u;
        if (S >= 128u && (t == 255 || Sn < 128u)) { cbU = (unsigned)t; cumU = Sn; }
    } else if (t < 512) {
        int c = t - 256;
        unsigned S = coarseM[c];
        unsigned Sn = (c < 255) ? coarseM[c + 1] : 0u;
        if (S >= 64u && (c == 255 || Sn < 64u)) { cbM = (unsigned)c; cumM = Sn; }
        if (c == 0 && S < 64u) { cbM = 0u; cumM = Sn; }   // degenerate: <64 masked total
    }
    __syncthreads();

    // ---- fine scans (t==0 for U, t==64 for M run concurrently) ----
    if (t == 0) {
        unsigned cum = cumU;
        int base = (int)cbU * 16, tb = base;
        for (int f = base + 15; f >= base; --f) {
            unsigned h = histU[f];
            if (cum + h >= 128u) { tb = f; break; }
            cum += h;
        }
        thrU = (unsigned)tb;
    }
    if (t == 64) {
        unsigned cum = cumM;
        int base = (int)cbM * 16, tb = base;
        for (int f = base + 15; f >= base; --f) {
            unsigned h = histM[f];
            if (cum + h >= 64u) { tb = f; break; }
            cum += h;
        }
        thrM = (unsigned)(tb > 0 ? tb - 1 : 0);   // one extra bin: margin for top-96 superset
    }
    __syncthreads();

    const unsigned TU = thrU, TM = thrM;

    // ---- candidate collection straight from registers ----
#pragma unroll
    for (int p = 0; p < 8; ++p) {
        int i = t + p * 1024;
#pragma unroll
        for (int e = 0; e < 4; ++e) {
            float val = (e == 0) ? v[p].x : (e == 1) ? v[p].y : (e == 2) ? v[p].z : v[p].w;
            unsigned key = f2k(val);
            int m = i * 4 + e;
            if ((key >> 20) >= TU) {
                unsigned pz = atomicAdd(&cntU, 1u);
                if (pz < 512u) candU[pz] = ((unsigned long long)key << 32) | (unsigned)(~m);
            }
            if (((deadmask >> (p * 4 + e)) & 1u) && (key >> 20) >= TM) {
                unsigned pz = atomicAdd(&cntM, 1u);
                if (pz < 512u) candM[pz] = ((unsigned long long)key << 32) | (unsigned)(~m);
            }
        }
    }
    __syncthreads();

    // ---- bitonic sort: threads 0-511 -> candU, 512-1023 -> candM ----
    // j<64 exchanges stay within one wave's 64-chunk: lgkmcnt(0) suffices.
    {
        unsigned long long* arr = (t < 512) ? candU : candM;
        const unsigned i = (unsigned)t & 511u;
        for (unsigned kk = 2; kk <= 512; kk <<= 1) {
            for (unsigned j = kk >> 1; j > 0; j >>= 1) {
                unsigned ixj = i ^ j;
                if (ixj > i) {
                    bool desc = ((i & kk) == 0);
                    unsigned long long a = arr[i], c = arr[ixj];
                    if (desc ? (a < c) : (a > c)) { arr[i] = c; arr[ixj] = a; }
                }
                unsigned nj = (j > 1) ? (j >> 1) : ((kk << 1) <= 512u ? kk : 0u);
                if (j >= 64 || nj >= 64) __syncthreads();
                else asm volatile("s_waitcnt lgkmcnt(0)" ::: "memory");
            }
        }
    }
    __syncthreads();   // candM written by waves 8-15, read below by waves 0-1

    if (t < 128) {
        unsigned long long c = candU[t];
        unsigned m = ~(unsigned)c;
        float vv = k2f((unsigned)(c >> 32));
        sel_idx[b * 128 + t] = (int)m;
        sel_val[b * 128 + t] = vv > 0.f ? vv : 0.f;
    }
    if (t < 96) {
        unsigned long long c = candM[t];
        auxcand[b * 96 + t] = c ? (int)(~(unsigned)c) : -1;
    }
}

// ---------- exact resolve in FLOAT64: recompute candidate dots at f64 precision ----------
__global__ __launch_bounds__(256) void resolve_k(
    const float* __restrict__ x, const float* __restrict__ ib,
    const float* __restrict__ wenc, const float* __restrict__ nb,
    const int* __restrict__ sel_idx, const int* __restrict__ auxcand,
    int* __restrict__ rec32_idx, float* __restrict__ rec32_val,
    float* __restrict__ out_tidx, float* __restrict__ out_tval,
    float* __restrict__ out_aidx, float* __restrict__ out_aval)
{
    __shared__ double xcs[1024];
    __shared__ unsigned long long kU[64];
    __shared__ unsigned long long kM[128];
    __shared__ float vU[64];
    __shared__ float vM[128];

    const int b = blockIdx.x, t = threadIdx.x;
    for (int d = t; d < 1024; d += 256)
        xcs[d] = (double)x[(size_t)b * 1024 + d] - (double)ib[d];
    if (t < 64)  { kU[t] = 0ULL; vU[t] = 0.f; }
    if (t < 128) { kM[t] = 0ULL; vM[t] = 0.f; }
    __syncthreads();

    int m = -1;
    if (t < 64) m = sel_idx[b * 128 + t];
    else if (t >= 64 && t < 160) m = auxcand[b * 96 + (t - 64)];
    if (m >= 0) {
        const float* w = wenc + (size_t)m * 1024;
        double a0 = 0.0, a1 = 0.0, a2 = 0.0, a3 = 0.0;
        for (int d = 0; d < 1024; d += 4) {
            float4 wv = *(const float4*)(w + d);
            a0 = fma((double)wv.x, xcs[d + 0], a0);
            a1 = fma((double)wv.y, xcs[d + 1], a1);
            a2 = fma((double)wv.z, xcs[d + 2], a2);
            a3 = fma((double)wv.w, xcs[d + 3], a3);
        }
        double v = ((a0 + a1) + (a2 + a3)) + (double)nb[m];
        unsigned long long key = (d2k(v) & 0xFFFFFFFFFFFF0000ull)
                               | (unsigned long long)((~(unsigned)m) & 0xFFFFu);
        float vf = (float)v;
        if (t < 64) { kU[t] = key; vU[t] = vf; }
        else        { kM[t - 64] = key; vM[t - 64] = vf; }
    }
    __syncthreads();

    for (unsigned kk = 2; kk <= 128; kk <<= 1) {
        for (unsigned j = kk >> 1; j > 0; j >>= 1) {
            unsigned i = (unsigned)t, ixj = i ^ j;
            if (kk <= 64 && i < 64 && ixj > i) {
                bool desc = ((i & kk) == 0);
                unsigned long long a = kU[i], c = kU[ixj];
                if (desc ? (a < c) : (a > c)) {
                    kU[i] = c; kU[ixj] = a;
                    float fa = vU[i]; vU[i] = vU[ixj]; vU[ixj] = fa;
                }
            }
            if (i < 128 && ixj > i) {
                bool desc = ((i & kk) == 0);
                unsigned long long a = kM[i], c = kM[ixj];
                if (desc ? (a < c) : (a > c)) {
                    kM[i] = c; kM[ixj] = a;
                    float fa = vM[i]; vM[i] = vM[ixj]; vM[ixj] = fa;
                }
            }
            __syncthreads();
        }
    }

    if (t < 32) {
        unsigned mm = (~(unsigned)kU[t]) & 0xFFFFu;
        float v = vU[t];
        float rv = v > 0.f ? v : 0.f;
        rec32_idx[b * 32 + t] = (int)mm;
        rec32_val[b * 32 + t] = rv;
        out_tidx[b * 32 + t] = (float)mm;
        out_tval[b * 32 + t] = rv;
    }
    if (t < 64) {
        unsigned mm = (~(unsigned)kM[t]) & 0xFFFFu;
        float v = vM[t];
        out_aidx[b * 64 + t] = (float)mm;
        out_aval[b * 64 + t] = v > 0.f ? v : 0.f;
    }
}

// ---------- sparse decoder: multik from MFMA top-128, recon/mat from exact top-32 ----------
__global__ __launch_bounds__(256) void dec_k(
    const float* __restrict__ wdt, const int* __restrict__ sel_idx,
    const float* __restrict__ sel_val, const int* __restrict__ rec32_idx,
    const float* __restrict__ rec32_val, const float* __restrict__ ib,
    float* __restrict__ o_recon, float* __restrict__ o_multik,
    float* __restrict__ o_mat0, float* __restrict__ o_mat1)
{
    __shared__ int sidx[128];
    __shared__ float sval[128];
    __shared__ int ridx[32];
    __shared__ float rval[32];
    const int b = blockIdx.x, t = threadIdx.x;
    if (t < 128) { sidx[t] = sel_idx[b * 128 + t]; sval[t] = sel_val[b * 128 + t]; }
    if (t < 32)  { ridx[t] = rec32_idx[b * 32 + t]; rval[t] = rec32_val[b * 32 + t]; }
    __syncthreads();

    const int d = t * 4;
    float4 bias = *(const float4*)(ib + d);
    float4 mul = bias, rec = bias, m0 = bias, m1 = bias;

    for (int k = 0; k < 128; ++k) {
        float v = sval[k];
        float4 w = *(const float4*)(wdt + (size_t)sidx[k] * D_ + d);
        mul.x += v * w.x; mul.y += v * w.y; mul.z += v * w.z; mul.w += v * w.w;
    }
    for (int k = 0; k < 32; ++k) {
        int idx = ridx[k];
        float v = rval[k];
        float4 w = *(const float4*)(wdt + (size_t)idx * D_ + d);
        rec.x += v * w.x; rec.y += v * w.y; rec.z += v * w.z; rec.w += v * w.w;
        if (idx < 16384) {
            m1.x += v * w.x; m1.y += v * w.y; m1.z += v * w.z; m1.w += v * w.w;
            if (idx < 4096) {
                m0.x += v * w.x; m0.y += v * w.y; m0.z += v * w.z; m0.w += v * w.w;
            }
        }
    }
    size_t o = (size_t)b * D_ + d;
    *(float4*)(o_recon + o)  = rec;
    *(float4*)(o_multik + o) = mul;
    *(float4*)(o_mat0 + o)   = m0;
    *(float4*)(o_mat1 + o)   = m1;
}

extern "C" void kernel_launch(void* const* d_in, const int* in_sizes, int n_in,
                              void* d_out, int out_size, void* d_ws, size_t ws_size,
                              hipStream_t stream)
{
    const float* x     = (const float*)d_in[0];
    const float* wenc  = (const float*)d_in[1];
    const float* wdec  = (const float*)d_in[2];
    const float* ib    = (const float*)d_in[3];
    const float* nb    = (const float*)d_in[4];
    const int*   steps = (const int*)d_in[5];
    float* out = (float*)d_out;

    char* ws = (char*)d_ws;
    float*     preact  = (float*)ws;                              // [0, 64MB)
    float*     wdt     = (float*)(ws + 67108864);                 // [64MB, 192MB)
    _Float16*  xhf     = (_Float16*)(ws + 201326592);             // [192MB, +1MB)
    int*       auxcand = (int*)(ws + 201326592 + 2097152);        // 192KB
    int*       rec32_i = (int*)(ws + 201326592 + 2097152 + 262144);
    float*     rec32_v = (float*)(ws + 201326592 + 2097152 + 327680);
    int*       sel_idx = (int*)(ws + 206569472);                  // +256KB
    float*     sel_val = (float*)(ws + 206831616);                // +256KB

    float* out_recon  = out;
    float* out_multik = out + 524288;
    float* out_mat0   = out + 1048576;
    float* out_mat1   = out + 1572864;
    float* out_tidx   = out + 2097152;
    float* out_tval   = out + 2097152 + 16384;
    float* out_aidx   = out + 2097152 + 32768;
    float* out_aval   = out + 2097152 + 32768 + 32768;

    split_x_k<<<dim3(512), dim3(256), 0, stream>>>(x, ib, xhf);
    enc_mfma<<<dim3(2048), dim3(256), 0, stream>>>(xhf, wenc, nb, preact);
    tr_k<<<dim3(1024, 32), dim3(32, 8), 0, stream>>>(wdec, wdt);
    select_both<<<dim3(512), dim3(1024), 0, stream>>>(preact, steps, sel_idx, sel_val, auxcand);
    resolve_k<<<dim3(512), dim3(256), 0, stream>>>(
        x, ib, wenc, nb, sel_idx, auxcand, rec32_i, rec32_v,
        out_tidx, out_tval, out_aidx, out_aval);
    dec_k<<<dim3(512), dim3(256), 0, stream>>>(
        wdt, sel_idx, sel_val, rec32_i, rec32_v, ib,
        out_recon, out_multik, out_mat0, out_mat1);
}

// Round 8
// 548.257 us; speedup vs baseline: 1.5119x; 1.0338x over previous
//
#include <hip/hip_runtime.h>
#include <stdint.h>

#define B_ 512
#define D_ 1024
#define M_ 32768

typedef _Float16 half8 __attribute__((ext_vector_type(8)));
typedef _Float16 half4 __attribute__((ext_vector_type(4)));
typedef float f32x4 __attribute__((ext_vector_type(4)));

// ---------- sortable key helpers (monotonic float <-> u32) ----------
__device__ __forceinline__ unsigned f2k(float f) {
    unsigned b = __float_as_uint(f);
    return (b & 0x80000000u) ? ~b : (b | 0x80000000u);
}
__device__ __forceinline__ float k2f(unsigned k) {
    unsigned b = (k & 0x80000000u) ? (k & 0x7FFFFFFFu) : ~k;
    return __uint_as_float(b);
}
// monotonic double -> u64 key
__device__ __forceinline__ unsigned long long d2k(double d) {
    unsigned long long b = (unsigned long long)__double_as_longlong(d);
    return (b & 0x8000000000000000ull) ? ~b : (b | 0x8000000000000000ull);
}

// ---------- async global->LDS (16B per lane, wave-uniform base + lane*16) ----------
__device__ __forceinline__ void gld16(const void* g, void* l) {
    __builtin_amdgcn_global_load_lds(
        (__attribute__((address_space(1))) void*)(uintptr_t)g,
        (__attribute__((address_space(3))) void*)(unsigned)(uintptr_t)l,
        16, 0, 0);
}

// ---------- split x: xc = (x - ib) * 2048 -> fp16 hi ----------
__global__ __launch_bounds__(256) void split_x_k(
    const float* __restrict__ x, const float* __restrict__ ib,
    _Float16* __restrict__ xh)
{
    int i = blockIdx.x * 256 + threadIdx.x;   // float4 index, 131072 total
    float4 v = ((const float4*)x)[i];
    float4 bb = ((const float4*)ib)[i & 255];
    float a0 = (v.x - bb.x) * 2048.0f;
    float a1 = (v.y - bb.y) * 2048.0f;
    float a2 = (v.z - bb.z) * 2048.0f;
    float a3 = (v.w - bb.w) * 2048.0f;
    half4 hv = {(_Float16)a0, (_Float16)a1, (_Float16)a2, (_Float16)a3};
    ((half4*)xh)[i] = hv;
}

// ---------- fused encoder GEMM + W_dec transpose (grid role-split) ----------
// Round-8: 4096 blocks; 256-block chunks alternate roles (chunk&1: 0=GEMM,
// 1=transpose) so every CU co-hosts both -> tr's pure-HBM streaming hides in
// enc's spare bandwidth instead of a serial ~60us kernel. sub-id keeps bid&7
// XCD swizzle valid (256 % 8 == 0). enc inner loop identical to round-7.
__global__ __launch_bounds__(256, 4) void enc_tr(
    const _Float16* __restrict__ xhf,
    const float* __restrict__ wenc, const float* __restrict__ nb,
    float* __restrict__ preact,
    const float* __restrict__ wdec, float* __restrict__ wdt)
{
    __shared__ alignas(16) _Float16 lA[2][128 * 32];      // 8 KB per buf
    __shared__ alignas(16) _Float16 lB[2][2][64 * 32];    // 4 KB per [s][hr]
    __shared__ float ttile[32][33];                       // transpose role

    const int tid = threadIdx.x;
    const int chunk = blockIdx.x >> 8;
    const int sub = (chunk >> 1) * 256 + (blockIdx.x & 255);   // [0,2048) per role

    if (chunk & 1) {
        // ---------------- transpose role: 16 tiles of 32x32 ----------------
        const int tx = tid & 31, ty = tid >> 5;   // 32 x 8
        for (int s = 0; s < 16; ++s) {
            int tix = sub * 16 + s;               // [0,32768)
            int x0 = (tix & 1023) * 32;
            int y0 = (tix >> 10) * 32;
#pragma unroll
            for (int j = 0; j < 32; j += 8)
                ttile[ty + j][tx] = wdec[(size_t)(y0 + ty + j) * M_ + x0 + tx];
            __syncthreads();
#pragma unroll
            for (int j = 0; j < 32; j += 8)
                wdt[(size_t)(x0 + ty + j) * D_ + y0 + tx] = ttile[tx][ty + j];
            __syncthreads();
        }
        return;
    }

    // ---------------- GEMM role (identical to round-7 enc) ----------------
    const int lane = tid & 63;
    const int wv = tid >> 6;
    const int wvr = wv >> 1;          // 0..1 -> M half (64 rows)
    const int wvc = wv & 1;           // 0..1 -> N half (32 cols)

    const int bid = sub;
    const int lb = bid >> 3;                      // [0,256)
    const int j0 = ((bid & 7) * 64 + (lb >> 2)) * 64;
    const int i0 = (lb & 3) * 128;

    const int ln15 = lane & 15;
    const int kq = (lane >> 4) * 8;   // half index of 16B chunk within 64B row

    f32x4 acc1[4][2], acc2[4][2];
#pragma unroll
    for (int r = 0; r < 4; ++r)
#pragma unroll
        for (int c = 0; c < 2; ++c) {
            acc1[r][c] = (f32x4){0.f, 0.f, 0.f, 0.f};
            acc2[r][c] = (f32x4){0.f, 0.f, 0.f, 0.f};
        }

    const int o0 = tid * 16;                // [0,4096)
    const int o1 = o0 + 4096;               // [4096,8192)
    const int rA0 = o0 >> 6, rA1 = o1 >> 6; // [0,64), [64,128)
    const int cA0s = (o0 & 63) ^ (((rA0 >> 1) & 3) << 4);
    const int cA1s = (o1 & 63) ^ (((rA1 >> 1) & 3) << 4);

    const int rW = tid >> 2;                 // [0,64)
    const int c8 = (tid & 3) * 8;
    const int c8s = c8 ^ (((rW >> 1) & 3) << 3);

    const int rowA = wvr * 64 + ln15;
    const int rowB = wvc * 32 + ln15;

#define STAGEA(k0, s)                                                                      \
    do {                                                                                   \
        gld16((const char*)(xhf + (size_t)(i0 + rA0) * 1024 + (k0)) + cA0s, (char*)lA[s] + o0); \
        gld16((const char*)(xhf + (size_t)(i0 + rA1) * 1024 + (k0)) + cA1s, (char*)lA[s] + o1); \
    } while (0)

#define LOADB(k0)                                                                          \
    do {                                                                                   \
        const float* wp = wenc + (size_t)(j0 + rW) * 1024 + (k0) + c8;                     \
        wv0 = *(const float4*)wp;                                                          \
        wv1 = *(const float4*)(wp + 4);                                                    \
    } while (0)

#define CVT1(idx, f)                                                                       \
    do { float a_ = (f) * 2048.0f; _Float16 h_ = (_Float16)a_;                             \
         bh[idx] = h_; br[idx] = (_Float16)((a_ - (float)h_) * 2048.0f); } while (0)

#define WRITEB(s)                                                                          \
    do {                                                                                   \
        half8 bh, br;                                                                      \
        CVT1(0, wv0.x); CVT1(1, wv0.y); CVT1(2, wv0.z); CVT1(3, wv0.w);                    \
        CVT1(4, wv1.x); CVT1(5, wv1.y); CVT1(6, wv1.z); CVT1(7, wv1.w);                    \
        *(half8*)&lB[s][0][rW * 32 + c8s] = bh;                                            \
        *(half8*)&lB[s][1][rW * 32 + c8s] = br;                                            \
    } while (0)

    float4 wv0, wv1;
    // ---- prologue: tiles 0,1 ----
    LOADB(0);
    asm volatile("s_waitcnt vmcnt(0)" ::: "memory");
    WRITEB(0);
    STAGEA(0, 0);
    LOADB(32);
    STAGEA(32, 1);
    asm volatile("s_waitcnt vmcnt(2)" ::: "memory");   // drains A(0)+B(32) regs; A(32) flying
    WRITEB(1);
    asm volatile("s_waitcnt lgkmcnt(0)" ::: "memory");
    __builtin_amdgcn_s_barrier();

    int cur = 0;
    for (int k0 = 0; k0 < 1024; k0 += 32) {
        if (k0 + 64 < 1024) LOADB(k0 + 64);

        half8 aH[4], bH[2], bR[2];
#pragma unroll
        for (int r = 0; r < 4; ++r) {
            const int ra = rowA + r * 16;
            const int ka = kq ^ (((ra >> 1) & 3) << 3);
            aH[r] = *(const half8*)&lA[cur][ra * 32 + ka];
        }
#pragma unroll
        for (int c = 0; c < 2; ++c) {
            const int rb = rowB + c * 16;
            const int kb = kq ^ (((rb >> 1) & 3) << 3);
            bH[c] = *(const half8*)&lB[cur][0][rb * 32 + kb];
            bR[c] = *(const half8*)&lB[cur][1][rb * 32 + kb];
        }
#pragma unroll
        for (int r = 0; r < 4; ++r)
#pragma unroll
            for (int c = 0; c < 2; ++c) {
                acc1[r][c] = __builtin_amdgcn_mfma_f32_16x16x32_f16(aH[r], bH[c], acc1[r][c], 0, 0, 0);
                acc2[r][c] = __builtin_amdgcn_mfma_f32_16x16x32_f16(aH[r], bR[c], acc2[r][c], 0, 0, 0);
            }

        if (k0 + 32 < 1024) {
            asm volatile("s_waitcnt lgkmcnt(0)" ::: "memory");
            __builtin_amdgcn_s_barrier();

            if (k0 + 64 < 1024) {
                STAGEA(k0 + 64, cur);
                asm volatile("s_waitcnt vmcnt(2)" ::: "memory");
                WRITEB(cur);
            } else {
                asm volatile("s_waitcnt vmcnt(0)" ::: "memory");
            }
            asm volatile("s_waitcnt lgkmcnt(0)" ::: "memory");
            __builtin_amdgcn_s_barrier();
        }
        cur ^= 1;
    }
#undef STAGEA
#undef LOADB
#undef CVT1
#undef WRITEB

    const float s1 = 0x1p-22f, s2 = 0x1p-33f;
#pragma unroll
    for (int c = 0; c < 2; ++c) {
        int n = j0 + wvc * 32 + c * 16 + ln15;
        float nbv = nb[n];
#pragma unroll
        for (int r = 0; r < 4; ++r) {
            int mb = i0 + wvr * 64 + r * 16 + (lane >> 4) * 4;
#pragma unroll
            for (int e = 0; e < 4; ++e)
                preact[(size_t)(mb + e) * M_ + n] = acc1[r][c][e] * s1 + acc2[r][c][e] * s2 + nbv;
        }
    }
}

// ---------- fused dual top-k select (1024 thr, single pass, reg value cache) ----------
__global__ __launch_bounds__(1024, 4) void select_both(
    const float* __restrict__ preact, const int* __restrict__ steps,
    int* __restrict__ sel_idx, float* __restrict__ sel_val,
    int* __restrict__ auxcand)
{
    __shared__ unsigned histU[4096];
    __shared__ unsigned histM[4096];
    __shared__ unsigned coarseU[256];
    __shared__ unsigned coarseM[256];
    __shared__ unsigned long long candU[512];
    __shared__ unsigned long long candM[512];
    __shared__ unsigned cntU, cntM, thrU, thrM, cbU, cbM, cumU, cumM;

    const int t = threadIdx.x;
    const int b = blockIdx.x;
    const float* row = preact + (size_t)b * M_;

    for (int i = t; i < 4096; i += 1024) { histU[i] = 0; histM[i] = 0; }
    if (t < 512) { candU[t] = 0ULL; candM[t] = 0ULL; }
    if (t == 0) { cntU = 0; cntM = 0; }
    __syncthreads();

    // ---- dead mask ----
    unsigned deadmask = 0;
#pragma unroll
    for (int p = 0; p < 8; ++p) {
        int i = t + p * 1024;                     // int4 / float4 index
        int4 sv = ((const int4*)steps)[i];
        unsigned mbits = 0;
        if (sv.x + 1 > 256) mbits |= 1u;
        if (sv.y + 1 > 256) mbits |= 2u;
        if (sv.z + 1 > 256) mbits |= 4u;
        if (sv.w + 1 > 256) mbits |= 8u;
        deadmask |= mbits << (p * 4);
    }

    // ---- single memory pass: load row into registers + histogram ----
    float4 v[8];
#pragma unroll
    for (int p = 0; p < 8; ++p) {
        int i = t + p * 1024;
        v[p] = ((const float4*)row)[i];
        unsigned k0 = f2k(v[p].x) >> 20;
        unsigned k1 = f2k(v[p].y) >> 20;
        unsigned k2 = f2k(v[p].z) >> 20;
        unsigned k3 = f2k(v[p].w) >> 20;
        atomicAdd(&histU[k0], 1u);
        atomicAdd(&histU[k1], 1u);
        atomicAdd(&histU[k2], 1u);
        atomicAdd(&histU[k3], 1u);
        unsigned dm = deadmask >> (p * 4);
        if (dm & 1u) atomicAdd(&histM[k0], 1u);
        if (dm & 2u) atomicAdd(&histM[k1], 1u);
        if (dm & 4u) atomicAdd(&histM[k2], 1u);
        if (dm & 8u) atomicAdd(&histM[k3], 1u);
    }
    __syncthreads();

    // ---- coarse sums (U by threads 0-255, M by 256-511) ----
    if (t < 256) {
        unsigned s = 0;
#pragma unroll
        for (int j = 0; j < 16; ++j) s += histU[t * 16 + j];
        coarseU[t] = s;
    } else if (t < 512) {
        int c = t - 256;
        unsigned s = 0;
#pragma unroll
        for (int j = 0; j < 16; ++j) s += histM[c * 16 + j];
        coarseM[c] = s;
    }
    __syncthreads();

    // ---- joint Hillis-Steele suffix scan over both coarse arrays ----
    for (int off = 1; off < 256; off <<= 1) {
        unsigned xv = 0;
        if (t < 256)      xv = coarseU[t] + (t + off < 256 ? coarseU[t + off] : 0u);
        else if (t < 512) { int c = t - 256; xv = coarseM[c] + (c + off < 256 ? coarseM[c + off] : 0u); }
        __syncthreads();
        if (t < 256)      coarseU[t] = xv;
        else if (t < 512) coarseM[t - 256] = xv;
        __syncthreads();
    }

    // ---- find crossing bins (suffix >= K boundary) ----
    if (t < 256) {
        unsigned S = coarseU[t];
        unsigned Sn = (t < 255) ? coarseU[t + 1] : 0u;
        if (S >= 128u && (t == 255 || Sn < 128u)) { cbU = (unsigned)t; cumU = Sn; }
    } else if (t < 512) {
        int c = t - 256;
        unsigned S = coarseM[c];
        unsigned Sn = (c < 255) ? coarseM[c + 1] : 0u;
        if (S >= 64u && (c == 255 || Sn < 64u)) { cbM = (unsigned)c; cumM = Sn; }
        if (c == 0 && S < 64u) { cbM = 0u; cumM = Sn; }   // degenerate: <64 masked total
    }
    __syncthreads();

    // ---- fine scans (t==0 for U, t==64 for M run concurrently) ----
    if (t == 0) {
        unsigned cum = cumU;
        int base = (int)cbU * 16, tb = base;
        for (int f = base + 15; f >= base; --f) {
            unsigned h = histU[f];
            if (cum + h >= 128u) { tb = f; break; }
            cum += h;
        }
        thrU = (unsigned)tb;
    }
    if (t == 64) {
        unsigned cum = cumM;
        int base = (int)cbM * 16, tb = base;
        for (int f = base + 15; f >= base; --f) {
            unsigned h = histM[f];
            if (cum + h >= 64u) { tb = f; break; }
            cum += h;
        }
        thrM = (unsigned)(tb > 0 ? tb - 1 : 0);   // one extra bin: margin for top-96 superset
    }
    __syncthreads();

    const unsigned TU = thrU, TM = thrM;

    // ---- candidate collection straight from registers ----
#pragma unroll
    for (int p = 0; p < 8; ++p) {
        int i = t + p * 1024;
#pragma unroll
        for (int e = 0; e < 4; ++e) {
            float val = (e == 0) ? v[p].x : (e == 1) ? v[p].y : (e == 2) ? v[p].z : v[p].w;
            unsigned key = f2k(val);
            int m = i * 4 + e;
            if ((key >> 20) >= TU) {
                unsigned pz = atomicAdd(&cntU, 1u);
                if (pz < 512u) candU[pz] = ((unsigned long long)key << 32) | (unsigned)(~m);
            }
            if (((deadmask >> (p * 4 + e)) & 1u) && (key >> 20) >= TM) {
                unsigned pz = atomicAdd(&cntM, 1u);
                if (pz < 512u) candM[pz] = ((unsigned long long)key << 32) | (unsigned)(~m);
            }
        }
    }
    __syncthreads();

    // ---- bitonic sort: threads 0-511 -> candU, 512-1023 -> candM ----
    // j<64 exchanges stay within one wave's 64-chunk: lgkmcnt(0) suffices.
    {
        unsigned long long* arr = (t < 512) ? candU : candM;
        const unsigned i = (unsigned)t & 511u;
        for (unsigned kk = 2; kk <= 512; kk <<= 1) {
            for (unsigned j = kk >> 1; j > 0; j >>= 1) {
                unsigned ixj = i ^ j;
                if (ixj > i) {
                    bool desc = ((i & kk) == 0);
                    unsigned long long a = arr[i], c = arr[ixj];
                    if (desc ? (a < c) : (a > c)) { arr[i] = c; arr[ixj] = a; }
                }
                unsigned nj = (j > 1) ? (j >> 1) : ((kk << 1) <= 512u ? kk : 0u);
                if (j >= 64 || nj >= 64) __syncthreads();
                else asm volatile("s_waitcnt lgkmcnt(0)" ::: "memory");
            }
        }
    }
    __syncthreads();   // candM written by waves 8-15, read below by waves 0-1

    if (t < 128) {
        unsigned long long c = candU[t];
        unsigned m = ~(unsigned)c;
        float vv = k2f((unsigned)(c >> 32));
        sel_idx[b * 128 + t] = (int)m;
        sel_val[b * 128 + t] = vv > 0.f ? vv : 0.f;
    }
    if (t < 96) {
        unsigned long long c = candM[t];
        auxcand[b * 96 + t] = c ? (int)(~(unsigned)c) : -1;
    }
}

// ---------- fused exact resolve (f64) + sparse decoder ----------
// Round-8: rec32 stays in LDS (no global round-trip); dec's wdt gather
// overlaps other blocks' f64 resolve via TLP.
__global__ __launch_bounds__(256) void resdec_k(
    const float* __restrict__ x, const float* __restrict__ ib,
    const float* __restrict__ wenc, const float* __restrict__ nb,
    const int* __restrict__ sel_idx, const float* __restrict__ sel_val,
    const int* __restrict__ auxcand, const float* __restrict__ wdt,
    float* __restrict__ out_tidx, float* __restrict__ out_tval,
    float* __restrict__ out_aidx, float* __restrict__ out_aval,
    float* __restrict__ o_recon, float* __restrict__ o_multik,
    float* __restrict__ o_mat0, float* __restrict__ o_mat1)
{
    __shared__ double xcs[1024];
    __shared__ unsigned long long kU[64];
    __shared__ unsigned long long kM[128];
    __shared__ float vU[64];
    __shared__ float vM[128];
    __shared__ int sidx[128];
    __shared__ float sval[128];
    __shared__ int ridx[32];
    __shared__ float rval[32];

    const int b = blockIdx.x, t = threadIdx.x;
    for (int d = t; d < 1024; d += 256)
        xcs[d] = (double)x[(size_t)b * 1024 + d] - (double)ib[d];
    if (t < 128) { sidx[t] = sel_idx[b * 128 + t]; sval[t] = sel_val[b * 128 + t]; }
    if (t < 64)  { kU[t] = 0ULL; vU[t] = 0.f; }
    if (t < 128) { kM[t] = 0ULL; vM[t] = 0.f; }
    __syncthreads();

    // ---- phase 1: f64-exact resolve of top-64 unmasked + 96 aux cands ----
    int m = -1;
    if (t < 64) m = sidx[t];
    else if (t >= 64 && t < 160) m = auxcand[b * 96 + (t - 64)];
    if (m >= 0) {
        const float* w = wenc + (size_t)m * 1024;
        double a0 = 0.0, a1 = 0.0, a2 = 0.0, a3 = 0.0;
        for (int d = 0; d < 1024; d += 4) {
            float4 wv = *(const float4*)(w + d);
            a0 = fma((double)wv.x, xcs[d + 0], a0);
            a1 = fma((double)wv.y, xcs[d + 1], a1);
            a2 = fma((double)wv.z, xcs[d + 2], a2);
            a3 = fma((double)wv.w, xcs[d + 3], a3);
        }
        double v = ((a0 + a1) + (a2 + a3)) + (double)nb[m];
        unsigned long long key = (d2k(v) & 0xFFFFFFFFFFFF0000ull)
                               | (unsigned long long)((~(unsigned)m) & 0xFFFFu);
        float vf = (float)v;
        if (t < 64) { kU[t] = key; vU[t] = vf; }
        else        { kM[t - 64] = key; vM[t - 64] = vf; }
    }
    __syncthreads();

    for (unsigned kk = 2; kk <= 128; kk <<= 1) {
        for (unsigned j = kk >> 1; j > 0; j >>= 1) {
            unsigned i = (unsigned)t, ixj = i ^ j;
            if (kk <= 64 && i < 64 && ixj > i) {
                bool desc = ((i & kk) == 0);
                unsigned long long a = kU[i], c = kU[ixj];
                if (desc ? (a < c) : (a > c)) {
                    kU[i] = c; kU[ixj] = a;
                    float fa = vU[i]; vU[i] = vU[ixj]; vU[ixj] = fa;
                }
            }
            if (i < 128 && ixj > i) {
                bool desc = ((i & kk) == 0);
                unsigned long long a = kM[i], c = kM[ixj];
                if (desc ? (a < c) : (a > c)) {
                    kM[i] = c; kM[ixj] = a;
                    float fa = vM[i]; vM[i] = vM[ixj]; vM[ixj] = fa;
                }
            }
            __syncthreads();
        }
    }

    if (t < 32) {
        unsigned mm = (~(unsigned)kU[t]) & 0xFFFFu;
        float v = vU[t];
        float rv = v > 0.f ? v : 0.f;
        ridx[t] = (int)mm;
        rval[t] = rv;
        out_tidx[b * 32 + t] = (float)mm;
        out_tval[b * 32 + t] = rv;
    }
    if (t < 64) {
        unsigned mm = (~(unsigned)kM[t]) & 0xFFFFu;
        float v = vM[t];
        out_aidx[b * 64 + t] = (float)mm;
        out_aval[b * 64 + t] = v > 0.f ? v : 0.f;
    }
    __syncthreads();

    // ---- phase 2: sparse decode (multik from sel 128, recon/mat from ridx) ----
    const int d = t * 4;
    float4 bias = *(const float4*)(ib + d);
    float4 mul = bias, rec = bias, m0 = bias, m1 = bias;

    for (int k = 0; k < 128; ++k) {
        float v = sval[k];
        float4 w = *(const float4*)(wdt + (size_t)sidx[k] * D_ + d);
        mul.x += v * w.x; mul.y += v * w.y; mul.z += v * w.z; mul.w += v * w.w;
    }
    for (int k = 0; k < 32; ++k) {
        int idx = ridx[k];
        float v = rval[k];
        float4 w = *(const float4*)(wdt + (size_t)idx * D_ + d);
        rec.x += v * w.x; rec.y += v * w.y; rec.z += v * w.z; rec.w += v * w.w;
        if (idx < 16384) {
            m1.x += v * w.x; m1.y += v * w.y; m1.z += v * w.z; m1.w += v * w.w;
            if (idx < 4096) {
                m0.x += v * w.x; m0.y += v * w.y; m0.z += v * w.z; m0.w += v * w.w;
            }
        }
    }
    size_t o = (size_t)b * D_ + d;
    *(float4*)(o_recon + o)  = rec;
    *(float4*)(o_multik + o) = mul;
    *(float4*)(o_mat0 + o)   = m0;
    *(float4*)(o_mat1 + o)   = m1;
}

extern "C" void kernel_launch(void* const* d_in, const int* in_sizes, int n_in,
                              void* d_out, int out_size, void* d_ws, size_t ws_size,
                              hipStream_t stream)
{
    const float* x     = (const float*)d_in[0];
    const float* wenc  = (const float*)d_in[1];
    const float* wdec  = (const float*)d_in[2];
    const float* ib    = (const float*)d_in[3];
    const float* nb    = (const float*)d_in[4];
    const int*   steps = (const int*)d_in[5];
    float* out = (float*)d_out;

    char* ws = (char*)d_ws;
    float*     preact  = (float*)ws;                              // [0, 64MB)
    float*     wdt     = (float*)(ws + 67108864);                 // [64MB, 192MB)
    _Float16*  xhf     = (_Float16*)(ws + 201326592);             // [192MB, +1MB)
    int*       auxcand = (int*)(ws + 201326592 + 2097152);        // 192KB
    int*       sel_idx = (int*)(ws + 206569472);                  // +256KB
    float*     sel_val = (float*)(ws + 206831616);                // +256KB

    float* out_recon  = out;
    float* out_multik = out + 524288;
    float* out_mat0   = out + 1048576;
    float* out_mat1   = out + 1572864;
    float* out_tidx   = out + 2097152;
    float* out_tval   = out + 2097152 + 16384;
    float* out_aidx   = out + 2097152 + 32768;
    float* out_aval   = out + 2097152 + 32768 + 32768;

    split_x_k<<<dim3(512), dim3(256), 0, stream>>>(x, ib, xhf);
    enc_tr<<<dim3(4096), dim3(256), 0, stream>>>(xhf, wenc, nb, preact, wdec, wdt);
    select_both<<<dim3(512), dim3(1024), 0, stream>>>(preact, steps, sel_idx, sel_val, auxcand);
    resdec_k<<<dim3(512), dim3(256), 0, stream>>>(
        x, ib, wenc, nb, sel_idx, sel_val, auxcand, wdt,
        out_tidx, out_tval, out_aidx, out_aval,
        out_recon, out_multik, out_mat0, out_mat1);
}

// Round 9
// 541.227 us; speedup vs baseline: 1.5316x; 1.0130x over previous
//
#include <hip/hip_runtime.h>
#include <stdint.h>

#define B_ 512
#define D_ 1024
#define M_ 32768

typedef _Float16 half8 __attribute__((ext_vector_type(8)));
typedef _Float16 half4 __attribute__((ext_vector_type(4)));
typedef float f32x4 __attribute__((ext_vector_type(4)));

// ---------- sortable key helpers (monotonic float <-> u32) ----------
__device__ __forceinline__ unsigned f2k(float f) {
    unsigned b = __float_as_uint(f);
    return (b & 0x80000000u) ? ~b : (b | 0x80000000u);
}
__device__ __forceinline__ float k2f(unsigned k) {
    unsigned b = (k & 0x80000000u) ? (k & 0x7FFFFFFFu) : ~k;
    return __uint_as_float(b);
}
// monotonic double -> u64 key
__device__ __forceinline__ unsigned long long d2k(double d) {
    unsigned long long b = (unsigned long long)__double_as_longlong(d);
    return (b & 0x8000000000000000ull) ? ~b : (b | 0x8000000000000000ull);
}

// ---------- async global->LDS (16B per lane, wave-uniform base + lane*16) ----------
__device__ __forceinline__ void gld16(const void* g, void* l) {
    __builtin_amdgcn_global_load_lds(
        (__attribute__((address_space(1))) void*)(uintptr_t)g,
        (__attribute__((address_space(3))) void*)(unsigned)(uintptr_t)l,
        16, 0, 0);
}

// ---------- split x: xc = (x - ib) * 2048 -> fp16 hi ----------
__global__ __launch_bounds__(256) void split_x_k(
    const float* __restrict__ x, const float* __restrict__ ib,
    _Float16* __restrict__ xh)
{
    int i = blockIdx.x * 256 + threadIdx.x;   // float4 index, 131072 total
    float4 v = ((const float4*)x)[i];
    float4 bb = ((const float4*)ib)[i & 255];
    float a0 = (v.x - bb.x) * 2048.0f;
    float a1 = (v.y - bb.y) * 2048.0f;
    float a2 = (v.z - bb.z) * 2048.0f;
    float a3 = (v.w - bb.w) * 2048.0f;
    half4 hv = {(_Float16)a0, (_Float16)a1, (_Float16)a2, (_Float16)a3};
    ((half4*)xh)[i] = hv;
}

// ---------- fused encoder GEMM + W_dec transpose (grid role-split) ----------
__global__ __launch_bounds__(256, 4) void enc_tr(
    const _Float16* __restrict__ xhf,
    const float* __restrict__ wenc, const float* __restrict__ nb,
    float* __restrict__ preact,
    const float* __restrict__ wdec, float* __restrict__ wdt)
{
    __shared__ alignas(16) _Float16 lA[2][128 * 32];      // 8 KB per buf
    __shared__ alignas(16) _Float16 lB[2][2][64 * 32];    // 4 KB per [s][hr]
    __shared__ float ttile[32][33];                       // transpose role

    const int tid = threadIdx.x;
    const int chunk = blockIdx.x >> 8;
    const int sub = (chunk >> 1) * 256 + (blockIdx.x & 255);   // [0,2048) per role

    if (chunk & 1) {
        // ---------------- transpose role: 16 tiles of 32x32 ----------------
        const int tx = tid & 31, ty = tid >> 5;   // 32 x 8
        for (int s = 0; s < 16; ++s) {
            int tix = sub * 16 + s;               // [0,32768)
            int x0 = (tix & 1023) * 32;
            int y0 = (tix >> 10) * 32;
#pragma unroll
            for (int j = 0; j < 32; j += 8)
                ttile[ty + j][tx] = wdec[(size_t)(y0 + ty + j) * M_ + x0 + tx];
            __syncthreads();
#pragma unroll
            for (int j = 0; j < 32; j += 8)
                wdt[(size_t)(x0 + ty + j) * D_ + y0 + tx] = ttile[tx][ty + j];
            __syncthreads();
        }
        return;
    }

    // ---------------- GEMM role ----------------
    const int lane = tid & 63;
    const int wv = tid >> 6;
    const int wvr = wv >> 1;          // 0..1 -> M half (64 rows)
    const int wvc = wv & 1;           // 0..1 -> N half (32 cols)

    const int bid = sub;
    const int lb = bid >> 3;                      // [0,256)
    const int j0 = ((bid & 7) * 64 + (lb >> 2)) * 64;
    const int i0 = (lb & 3) * 128;

    const int ln15 = lane & 15;
    const int kq = (lane >> 4) * 8;   // half index of 16B chunk within 64B row

    f32x4 acc1[4][2], acc2[4][2];
#pragma unroll
    for (int r = 0; r < 4; ++r)
#pragma unroll
        for (int c = 0; c < 2; ++c) {
            acc1[r][c] = (f32x4){0.f, 0.f, 0.f, 0.f};
            acc2[r][c] = (f32x4){0.f, 0.f, 0.f, 0.f};
        }

    const int o0 = tid * 16;                // [0,4096)
    const int o1 = o0 + 4096;               // [4096,8192)
    const int rA0 = o0 >> 6, rA1 = o1 >> 6; // [0,64), [64,128)
    const int cA0s = (o0 & 63) ^ (((rA0 >> 1) & 3) << 4);
    const int cA1s = (o1 & 63) ^ (((rA1 >> 1) & 3) << 4);

    const int rW = tid >> 2;                 // [0,64)
    const int c8 = (tid & 3) * 8;
    const int c8s = c8 ^ (((rW >> 1) & 3) << 3);

    const int rowA = wvr * 64 + ln15;
    const int rowB = wvc * 32 + ln15;

#define STAGEA(k0, s)                                                                      \
    do {                                                                                   \
        gld16((const char*)(xhf + (size_t)(i0 + rA0) * 1024 + (k0)) + cA0s, (char*)lA[s] + o0); \
        gld16((const char*)(xhf + (size_t)(i0 + rA1) * 1024 + (k0)) + cA1s, (char*)lA[s] + o1); \
    } while (0)

#define LOADB(k0)                                                                          \
    do {                                                                                   \
        const float* wp = wenc + (size_t)(j0 + rW) * 1024 + (k0) + c8;                     \
        wv0 = *(const float4*)wp;                                                          \
        wv1 = *(const float4*)(wp + 4);                                                    \
    } while (0)

#define CVT1(idx, f)                                                                       \
    do { float a_ = (f) * 2048.0f; _Float16 h_ = (_Float16)a_;                             \
         bh[idx] = h_; br[idx] = (_Float16)((a_ - (float)h_) * 2048.0f); } while (0)

#define WRITEB(s)                                                                          \
    do {                                                                                   \
        half8 bh, br;                                                                      \
        CVT1(0, wv0.x); CVT1(1, wv0.y); CVT1(2, wv0.z); CVT1(3, wv0.w);                    \
        CVT1(4, wv1.x); CVT1(5, wv1.y); CVT1(6, wv1.z); CVT1(7, wv1.w);                    \
        *(half8*)&lB[s][0][rW * 32 + c8s] = bh;                                            \
        *(half8*)&lB[s][1][rW * 32 + c8s] = br;                                            \
    } while (0)

    float4 wv0, wv1;
    // ---- prologue: tiles 0,1 ----
    LOADB(0);
    asm volatile("s_waitcnt vmcnt(0)" ::: "memory");
    WRITEB(0);
    STAGEA(0, 0);
    LOADB(32);
    STAGEA(32, 1);
    asm volatile("s_waitcnt vmcnt(2)" ::: "memory");   // drains A(0)+B(32) regs; A(32) flying
    WRITEB(1);
    asm volatile("s_waitcnt lgkmcnt(0)" ::: "memory");
    __builtin_amdgcn_s_barrier();

    int cur = 0;
    for (int k0 = 0; k0 < 1024; k0 += 32) {
        if (k0 + 64 < 1024) LOADB(k0 + 64);

        half8 aH[4], bH[2], bR[2];
#pragma unroll
        for (int r = 0; r < 4; ++r) {
            const int ra = rowA + r * 16;
            const int ka = kq ^ (((ra >> 1) & 3) << 3);
            aH[r] = *(const half8*)&lA[cur][ra * 32 + ka];
        }
#pragma unroll
        for (int c = 0; c < 2; ++c) {
            const int rb = rowB + c * 16;
            const int kb = kq ^ (((rb >> 1) & 3) << 3);
            bH[c] = *(const half8*)&lB[cur][0][rb * 32 + kb];
            bR[c] = *(const half8*)&lB[cur][1][rb * 32 + kb];
        }
#pragma unroll
        for (int r = 0; r < 4; ++r)
#pragma unroll
            for (int c = 0; c < 2; ++c) {
                acc1[r][c] = __builtin_amdgcn_mfma_f32_16x16x32_f16(aH[r], bH[c], acc1[r][c], 0, 0, 0);
                acc2[r][c] = __builtin_amdgcn_mfma_f32_16x16x32_f16(aH[r], bR[c], acc2[r][c], 0, 0, 0);
            }

        if (k0 + 32 < 1024) {
            asm volatile("s_waitcnt lgkmcnt(0)" ::: "memory");
            __builtin_amdgcn_s_barrier();

            if (k0 + 64 < 1024) {
                STAGEA(k0 + 64, cur);
                asm volatile("s_waitcnt vmcnt(2)" ::: "memory");
                WRITEB(cur);
            } else {
                asm volatile("s_waitcnt vmcnt(0)" ::: "memory");
            }
            asm volatile("s_waitcnt lgkmcnt(0)" ::: "memory");
            __builtin_amdgcn_s_barrier();
        }
        cur ^= 1;
    }
#undef STAGEA
#undef LOADB
#undef CVT1
#undef WRITEB

    const float s1 = 0x1p-22f, s2 = 0x1p-33f;
#pragma unroll
    for (int c = 0; c < 2; ++c) {
        int n = j0 + wvc * 32 + c * 16 + ln15;
        float nbv = nb[n];
#pragma unroll
        for (int r = 0; r < 4; ++r) {
            int mb = i0 + wvr * 64 + r * 16 + (lane >> 4) * 4;
#pragma unroll
            for (int e = 0; e < 4; ++e)
                preact[(size_t)(mb + e) * M_ + n] = acc1[r][c][e] * s1 + acc2[r][c][e] * s2 + nbv;
        }
    }
}

// ---------- fused select + f64-exact resolve + sparse decode (one block/row) ----------
// Round-9: sel/aux stay in LDS (no global round-trip, one fewer launch);
// resolve dots split 4-way over d (f64 partials, reorder error ~1e-13 vs
// ~1e-5 rank gaps -> same ordering as np f64 golden); decode scalar-per-thread
// (k ascending per element -> decode outputs bit-identical to round-8).
__global__ __launch_bounds__(1024, 2) void selresdec(
    const float* __restrict__ preact, const int* __restrict__ steps,
    const float* __restrict__ x, const float* __restrict__ ib,
    const float* __restrict__ wenc, const float* __restrict__ nb,
    const float* __restrict__ wdt,
    float* __restrict__ out_tidx, float* __restrict__ out_tval,
    float* __restrict__ out_aidx, float* __restrict__ out_aval,
    float* __restrict__ o_recon, float* __restrict__ o_multik,
    float* __restrict__ o_mat0, float* __restrict__ o_mat1)
{
    __shared__ unsigned histU[4096];
    __shared__ unsigned histM[4096];
    __shared__ unsigned coarseU[256];
    __shared__ unsigned coarseM[256];
    __shared__ unsigned long long candU[512];
    __shared__ unsigned long long candM[512];
    __shared__ double xcs[1024];
    __shared__ double part[160][4];
    __shared__ unsigned long long kU[64];
    __shared__ unsigned long long kM[128];
    __shared__ float vU[64];
    __shared__ float vM[128];
    __shared__ int sidx[128];
    __shared__ float sval[128];
    __shared__ int auxm[96];
    __shared__ int ridx[32];
    __shared__ float rval[32];
    __shared__ unsigned cntU, cntM, thrU, thrM, cbU, cbM, cumU, cumM;

    const int t = threadIdx.x;
    const int b = blockIdx.x;
    const float* row = preact + (size_t)b * M_;

    for (int i = t; i < 4096; i += 1024) { histU[i] = 0; histM[i] = 0; }
    if (t < 512) { candU[t] = 0ULL; candM[t] = 0ULL; }
    if (t == 0) { cntU = 0; cntM = 0; }
    xcs[t] = (double)x[(size_t)b * 1024 + t] - (double)ib[t];
    if (t < 64)  { kU[t] = 0ULL; vU[t] = 0.f; }
    if (t < 128) { kM[t] = 0ULL; vM[t] = 0.f; }
    __syncthreads();

    // ---- dead mask ----
    unsigned deadmask = 0;
#pragma unroll
    for (int p = 0; p < 8; ++p) {
        int i = t + p * 1024;                     // int4 / float4 index
        int4 sv = ((const int4*)steps)[i];
        unsigned mbits = 0;
        if (sv.x + 1 > 256) mbits |= 1u;
        if (sv.y + 1 > 256) mbits |= 2u;
        if (sv.z + 1 > 256) mbits |= 4u;
        if (sv.w + 1 > 256) mbits |= 8u;
        deadmask |= mbits << (p * 4);
    }

    // ---- single memory pass: load row into registers + histogram ----
    float4 v[8];
#pragma unroll
    for (int p = 0; p < 8; ++p) {
        int i = t + p * 1024;
        v[p] = ((const float4*)row)[i];
        unsigned k0 = f2k(v[p].x) >> 20;
        unsigned k1 = f2k(v[p].y) >> 20;
        unsigned k2 = f2k(v[p].z) >> 20;
        unsigned k3 = f2k(v[p].w) >> 20;
        atomicAdd(&histU[k0], 1u);
        atomicAdd(&histU[k1], 1u);
        atomicAdd(&histU[k2], 1u);
        atomicAdd(&histU[k3], 1u);
        unsigned dm = deadmask >> (p * 4);
        if (dm & 1u) atomicAdd(&histM[k0], 1u);
        if (dm & 2u) atomicAdd(&histM[k1], 1u);
        if (dm & 4u) atomicAdd(&histM[k2], 1u);
        if (dm & 8u) atomicAdd(&histM[k3], 1u);
    }
    __syncthreads();

    // ---- coarse sums ----
    if (t < 256) {
        unsigned s = 0;
#pragma unroll
        for (int j = 0; j < 16; ++j) s += histU[t * 16 + j];
        coarseU[t] = s;
    } else if (t < 512) {
        int c = t - 256;
        unsigned s = 0;
#pragma unroll
        for (int j = 0; j < 16; ++j) s += histM[c * 16 + j];
        coarseM[c] = s;
    }
    __syncthreads();

    // ---- joint Hillis-Steele suffix scan ----
    for (int off = 1; off < 256; off <<= 1) {
        unsigned xv = 0;
        if (t < 256)      xv = coarseU[t] + (t + off < 256 ? coarseU[t + off] : 0u);
        else if (t < 512) { int c = t - 256; xv = coarseM[c] + (c + off < 256 ? coarseM[c + off] : 0u); }
        __syncthreads();
        if (t < 256)      coarseU[t] = xv;
        else if (t < 512) coarseM[t - 256] = xv;
        __syncthreads();
    }

    // ---- crossing bins ----
    if (t < 256) {
        unsigned S = coarseU[t];
        unsigned Sn = (t < 255) ? coarseU[t + 1] : 0u;
        if (S >= 128u && (t == 255 || Sn < 128u)) { cbU = (unsigned)t; cumU = Sn; }
    } else if (t < 512) {
        int c = t - 256;
        unsigned S = coarseM[c];
        unsigned Sn = (c < 255) ? coarseM[c + 1] : 0u;
        if (S >= 64u && (c == 255 || Sn < 64u)) { cbM = (unsigned)c; cumM = Sn; }
        if (c == 0 && S < 64u) { cbM = 0u; cumM = Sn; }
    }
    __syncthreads();

    // ---- fine scans ----
    if (t == 0) {
        unsigned cum = cumU;
        int base = (int)cbU * 16, tb = base;
        for (int f = base + 15; f >= base; --f) {
            unsigned h = histU[f];
            if (cum + h >= 128u) { tb = f; break; }
            cum += h;
        }
        thrU = (unsigned)tb;
    }
    if (t == 64) {
        unsigned cum = cumM;
        int base = (int)cbM * 16, tb = base;
        for (int f = base + 15; f >= base; --f) {
            unsigned h = histM[f];
            if (cum + h >= 64u) { tb = f; break; }
            cum += h;
        }
        thrM = (unsigned)(tb > 0 ? tb - 1 : 0);
    }
    __syncthreads();

    const unsigned TU = thrU, TM = thrM;

    // ---- candidate collection straight from registers ----
#pragma unroll
    for (int p = 0; p < 8; ++p) {
        int i = t + p * 1024;
#pragma unroll
        for (int e = 0; e < 4; ++e) {
            float val = (e == 0) ? v[p].x : (e == 1) ? v[p].y : (e == 2) ? v[p].z : v[p].w;
            unsigned key = f2k(val);
            int m = i * 4 + e;
            if ((key >> 20) >= TU) {
                unsigned pz = atomicAdd(&cntU, 1u);
                if (pz < 512u) candU[pz] = ((unsigned long long)key << 32) | (unsigned)(~m);
            }
            if (((deadmask >> (p * 4 + e)) & 1u) && (key >> 20) >= TM) {
                unsigned pz = atomicAdd(&cntM, 1u);
                if (pz < 512u) candM[pz] = ((unsigned long long)key << 32) | (unsigned)(~m);
            }
        }
    }
    __syncthreads();

    // ---- bitonic sort: threads 0-511 -> candU, 512-1023 -> candM ----
    {
        unsigned long long* arr = (t < 512) ? candU : candM;
        const unsigned i = (unsigned)t & 511u;
        for (unsigned kk = 2; kk <= 512; kk <<= 1) {
            for (unsigned j = kk >> 1; j > 0; j >>= 1) {
                unsigned ixj = i ^ j;
                if (ixj > i) {
                    bool desc = ((i & kk) == 0);
                    unsigned long long a = arr[i], c = arr[ixj];
                    if (desc ? (a < c) : (a > c)) { arr[i] = c; arr[ixj] = a; }
                }
                unsigned nj = (j > 1) ? (j >> 1) : ((kk << 1) <= 512u ? kk : 0u);
                if (j >= 64 || nj >= 64) __syncthreads();
                else asm volatile("s_waitcnt lgkmcnt(0)" ::: "memory");
            }
        }
    }
    __syncthreads();

    // ---- sel/aux into LDS (no global round-trip) ----
    if (t < 128) {
        unsigned long long c = candU[t];
        unsigned m = ~(unsigned)c;
        float vv = k2f((unsigned)(c >> 32));
        sidx[t] = (int)m;
        sval[t] = vv > 0.f ? vv : 0.f;
    }
    if (t < 96) {
        unsigned long long c = candM[t];
        auxm[t] = c ? (int)(~(unsigned)c) : -1;
    }
    __syncthreads();

    // ---- f64 resolve: 4-way d-split over threads 0-639 ----
    if (t < 640) {
        const int ci = t >> 2, q = t & 3;
        int m = (ci < 64) ? sidx[ci] : auxm[ci - 64];
        if (m >= 0) {
            const float* w = wenc + (size_t)m * 1024 + q * 256;
            const double* xq = xcs + q * 256;
            double a0 = 0.0, a1 = 0.0, a2 = 0.0, a3 = 0.0;
            for (int d = 0; d < 256; d += 4) {
                float4 wv = *(const float4*)(w + d);
                a0 = fma((double)wv.x, xq[d + 0], a0);
                a1 = fma((double)wv.y, xq[d + 1], a1);
                a2 = fma((double)wv.z, xq[d + 2], a2);
                a3 = fma((double)wv.w, xq[d + 3], a3);
            }
            part[ci][q] = ((a0 + a1) + (a2 + a3));
        }
    }
    __syncthreads();

    // ---- combine partials, build keys ----
    if (t < 160) {
        int m = (t < 64) ? sidx[t] : auxm[t - 64];
        if (m >= 0) {
            double vd = ((part[t][0] + part[t][1]) + (part[t][2] + part[t][3])) + (double)nb[m];
            unsigned long long key = (d2k(vd) & 0xFFFFFFFFFFFF0000ull)
                                   | (unsigned long long)((~(unsigned)m) & 0xFFFFu);
            float vf = (float)vd;
            if (t < 64) { kU[t] = key; vU[t] = vf; }
            else        { kM[t - 64] = key; vM[t - 64] = vf; }
        }
    }
    __syncthreads();

    // ---- sort kU (64) and kM (128) ----
    for (unsigned kk = 2; kk <= 128; kk <<= 1) {
        for (unsigned j = kk >> 1; j > 0; j >>= 1) {
            unsigned i = (unsigned)t, ixj = i ^ j;
            if (kk <= 64 && i < 64 && ixj > i) {
                bool desc = ((i & kk) == 0);
                unsigned long long a = kU[i], c = kU[ixj];
                if (desc ? (a < c) : (a > c)) {
                    kU[i] = c; kU[ixj] = a;
                    float fa = vU[i]; vU[i] = vU[ixj]; vU[ixj] = fa;
                }
            }
            if (i < 128 && ixj > i) {
                bool desc = ((i & kk) == 0);
                unsigned long long a = kM[i], c = kM[ixj];
                if (desc ? (a < c) : (a > c)) {
                    kM[i] = c; kM[ixj] = a;
                    float fa = vM[i]; vM[i] = vM[ixj]; vM[ixj] = fa;
                }
            }
            __syncthreads();
        }
    }

    if (t < 32) {
        unsigned mm = (~(unsigned)kU[t]) & 0xFFFFu;
        float vv = vU[t];
        float rv = vv > 0.f ? vv : 0.f;
        ridx[t] = (int)mm;
        rval[t] = rv;
        out_tidx[b * 32 + t] = (float)mm;
        out_tval[b * 32 + t] = rv;
    }
    if (t < 64) {
        unsigned mm = (~(unsigned)kM[t]) & 0xFFFFu;
        float vv = vM[t];
        out_aidx[b * 64 + t] = (float)mm;
        out_aval[b * 64 + t] = vv > 0.f ? vv : 0.f;
    }
    __syncthreads();

    // ---- sparse decode: thread t owns output element d=t (k ascending) ----
    {
        const int d = t;
        float bias = ib[d];
        float mul = bias, rec = bias, m0 = bias, m1 = bias;
        for (int k = 0; k < 128; ++k) {
            float vv = sval[k];
            float w = wdt[(size_t)sidx[k] * D_ + d];
            mul += vv * w;
        }
        for (int k = 0; k < 32; ++k) {
            int idx = ridx[k];
            float vv = rval[k];
            float w = wdt[(size_t)idx * D_ + d];
            rec += vv * w;
            if (idx < 16384) {
                m1 += vv * w;
                if (idx < 4096) m0 += vv * w;
            }
        }
        size_t o = (size_t)b * D_ + d;
        o_recon[o]  = rec;
        o_multik[o] = mul;
        o_mat0[o]   = m0;
        o_mat1[o]   = m1;
    }
}

extern "C" void kernel_launch(void* const* d_in, const int* in_sizes, int n_in,
                              void* d_out, int out_size, void* d_ws, size_t ws_size,
                              hipStream_t stream)
{
    const float* x     = (const float*)d_in[0];
    const float* wenc  = (const float*)d_in[1];
    const float* wdec  = (const float*)d_in[2];
    const float* ib    = (const float*)d_in[3];
    const float* nb    = (const float*)d_in[4];
    const int*   steps = (const int*)d_in[5];
    float* out = (float*)d_out;

    char* ws = (char*)d_ws;
    float*     preact  = (float*)ws;                              // [0, 64MB)
    float*     wdt     = (float*)(ws + 67108864);                 // [64MB, 192MB)
    _Float16*  xhf     = (_Float16*)(ws + 201326592);             // [192MB, +1MB)

    float* out_recon  = out;
    float* out_multik = out + 524288;
    float* out_mat0   = out + 1048576;
    float* out_mat1   = out + 1572864;
    float* out_tidx   = out + 2097152;
    float* out_tval   = out + 2097152 + 16384;
    float* out_aidx   = out + 2097152 + 32768;
    float* out_aval   = out + 2097152 + 32768 + 32768;

    split_x_k<<<dim3(512), dim3(256), 0, stream>>>(x, ib, xhf);
    enc_tr<<<dim3(4096), dim3(256), 0, stream>>>(xhf, wenc, nb, preact, wdec, wdt);
    selresdec<<<dim3(512), dim3(1024), 0, stream>>>(
        preact, steps, x, ib, wenc, nb, wdt,
        out_tidx, out_tval, out_aidx, out_aval,
        out_recon, out_multik, out_mat0, out_mat1);
}

// Round 10
// 533.614 us; speedup vs baseline: 1.5534x; 1.0143x over previous
//
#include <hip/hip_runtime.h>
#include <stdint.h>

#define B_ 512
#define D_ 1024
#define M_ 32768

typedef _Float16 half8 __attribute__((ext_vector_type(8)));
typedef _Float16 half4 __attribute__((ext_vector_type(4)));
typedef float f32x4 __attribute__((ext_vector_type(4)));

// ---------- sortable key helpers (monotonic float <-> u32) ----------
__device__ __forceinline__ unsigned f2k(float f) {
    unsigned b = __float_as_uint(f);
    return (b & 0x80000000u) ? ~b : (b | 0x80000000u);
}
__device__ __forceinline__ float k2f(unsigned k) {
    unsigned b = (k & 0x80000000u) ? (k & 0x7FFFFFFFu) : ~k;
    return __uint_as_float(b);
}
// monotonic double -> u64 key
__device__ __forceinline__ unsigned long long d2k(double d) {
    unsigned long long b = (unsigned long long)__double_as_longlong(d);
    return (b & 0x8000000000000000ull) ? ~b : (b | 0x8000000000000000ull);
}

// ---------- async global->LDS (16B per lane, wave-uniform base + lane*16) ----------
__device__ __forceinline__ void gld16(const void* g, void* l) {
    __builtin_amdgcn_global_load_lds(
        (__attribute__((address_space(1))) void*)(uintptr_t)g,
        (__attribute__((address_space(3))) void*)(unsigned)(uintptr_t)l,
        16, 0, 0);
}

// ---------- split x: xc = (x - ib) * 2048 -> fp16 hi ----------
__global__ __launch_bounds__(256) void split_x_k(
    const float* __restrict__ x, const float* __restrict__ ib,
    _Float16* __restrict__ xh)
{
    int i = blockIdx.x * 256 + threadIdx.x;   // float4 index, 131072 total
    float4 v = ((const float4*)x)[i];
    float4 bb = ((const float4*)ib)[i & 255];
    float a0 = (v.x - bb.x) * 2048.0f;
    float a1 = (v.y - bb.y) * 2048.0f;
    float a2 = (v.z - bb.z) * 2048.0f;
    float a3 = (v.w - bb.w) * 2048.0f;
    half4 hv = {(_Float16)a0, (_Float16)a1, (_Float16)a2, (_Float16)a3};
    ((half4*)xh)[i] = hv;
}

// ---------- fused encoder GEMM + W_dec transpose (grid role-split) ----------
// Round-10: single hi*hi MFMA (B-residual dropped: preact err ~4e-4 vs
// selection margins 0.08-0.19; all index outputs f64-resolved). LDS union'd
// (GEMM 24KB | tr 4.2KB) -> 6 blocks/CU. preact stored fp16 (write 64->32MB).
__global__ __launch_bounds__(256, 6) void enc_tr(
    const _Float16* __restrict__ xhf,
    const float* __restrict__ wenc, const float* __restrict__ nb,
    _Float16* __restrict__ preact,
    const float* __restrict__ wdec, float* __restrict__ wdt)
{
    __shared__ alignas(16) char smem[24576];   // GEMM: lA 16KB + lB 8KB; tr: 4.2KB

    const int tid = threadIdx.x;
    const int chunk = blockIdx.x >> 8;
    const int sub = (chunk >> 1) * 256 + (blockIdx.x & 255);   // [0,2048) per role

    if (chunk & 1) {
        // ---------------- transpose role: 16 tiles of 32x32 ----------------
        float (*ttile)[33] = (float(*)[33])smem;
        const int tx = tid & 31, ty = tid >> 5;   // 32 x 8
        for (int s = 0; s < 16; ++s) {
            int tix = sub * 16 + s;               // [0,32768)
            int x0 = (tix & 1023) * 32;
            int y0 = (tix >> 10) * 32;
#pragma unroll
            for (int j = 0; j < 32; j += 8)
                ttile[ty + j][tx] = wdec[(size_t)(y0 + ty + j) * M_ + x0 + tx];
            __syncthreads();
#pragma unroll
            for (int j = 0; j < 32; j += 8)
                wdt[(size_t)(x0 + ty + j) * D_ + y0 + tx] = ttile[tx][ty + j];
            __syncthreads();
        }
        return;
    }

    // ---------------- GEMM role ----------------
    _Float16* lA0 = (_Float16*)smem;            // [2][128*32] halfs
    _Float16* lB0 = (_Float16*)(smem + 16384);  // [2][64*32] halfs

    const int lane = tid & 63;
    const int wv = tid >> 6;
    const int wvr = wv >> 1;          // 0..1 -> M half (64 rows)
    const int wvc = wv & 1;           // 0..1 -> N half (32 cols)

    const int bid = sub;
    const int lb = bid >> 3;                      // [0,256)
    const int j0 = ((bid & 7) * 64 + (lb >> 2)) * 64;
    const int i0 = (lb & 3) * 128;

    const int ln15 = lane & 15;
    const int kq = (lane >> 4) * 8;   // half index of 16B chunk within 64B row

    f32x4 acc1[4][2];
#pragma unroll
    for (int r = 0; r < 4; ++r)
#pragma unroll
        for (int c = 0; c < 2; ++c)
            acc1[r][c] = (f32x4){0.f, 0.f, 0.f, 0.f};

    const int o0 = tid * 16;                // [0,4096)
    const int o1 = o0 + 4096;               // [4096,8192)
    const int rA0 = o0 >> 6, rA1 = o1 >> 6; // [0,64), [64,128)
    const int cA0s = (o0 & 63) ^ (((rA0 >> 1) & 3) << 4);
    const int cA1s = (o1 & 63) ^ (((rA1 >> 1) & 3) << 4);

    const int rW = tid >> 2;                 // [0,64)
    const int c8 = (tid & 3) * 8;
    const int c8s = c8 ^ (((rW >> 1) & 3) << 3);

    const int rowA = wvr * 64 + ln15;
    const int rowB = wvc * 32 + ln15;

#define STAGEA(k0, s)                                                                      \
    do {                                                                                   \
        gld16((const char*)(xhf + (size_t)(i0 + rA0) * 1024 + (k0)) + cA0s, (char*)lA0 + (s) * 8192 + o0); \
        gld16((const char*)(xhf + (size_t)(i0 + rA1) * 1024 + (k0)) + cA1s, (char*)lA0 + (s) * 8192 + o1); \
    } while (0)

#define LOADB(k0)                                                                          \
    do {                                                                                   \
        const float* wp = wenc + (size_t)(j0 + rW) * 1024 + (k0) + c8;                     \
        wv0 = *(const float4*)wp;                                                          \
        wv1 = *(const float4*)(wp + 4);                                                    \
    } while (0)

#define CVT1(idx, f) do { bh[idx] = (_Float16)((f) * 2048.0f); } while (0)

#define WRITEB(s)                                                                          \
    do {                                                                                   \
        half8 bh;                                                                          \
        CVT1(0, wv0.x); CVT1(1, wv0.y); CVT1(2, wv0.z); CVT1(3, wv0.w);                    \
        CVT1(4, wv1.x); CVT1(5, wv1.y); CVT1(6, wv1.z); CVT1(7, wv1.w);                    \
        *(half8*)&lB0[(s) * 2048 + rW * 32 + c8s] = bh;                                    \
    } while (0)

    float4 wv0, wv1;
    // ---- prologue: tiles 0,1 ----
    LOADB(0);
    asm volatile("s_waitcnt vmcnt(0)" ::: "memory");
    WRITEB(0);
    STAGEA(0, 0);
    LOADB(32);
    STAGEA(32, 1);
    asm volatile("s_waitcnt vmcnt(2)" ::: "memory");   // drains A(0)+B(32) regs; A(32) flying
    WRITEB(1);
    asm volatile("s_waitcnt lgkmcnt(0)" ::: "memory");
    __builtin_amdgcn_s_barrier();

    int cur = 0;
    for (int k0 = 0; k0 < 1024; k0 += 32) {
        if (k0 + 64 < 1024) LOADB(k0 + 64);   // B(k+2) reg-loads fly under MFMA

        half8 aH[4], bH[2];
#pragma unroll
        for (int r = 0; r < 4; ++r) {
            const int ra = rowA + r * 16;
            const int ka = kq ^ (((ra >> 1) & 3) << 3);
            aH[r] = *(const half8*)&lA0[cur * 4096 + ra * 32 + ka];
        }
#pragma unroll
        for (int c = 0; c < 2; ++c) {
            const int rb = rowB + c * 16;
            const int kb = kq ^ (((rb >> 1) & 3) << 3);
            bH[c] = *(const half8*)&lB0[cur * 2048 + rb * 32 + kb];
        }
#pragma unroll
        for (int r = 0; r < 4; ++r)
#pragma unroll
            for (int c = 0; c < 2; ++c)
                acc1[r][c] = __builtin_amdgcn_mfma_f32_16x16x32_f16(aH[r], bH[c], acc1[r][c], 0, 0, 0);

        if (k0 + 32 < 1024) {
            asm volatile("s_waitcnt lgkmcnt(0)" ::: "memory");
            __builtin_amdgcn_s_barrier();

            if (k0 + 64 < 1024) {
                STAGEA(k0 + 64, cur);                              // +2 glds
                asm volatile("s_waitcnt vmcnt(2)" ::: "memory");   // drain A(k+1) glds + B(k+2) regs
                WRITEB(cur);
            } else {
                asm volatile("s_waitcnt vmcnt(0)" ::: "memory");
            }
            asm volatile("s_waitcnt lgkmcnt(0)" ::: "memory");
            __builtin_amdgcn_s_barrier();
        }
        cur ^= 1;
    }
#undef STAGEA
#undef LOADB
#undef CVT1
#undef WRITEB

    const float s1 = 0x1p-22f;
#pragma unroll
    for (int c = 0; c < 2; ++c) {
        int n = j0 + wvc * 32 + c * 16 + ln15;
        float nbv = nb[n];
#pragma unroll
        for (int r = 0; r < 4; ++r) {
            int mb = i0 + wvr * 64 + r * 16 + (lane >> 4) * 4;
#pragma unroll
            for (int e = 0; e < 4; ++e)
                preact[(size_t)(mb + e) * M_ + n] = (_Float16)(acc1[r][c][e] * s1 + nbv);
        }
    }
}

// ---------- fused select + f64-exact resolve + sparse decode (one block/row) ----------
// Round-10: preact is fp16 (half the read); value cache 4x half8 regs.
__global__ __launch_bounds__(1024, 2) void selresdec(
    const _Float16* __restrict__ preact, const int* __restrict__ steps,
    const float* __restrict__ x, const float* __restrict__ ib,
    const float* __restrict__ wenc, const float* __restrict__ nb,
    const float* __restrict__ wdt,
    float* __restrict__ out_tidx, float* __restrict__ out_tval,
    float* __restrict__ out_aidx, float* __restrict__ out_aval,
    float* __restrict__ o_recon, float* __restrict__ o_multik,
    float* __restrict__ o_mat0, float* __restrict__ o_mat1)
{
    __shared__ unsigned histU[4096];
    __shared__ unsigned histM[4096];
    __shared__ unsigned coarseU[256];
    __shared__ unsigned coarseM[256];
    __shared__ unsigned long long candU[512];
    __shared__ unsigned long long candM[512];
    __shared__ double xcs[1024];
    __shared__ double part[160][4];
    __shared__ unsigned long long kU[64];
    __shared__ unsigned long long kM[128];
    __shared__ float vU[64];
    __shared__ float vM[128];
    __shared__ int sidx[128];
    __shared__ float sval[128];
    __shared__ int auxm[96];
    __shared__ int ridx[32];
    __shared__ float rval[32];
    __shared__ unsigned cntU, cntM, thrU, thrM, cbU, cbM, cumU, cumM;

    const int t = threadIdx.x;
    const int b = blockIdx.x;
    const half8* rowh = (const half8*)(preact + (size_t)b * M_);

    for (int i = t; i < 4096; i += 1024) { histU[i] = 0; histM[i] = 0; }
    if (t < 512) { candU[t] = 0ULL; candM[t] = 0ULL; }
    if (t == 0) { cntU = 0; cntM = 0; }
    xcs[t] = (double)x[(size_t)b * 1024 + t] - (double)ib[t];
    if (t < 64)  { kU[t] = 0ULL; vU[t] = 0.f; }
    if (t < 128) { kM[t] = 0ULL; vM[t] = 0.f; }
    __syncthreads();

    // ---- dead mask: bit p*8+e for m = (t + p*1024)*8 + e ----
    unsigned deadmask = 0;
#pragma unroll
    for (int p = 0; p < 4; ++p) {
        int base = 2 * t + 2048 * p;              // int4 index
        int4 s0 = ((const int4*)steps)[base];
        int4 s1 = ((const int4*)steps)[base + 1];
        unsigned mb = 0;
        if (s0.x + 1 > 256) mb |= 1u;
        if (s0.y + 1 > 256) mb |= 2u;
        if (s0.z + 1 > 256) mb |= 4u;
        if (s0.w + 1 > 256) mb |= 8u;
        if (s1.x + 1 > 256) mb |= 16u;
        if (s1.y + 1 > 256) mb |= 32u;
        if (s1.z + 1 > 256) mb |= 64u;
        if (s1.w + 1 > 256) mb |= 128u;
        deadmask |= mb << (p * 8);
    }

    // ---- single memory pass: load fp16 row into registers + histogram ----
    half8 v[4];
#pragma unroll
    for (int p = 0; p < 4; ++p) {
        v[p] = rowh[t + p * 1024];
#pragma unroll
        for (int e = 0; e < 8; ++e) {
            unsigned key = f2k((float)v[p][e]) >> 20;
            atomicAdd(&histU[key], 1u);
            if ((deadmask >> (p * 8 + e)) & 1u) atomicAdd(&histM[key], 1u);
        }
    }
    __syncthreads();

    // ---- coarse sums ----
    if (t < 256) {
        unsigned s = 0;
#pragma unroll
        for (int j = 0; j < 16; ++j) s += histU[t * 16 + j];
        coarseU[t] = s;
    } else if (t < 512) {
        int c = t - 256;
        unsigned s = 0;
#pragma unroll
        for (int j = 0; j < 16; ++j) s += histM[c * 16 + j];
        coarseM[c] = s;
    }
    __syncthreads();

    // ---- joint Hillis-Steele suffix scan ----
    for (int off = 1; off < 256; off <<= 1) {
        unsigned xv = 0;
        if (t < 256)      xv = coarseU[t] + (t + off < 256 ? coarseU[t + off] : 0u);
        else if (t < 512) { int c = t - 256; xv = coarseM[c] + (c + off < 256 ? coarseM[c + off] : 0u); }
        __syncthreads();
        if (t < 256)      coarseU[t] = xv;
        else if (t < 512) coarseM[t - 256] = xv;
        __syncthreads();
    }

    // ---- crossing bins ----
    if (t < 256) {
        unsigned S = coarseU[t];
        unsigned Sn = (t < 255) ? coarseU[t + 1] : 0u;
        if (S >= 128u && (t == 255 || Sn < 128u)) { cbU = (unsigned)t; cumU = Sn; }
    } else if (t < 512) {
        int c = t - 256;
        unsigned S = coarseM[c];
        unsigned Sn = (c < 255) ? coarseM[c + 1] : 0u;
        if (S >= 64u && (c == 255 || Sn < 64u)) { cbM = (unsigned)c; cumM = Sn; }
        if (c == 0 && S < 64u) { cbM = 0u; cumM = Sn; }
    }
    __syncthreads();

    // ---- fine scans ----
    if (t == 0) {
        unsigned cum = cumU;
        int base = (int)cbU * 16, tb = base;
        for (int f = base + 15; f >= base; --f) {
            unsigned h = histU[f];
            if (cum + h >= 128u) { tb = f; break; }
            cum += h;
        }
        thrU = (unsigned)tb;
    }
    if (t == 64) {
        unsigned cum = cumM;
        int base = (int)cbM * 16, tb = base;
        for (int f = base + 15; f >= base; --f) {
            unsigned h = histM[f];
            if (cum + h >= 64u) { tb = f; break; }
            cum += h;
        }
        thrM = (unsigned)(tb > 0 ? tb - 1 : 0);
    }
    __syncthreads();

    const unsigned TU = thrU, TM = thrM;

    // ---- candidate collection straight from registers ----
#pragma unroll
    for (int p = 0; p < 4; ++p) {
#pragma unroll
        for (int e = 0; e < 8; ++e) {
            float val = (float)v[p][e];
            unsigned key = f2k(val);
            int m = (t + p * 1024) * 8 + e;
            if ((key >> 20) >= TU) {
                unsigned pz = atomicAdd(&cntU, 1u);
                if (pz < 512u) candU[pz] = ((unsigned long long)key << 32) | (unsigned)(~m);
            }
            if (((deadmask >> (p * 8 + e)) & 1u) && (key >> 20) >= TM) {
                unsigned pz = atomicAdd(&cntM, 1u);
                if (pz < 512u) candM[pz] = ((unsigned long long)key << 32) | (unsigned)(~m);
            }
        }
    }
    __syncthreads();

    // ---- bitonic sort: threads 0-511 -> candU, 512-1023 -> candM ----
    {
        unsigned long long* arr = (t < 512) ? candU : candM;
        const unsigned i = (unsigned)t & 511u;
        for (unsigned kk = 2; kk <= 512; kk <<= 1) {
            for (unsigned j = kk >> 1; j > 0; j >>= 1) {
                unsigned ixj = i ^ j;
                if (ixj > i) {
                    bool desc = ((i & kk) == 0);
                    unsigned long long a = arr[i], c = arr[ixj];
                    if (desc ? (a < c) : (a > c)) { arr[i] = c; arr[ixj] = a; }
                }
                unsigned nj = (j > 1) ? (j >> 1) : ((kk << 1) <= 512u ? kk : 0u);
                if (j >= 64 || nj >= 64) __syncthreads();
                else asm volatile("s_waitcnt lgkmcnt(0)" ::: "memory");
            }
        }
    }
    __syncthreads();

    // ---- sel/aux into LDS ----
    if (t < 128) {
        unsigned long long c = candU[t];
        unsigned m = ~(unsigned)c;
        float vv = k2f((unsigned)(c >> 32));
        sidx[t] = (int)m;
        sval[t] = vv > 0.f ? vv : 0.f;
    }
    if (t < 96) {
        unsigned long long c = candM[t];
        auxm[t] = c ? (int)(~(unsigned)c) : -1;
    }
    __syncthreads();

    // ---- f64 resolve: 4-way d-split over threads 0-639 ----
    if (t < 640) {
        const int ci = t >> 2, q = t & 3;
        int m = (ci < 64) ? sidx[ci] : auxm[ci - 64];
        if (m >= 0) {
            const float* w = wenc + (size_t)m * 1024 + q * 256;
            const double* xq = xcs + q * 256;
            double a0 = 0.0, a1 = 0.0, a2 = 0.0, a3 = 0.0;
            for (int d = 0; d < 256; d += 4) {
                float4 wv = *(const float4*)(w + d);
                a0 = fma((double)wv.x, xq[d + 0], a0);
                a1 = fma((double)wv.y, xq[d + 1], a1);
                a2 = fma((double)wv.z, xq[d + 2], a2);
                a3 = fma((double)wv.w, xq[d + 3], a3);
            }
            part[ci][q] = ((a0 + a1) + (a2 + a3));
        }
    }
    __syncthreads();

    // ---- combine partials, build keys ----
    if (t < 160) {
        int m = (t < 64) ? sidx[t] : auxm[t - 64];
        if (m >= 0) {
            double vd = ((part[t][0] + part[t][1]) + (part[t][2] + part[t][3])) + (double)nb[m];
            unsigned long long key = (d2k(vd) & 0xFFFFFFFFFFFF0000ull)
                                   | (unsigned long long)((~(unsigned)m) & 0xFFFFu);
            float vf = (float)vd;
            if (t < 64) { kU[t] = key; vU[t] = vf; }
            else        { kM[t - 64] = key; vM[t - 64] = vf; }
        }
    }
    __syncthreads();

    // ---- sort kU (64) and kM (128) ----
    for (unsigned kk = 2; kk <= 128; kk <<= 1) {
        for (unsigned j = kk >> 1; j > 0; j >>= 1) {
            unsigned i = (unsigned)t, ixj = i ^ j;
            if (kk <= 64 && i < 64 && ixj > i) {
                bool desc = ((i & kk) == 0);
                unsigned long long a = kU[i], c = kU[ixj];
                if (desc ? (a < c) : (a > c)) {
                    kU[i] = c; kU[ixj] = a;
                    float fa = vU[i]; vU[i] = vU[ixj]; vU[ixj] = fa;
                }
            }
            if (i < 128 && ixj > i) {
                bool desc = ((i & kk) == 0);
                unsigned long long a = kM[i], c = kM[ixj];
                if (desc ? (a < c) : (a > c)) {
                    kM[i] = c; kM[ixj] = a;
                    float fa = vM[i]; vM[i] = vM[ixj]; vM[ixj] = fa;
                }
            }
            __syncthreads();
        }
    }

    if (t < 32) {
        unsigned mm = (~(unsigned)kU[t]) & 0xFFFFu;
        float vv = vU[t];
        float rv = vv > 0.f ? vv : 0.f;
        ridx[t] = (int)mm;
        rval[t] = rv;
        out_tidx[b * 32 + t] = (float)mm;
        out_tval[b * 32 + t] = rv;
    }
    if (t < 64) {
        unsigned mm = (~(unsigned)kM[t]) & 0xFFFFu;
        float vv = vM[t];
        out_aidx[b * 64 + t] = (float)mm;
        out_aval[b * 64 + t] = vv > 0.f ? vv : 0.f;
    }
    __syncthreads();

    // ---- sparse decode: thread t owns output element d=t (k ascending) ----
    {
        const int d = t;
        float bias = ib[d];
        float mul = bias, rec = bias, m0 = bias, m1 = bias;
        for (int k = 0; k < 128; ++k) {
            float vv = sval[k];
            float w = wdt[(size_t)sidx[k] * D_ + d];
            mul += vv * w;
        }
        for (int k = 0; k < 32; ++k) {
            int idx = ridx[k];
            float vv = rval[k];
            float w = wdt[(size_t)idx * D_ + d];
            rec += vv * w;
            if (idx < 16384) {
                m1 += vv * w;
                if (idx < 4096) m0 += vv * w;
            }
        }
        size_t o = (size_t)b * D_ + d;
        o_recon[o]  = rec;
        o_multik[o] = mul;
        o_mat0[o]   = m0;
        o_mat1[o]   = m1;
    }
}

extern "C" void kernel_launch(void* const* d_in, const int* in_sizes, int n_in,
                              void* d_out, int out_size, void* d_ws, size_t ws_size,
                              hipStream_t stream)
{
    const float* x     = (const float*)d_in[0];
    const float* wenc  = (const float*)d_in[1];
    const float* wdec  = (const float*)d_in[2];
    const float* ib    = (const float*)d_in[3];
    const float* nb    = (const float*)d_in[4];
    const int*   steps = (const int*)d_in[5];
    float* out = (float*)d_out;

    char* ws = (char*)d_ws;
    _Float16*  preact  = (_Float16*)ws;                           // [0, 32MB)
    float*     wdt     = (float*)(ws + 67108864);                 // [64MB, 192MB)
    _Float16*  xhf     = (_Float16*)(ws + 201326592);             // [192MB, +1MB)

    float* out_recon  = out;
    float* out_multik = out + 524288;
    float* out_mat0   = out + 1048576;
    float* out_mat1   = out + 1572864;
    float* out_tidx   = out + 2097152;
    float* out_tval   = out + 2097152 + 16384;
    float* out_aidx   = out + 2097152 + 32768;
    float* out_aval   = out + 2097152 + 32768 + 32768;

    split_x_k<<<dim3(512), dim3(256), 0, stream>>>(x, ib, xhf);
    enc_tr<<<dim3(4096), dim3(256), 0, stream>>>(xhf, wenc, nb, preact, wdec, wdt);
    selresdec<<<dim3(512), dim3(1024), 0, stream>>>(
        preact, steps, x, ib, wenc, nb, wdt,
        out_tidx, out_tval, out_aidx, out_aval,
        out_recon, out_multik, out_mat0, out_mat1);
}

// Round 11
// 487.845 us; speedup vs baseline: 1.6991x; 1.0938x over previous
//
#include <hip/hip_runtime.h>
#include <stdint.h>

#define B_ 512
#define D_ 1024
#define M_ 32768

typedef _Float16 half8 __attribute__((ext_vector_type(8)));
typedef _Float16 half4 __attribute__((ext_vector_type(4)));
typedef float f32x4 __attribute__((ext_vector_type(4)));

// ---------- sortable key helpers (monotonic float <-> u32) ----------
__device__ __forceinline__ unsigned f2k(float f) {
    unsigned b = __float_as_uint(f);
    return (b & 0x80000000u) ? ~b : (b | 0x80000000u);
}
__device__ __forceinline__ float k2f(unsigned k) {
    unsigned b = (k & 0x80000000u) ? (k & 0x7FFFFFFFu) : ~k;
    return __uint_as_float(b);
}
// monotonic double -> u64 key
__device__ __forceinline__ unsigned long long d2k(double d) {
    unsigned long long b = (unsigned long long)__double_as_longlong(d);
    return (b & 0x8000000000000000ull) ? ~b : (b | 0x8000000000000000ull);
}

// ---------- async global->LDS (16B per lane, wave-uniform base + lane*16) ----------
__device__ __forceinline__ void gld16(const void* g, void* l) {
    __builtin_amdgcn_global_load_lds(
        (__attribute__((address_space(1))) void*)(uintptr_t)g,
        (__attribute__((address_space(3))) void*)(unsigned)(uintptr_t)l,
        16, 0, 0);
}

// ---------- split x: xc = (x - ib) * 2048 -> fp16 hi ----------
__global__ __launch_bounds__(256) void split_x_k(
    const float* __restrict__ x, const float* __restrict__ ib,
    _Float16* __restrict__ xh)
{
    int i = blockIdx.x * 256 + threadIdx.x;   // float4 index, 131072 total
    float4 v = ((const float4*)x)[i];
    float4 bb = ((const float4*)ib)[i & 255];
    float a0 = (v.x - bb.x) * 2048.0f;
    float a1 = (v.y - bb.y) * 2048.0f;
    float a2 = (v.z - bb.z) * 2048.0f;
    float a3 = (v.w - bb.w) * 2048.0f;
    half4 hv = {(_Float16)a0, (_Float16)a1, (_Float16)a2, (_Float16)a3};
    ((half4*)xh)[i] = hv;
}

// ---------- fused encoder GEMM + W_dec transpose (grid role-split) ----------
// Round-11: byte-diet + pattern fixes. tr role: 64x64 tiles, float4 loads
// (256B/row), pad-65 scalar LDS (2-way free), fp16 wdt (write 128->64MB,
// decode gather halves). GEMM epilogue: C-tile repacked via LDS -> 16B/thread
// coalesced preact stores (kills 32B-segment RMW). GEMM K-loop untouched ->
// preact values bit-identical to round-10.
__global__ __launch_bounds__(256, 6) void enc_tr(
    const _Float16* __restrict__ xhf,
    const float* __restrict__ wenc, const float* __restrict__ nb,
    _Float16* __restrict__ preact,
    const float* __restrict__ wdec, _Float16* __restrict__ wdt)
{
    __shared__ alignas(16) char smem[24576];   // GEMM: lA 16KB + lB 8KB; epi: 16KB; tr: 16.6KB

    const int tid = threadIdx.x;
    const int chunk = blockIdx.x >> 8;
    const int sub = (chunk >> 1) * 256 + (blockIdx.x & 255);   // [0,2048) per role

    if (chunk & 1) {
        // ---------------- transpose role: 4 tiles of 64x64, fp16 out ----------------
        float* tile = (float*)smem;               // [64][65] floats, scalar LDS ops
        const int r = tid >> 2;                   // [0,64) row (load) / col quarter owner (store)
        const int q4 = (tid & 3) * 16;            // 16-wide quarter
        for (int s = 0; s < 4; ++s) {
            int tix = sub * 4 + s;                // [0,8192)
            int x0 = (tix & 511) * 64;            // M coord
            int y0 = (tix >> 9) * 64;             // D coord
            const float* src = wdec + (size_t)(y0 + r) * M_ + x0 + q4;
            float4 v0 = *(const float4*)(src + 0);
            float4 v1 = *(const float4*)(src + 4);
            float4 v2 = *(const float4*)(src + 8);
            float4 v3 = *(const float4*)(src + 12);
            float* dst = &tile[r * 65 + q4];
            dst[0] = v0.x;  dst[1] = v0.y;  dst[2] = v0.z;  dst[3] = v0.w;
            dst[4] = v1.x;  dst[5] = v1.y;  dst[6] = v1.z;  dst[7] = v1.w;
            dst[8] = v2.x;  dst[9] = v2.y;  dst[10] = v2.z; dst[11] = v2.w;
            dst[12] = v3.x; dst[13] = v3.y; dst[14] = v3.z; dst[15] = v3.w;
            __syncthreads();
            // gather column c = r, rows q4..q4+15 -> 32B contiguous fp16 store
            half8 h0, h1;
#pragma unroll
            for (int i = 0; i < 8; ++i) h0[i] = (_Float16)tile[(q4 + i) * 65 + r];
#pragma unroll
            for (int i = 0; i < 8; ++i) h1[i] = (_Float16)tile[(q4 + 8 + i) * 65 + r];
            _Float16* od = wdt + (size_t)(x0 + r) * D_ + y0 + q4;
            *(half8*)(od + 0) = h0;
            *(half8*)(od + 8) = h1;
            __syncthreads();
        }
        return;
    }

    // ---------------- GEMM role ----------------
    _Float16* lA0 = (_Float16*)smem;            // [2][128*32] halfs
    _Float16* lB0 = (_Float16*)(smem + 16384);  // [2][64*32] halfs

    const int lane = tid & 63;
    const int wv = tid >> 6;
    const int wvr = wv >> 1;          // 0..1 -> M half (64 rows)
    const int wvc = wv & 1;           // 0..1 -> N half (32 cols)

    const int bid = sub;
    const int lb = bid >> 3;                      // [0,256)
    const int j0 = ((bid & 7) * 64 + (lb >> 2)) * 64;
    const int i0 = (lb & 3) * 128;

    const int ln15 = lane & 15;
    const int kq = (lane >> 4) * 8;   // half index of 16B chunk within 64B row

    f32x4 acc1[4][2];
#pragma unroll
    for (int r = 0; r < 4; ++r)
#pragma unroll
        for (int c = 0; c < 2; ++c)
            acc1[r][c] = (f32x4){0.f, 0.f, 0.f, 0.f};

    const int o0 = tid * 16;                // [0,4096)
    const int o1 = o0 + 4096;               // [4096,8192)
    const int rA0 = o0 >> 6, rA1 = o1 >> 6; // [0,64), [64,128)
    const int cA0s = (o0 & 63) ^ (((rA0 >> 1) & 3) << 4);
    const int cA1s = (o1 & 63) ^ (((rA1 >> 1) & 3) << 4);

    const int rW = tid >> 2;                 // [0,64)
    const int c8 = (tid & 3) * 8;
    const int c8s = c8 ^ (((rW >> 1) & 3) << 3);

    const int rowA = wvr * 64 + ln15;
    const int rowB = wvc * 32 + ln15;

#define STAGEA(k0, s)                                                                      \
    do {                                                                                   \
        gld16((const char*)(xhf + (size_t)(i0 + rA0) * 1024 + (k0)) + cA0s, (char*)lA0 + (s) * 8192 + o0); \
        gld16((const char*)(xhf + (size_t)(i0 + rA1) * 1024 + (k0)) + cA1s, (char*)lA0 + (s) * 8192 + o1); \
    } while (0)

#define LOADB(k0)                                                                          \
    do {                                                                                   \
        const float* wp = wenc + (size_t)(j0 + rW) * 1024 + (k0) + c8;                     \
        wv0 = *(const float4*)wp;                                                          \
        wv1 = *(const float4*)(wp + 4);                                                    \
    } while (0)

#define CVT1(idx, f) do { bh[idx] = (_Float16)((f) * 2048.0f); } while (0)

#define WRITEB(s)                                                                          \
    do {                                                                                   \
        half8 bh;                                                                          \
        CVT1(0, wv0.x); CVT1(1, wv0.y); CVT1(2, wv0.z); CVT1(3, wv0.w);                    \
        CVT1(4, wv1.x); CVT1(5, wv1.y); CVT1(6, wv1.z); CVT1(7, wv1.w);                    \
        *(half8*)&lB0[(s) * 2048 + rW * 32 + c8s] = bh;                                    \
    } while (0)

    float4 wv0, wv1;
    // ---- prologue: tiles 0,1 ----
    LOADB(0);
    asm volatile("s_waitcnt vmcnt(0)" ::: "memory");
    WRITEB(0);
    STAGEA(0, 0);
    LOADB(32);
    STAGEA(32, 1);
    asm volatile("s_waitcnt vmcnt(2)" ::: "memory");   // drains A(0)+B(32) regs; A(32) flying
    WRITEB(1);
    asm volatile("s_waitcnt lgkmcnt(0)" ::: "memory");
    __builtin_amdgcn_s_barrier();

    int cur = 0;
    for (int k0 = 0; k0 < 1024; k0 += 32) {
        if (k0 + 64 < 1024) LOADB(k0 + 64);   // B(k+2) reg-loads fly under MFMA

        half8 aH[4], bH[2];
#pragma unroll
        for (int r = 0; r < 4; ++r) {
            const int ra = rowA + r * 16;
            const int ka = kq ^ (((ra >> 1) & 3) << 3);
            aH[r] = *(const half8*)&lA0[cur * 4096 + ra * 32 + ka];
        }
#pragma unroll
        for (int c = 0; c < 2; ++c) {
            const int rb = rowB + c * 16;
            const int kb = kq ^ (((rb >> 1) & 3) << 3);
            bH[c] = *(const half8*)&lB0[cur * 2048 + rb * 32 + kb];
        }
#pragma unroll
        for (int r = 0; r < 4; ++r)
#pragma unroll
            for (int c = 0; c < 2; ++c)
                acc1[r][c] = __builtin_amdgcn_mfma_f32_16x16x32_f16(aH[r], bH[c], acc1[r][c], 0, 0, 0);

        if (k0 + 32 < 1024) {
            asm volatile("s_waitcnt lgkmcnt(0)" ::: "memory");
            __builtin_amdgcn_s_barrier();

            if (k0 + 64 < 1024) {
                STAGEA(k0 + 64, cur);                              // +2 glds
                asm volatile("s_waitcnt vmcnt(2)" ::: "memory");   // drain A(k+1) glds + B(k+2) regs
                WRITEB(cur);
            } else {
                asm volatile("s_waitcnt vmcnt(0)" ::: "memory");
            }
            asm volatile("s_waitcnt lgkmcnt(0)" ::: "memory");
            __builtin_amdgcn_s_barrier();
        }
        cur ^= 1;
    }
#undef STAGEA
#undef LOADB
#undef CVT1
#undef WRITEB

    // ---- epilogue: repack C-tile via LDS, 16B-per-thread coalesced stores ----
    asm volatile("s_waitcnt lgkmcnt(0)" ::: "memory");
    __builtin_amdgcn_s_barrier();                    // all waves done with lA/lB
    _Float16* ct = (_Float16*)smem;                  // [128][64] halfs, 16KB
    const float s1 = 0x1p-22f;
#pragma unroll
    for (int c = 0; c < 2; ++c) {
        int n = wvc * 32 + c * 16 + ln15;            // tile-local col
        float nbv = nb[j0 + n];
#pragma unroll
        for (int r = 0; r < 4; ++r) {
            int mb = wvr * 64 + r * 16 + (lane >> 4) * 4;   // tile-local row
#pragma unroll
            for (int e = 0; e < 4; ++e)
                ct[(mb + e) * 64 + n] = (_Float16)(acc1[r][c][e] * s1 + nbv);
        }
    }
    __syncthreads();
#pragma unroll
    for (int s = 0; s < 4; ++s) {
        int idx = s * 256 + tid;                     // [0,1024) 16B chunks
        int row = idx >> 3;                          // [0,128)
        int off8 = (idx & 7) * 8;                    // half offset within 64
        *(half8*)(preact + (size_t)(i0 + row) * M_ + j0 + off8) = *(half8*)&ct[row * 64 + off8];
    }
}

// ---------- fused select + f64-exact resolve + sparse decode (one block/row) ----------
// Round-11: wdt gather is fp16 (half the bytes).
__global__ __launch_bounds__(1024, 2) void selresdec(
    const _Float16* __restrict__ preact, const int* __restrict__ steps,
    const float* __restrict__ x, const float* __restrict__ ib,
    const float* __restrict__ wenc, const float* __restrict__ nb,
    const _Float16* __restrict__ wdt,
    float* __restrict__ out_tidx, float* __restrict__ out_tval,
    float* __restrict__ out_aidx, float* __restrict__ out_aval,
    float* __restrict__ o_recon, float* __restrict__ o_multik,
    float* __restrict__ o_mat0, float* __restrict__ o_mat1)
{
    __shared__ unsigned histU[4096];
    __shared__ unsigned histM[4096];
    __shared__ unsigned coarseU[256];
    __shared__ unsigned coarseM[256];
    __shared__ unsigned long long candU[512];
    __shared__ unsigned long long candM[512];
    __shared__ double xcs[1024];
    __shared__ double part[160][4];
    __shared__ unsigned long long kU[64];
    __shared__ unsigned long long kM[128];
    __shared__ float vU[64];
    __shared__ float vM[128];
    __shared__ int sidx[128];
    __shared__ float sval[128];
    __shared__ int auxm[96];
    __shared__ int ridx[32];
    __shared__ float rval[32];
    __shared__ unsigned cntU, cntM, thrU, thrM, cbU, cbM, cumU, cumM;

    const int t = threadIdx.x;
    const int b = blockIdx.x;
    const half8* rowh = (const half8*)(preact + (size_t)b * M_);

    for (int i = t; i < 4096; i += 1024) { histU[i] = 0; histM[i] = 0; }
    if (t < 512) { candU[t] = 0ULL; candM[t] = 0ULL; }
    if (t == 0) { cntU = 0; cntM = 0; }
    xcs[t] = (double)x[(size_t)b * 1024 + t] - (double)ib[t];
    if (t < 64)  { kU[t] = 0ULL; vU[t] = 0.f; }
    if (t < 128) { kM[t] = 0ULL; vM[t] = 0.f; }
    __syncthreads();

    // ---- dead mask: bit p*8+e for m = (t + p*1024)*8 + e ----
    unsigned deadmask = 0;
#pragma unroll
    for (int p = 0; p < 4; ++p) {
        int base = 2 * t + 2048 * p;              // int4 index
        int4 s0 = ((const int4*)steps)[base];
        int4 s1 = ((const int4*)steps)[base + 1];
        unsigned mb = 0;
        if (s0.x + 1 > 256) mb |= 1u;
        if (s0.y + 1 > 256) mb |= 2u;
        if (s0.z + 1 > 256) mb |= 4u;
        if (s0.w + 1 > 256) mb |= 8u;
        if (s1.x + 1 > 256) mb |= 16u;
        if (s1.y + 1 > 256) mb |= 32u;
        if (s1.z + 1 > 256) mb |= 64u;
        if (s1.w + 1 > 256) mb |= 128u;
        deadmask |= mb << (p * 8);
    }

    // ---- single memory pass: load fp16 row into registers + histogram ----
    half8 v[4];
#pragma unroll
    for (int p = 0; p < 4; ++p) {
        v[p] = rowh[t + p * 1024];
#pragma unroll
        for (int e = 0; e < 8; ++e) {
            unsigned key = f2k((float)v[p][e]) >> 20;
            atomicAdd(&histU[key], 1u);
            if ((deadmask >> (p * 8 + e)) & 1u) atomicAdd(&histM[key], 1u);
        }
    }
    __syncthreads();

    // ---- coarse sums ----
    if (t < 256) {
        unsigned s = 0;
#pragma unroll
        for (int j = 0; j < 16; ++j) s += histU[t * 16 + j];
        coarseU[t] = s;
    } else if (t < 512) {
        int c = t - 256;
        unsigned s = 0;
#pragma unroll
        for (int j = 0; j < 16; ++j) s += histM[c * 16 + j];
        coarseM[c] = s;
    }
    __syncthreads();

    // ---- joint Hillis-Steele suffix scan ----
    for (int off = 1; off < 256; off <<= 1) {
        unsigned xv = 0;
        if (t < 256)      xv = coarseU[t] + (t + off < 256 ? coarseU[t + off] : 0u);
        else if (t < 512) { int c = t - 256; xv = coarseM[c] + (c + off < 256 ? coarseM[c + off] : 0u); }
        __syncthreads();
        if (t < 256)      coarseU[t] = xv;
        else if (t < 512) coarseM[t - 256] = xv;
        __syncthreads();
    }

    // ---- crossing bins ----
    if (t < 256) {
        unsigned S = coarseU[t];
        unsigned Sn = (t < 255) ? coarseU[t + 1] : 0u;
        if (S >= 128u && (t == 255 || Sn < 128u)) { cbU = (unsigned)t; cumU = Sn; }
    } else if (t < 512) {
        int c = t - 256;
        unsigned S = coarseM[c];
        unsigned Sn = (c < 255) ? coarseM[c + 1] : 0u;
        if (S >= 64u && (c == 255 || Sn < 64u)) { cbM = (unsigned)c; cumM = Sn; }
        if (c == 0 && S < 64u) { cbM = 0u; cumM = Sn; }
    }
    __syncthreads();

    // ---- fine scans ----
    if (t == 0) {
        unsigned cum = cumU;
        int base = (int)cbU * 16, tb = base;
        for (int f = base + 15; f >= base; --f) {
            unsigned h = histU[f];
            if (cum + h >= 128u) { tb = f; break; }
            cum += h;
        }
        thrU = (unsigned)tb;
    }
    if (t == 64) {
        unsigned cum = cumM;
        int base = (int)cbM * 16, tb = base;
        for (int f = base + 15; f >= base; --f) {
            unsigned h = histM[f];
            if (cum + h >= 64u) { tb = f; break; }
            cum += h;
        }
        thrM = (unsigned)(tb > 0 ? tb - 1 : 0);
    }
    __syncthreads();

    const unsigned TU = thrU, TM = thrM;

    // ---- candidate collection straight from registers ----
#pragma unroll
    for (int p = 0; p < 4; ++p) {
#pragma unroll
        for (int e = 0; e < 8; ++e) {
            float val = (float)v[p][e];
            unsigned key = f2k(val);
            int m = (t + p * 1024) * 8 + e;
            if ((key >> 20) >= TU) {
                unsigned pz = atomicAdd(&cntU, 1u);
                if (pz < 512u) candU[pz] = ((unsigned long long)key << 32) | (unsigned)(~m);
            }
            if (((deadmask >> (p * 8 + e)) & 1u) && (key >> 20) >= TM) {
                unsigned pz = atomicAdd(&cntM, 1u);
                if (pz < 512u) candM[pz] = ((unsigned long long)key << 32) | (unsigned)(~m);
            }
        }
    }
    __syncthreads();

    // ---- bitonic sort: threads 0-511 -> candU, 512-1023 -> candM ----
    {
        unsigned long long* arr = (t < 512) ? candU : candM;
        const unsigned i = (unsigned)t & 511u;
        for (unsigned kk = 2; kk <= 512; kk <<= 1) {
            for (unsigned j = kk >> 1; j > 0; j >>= 1) {
                unsigned ixj = i ^ j;
                if (ixj > i) {
                    bool desc = ((i & kk) == 0);
                    unsigned long long a = arr[i], c = arr[ixj];
                    if (desc ? (a < c) : (a > c)) { arr[i] = c; arr[ixj] = a; }
                }
                unsigned nj = (j > 1) ? (j >> 1) : ((kk << 1) <= 512u ? kk : 0u);
                if (j >= 64 || nj >= 64) __syncthreads();
                else asm volatile("s_waitcnt lgkmcnt(0)" ::: "memory");
            }
        }
    }
    __syncthreads();

    // ---- sel/aux into LDS ----
    if (t < 128) {
        unsigned long long c = candU[t];
        unsigned m = ~(unsigned)c;
        float vv = k2f((unsigned)(c >> 32));
        sidx[t] = (int)m;
        sval[t] = vv > 0.f ? vv : 0.f;
    }
    if (t < 96) {
        unsigned long long c = candM[t];
        auxm[t] = c ? (int)(~(unsigned)c) : -1;
    }
    __syncthreads();

    // ---- f64 resolve: 4-way d-split over threads 0-639 ----
    if (t < 640) {
        const int ci = t >> 2, q = t & 3;
        int m = (ci < 64) ? sidx[ci] : auxm[ci - 64];
        if (m >= 0) {
            const float* w = wenc + (size_t)m * 1024 + q * 256;
            const double* xq = xcs + q * 256;
            double a0 = 0.0, a1 = 0.0, a2 = 0.0, a3 = 0.0;
            for (int d = 0; d < 256; d += 4) {
                float4 wv = *(const float4*)(w + d);
                a0 = fma((double)wv.x, xq[d + 0], a0);
                a1 = fma((double)wv.y, xq[d + 1], a1);
                a2 = fma((double)wv.z, xq[d + 2], a2);
                a3 = fma((double)wv.w, xq[d + 3], a3);
            }
            part[ci][q] = ((a0 + a1) + (a2 + a3));
        }
    }
    __syncthreads();

    // ---- combine partials, build keys ----
    if (t < 160) {
        int m = (t < 64) ? sidx[t] : auxm[t - 64];
        if (m >= 0) {
            double vd = ((part[t][0] + part[t][1]) + (part[t][2] + part[t][3])) + (double)nb[m];
            unsigned long long key = (d2k(vd) & 0xFFFFFFFFFFFF0000ull)
                                   | (unsigned long long)((~(unsigned)m) & 0xFFFFu);
            float vf = (float)vd;
            if (t < 64) { kU[t] = key; vU[t] = vf; }
            else        { kM[t - 64] = key; vM[t - 64] = vf; }
        }
    }
    __syncthreads();

    // ---- sort kU (64) and kM (128) ----
    for (unsigned kk = 2; kk <= 128; kk <<= 1) {
        for (unsigned j = kk >> 1; j > 0; j >>= 1) {
            unsigned i = (unsigned)t, ixj = i ^ j;
            if (kk <= 64 && i < 64 && ixj > i) {
                bool desc = ((i & kk) == 0);
                unsigned long long a = kU[i], c = kU[ixj];
                if (desc ? (a < c) : (a > c)) {
                    kU[i] = c; kU[ixj] = a;
                    float fa = vU[i]; vU[i] = vU[ixj]; vU[ixj] = fa;
                }
            }
            if (i < 128 && ixj > i) {
                bool desc = ((i & kk) == 0);
                unsigned long long a = kM[i], c = kM[ixj];
                if (desc ? (a < c) : (a > c)) {
                    kM[i] = c; kM[ixj] = a;
                    float fa = vM[i]; vM[i] = vM[ixj]; vM[ixj] = fa;
                }
            }
            __syncthreads();
        }
    }

    if (t < 32) {
        unsigned mm = (~(unsigned)kU[t]) & 0xFFFFu;
        float vv = vU[t];
        float rv = vv > 0.f ? vv : 0.f;
        ridx[t] = (int)mm;
        rval[t] = rv;
        out_tidx[b * 32 + t] = (float)mm;
        out_tval[b * 32 + t] = rv;
    }
    if (t < 64) {
        unsigned mm = (~(unsigned)kM[t]) & 0xFFFFu;
        float vv = vM[t];
        out_aidx[b * 64 + t] = (float)mm;
        out_aval[b * 64 + t] = vv > 0.f ? vv : 0.f;
    }
    __syncthreads();

    // ---- sparse decode: thread t owns output element d=t (k ascending) ----
    {
        const int d = t;
        float bias = ib[d];
        float mul = bias, rec = bias, m0 = bias, m1 = bias;
        for (int k = 0; k < 128; ++k) {
            float vv = sval[k];
            float w = (float)wdt[(size_t)sidx[k] * D_ + d];
            mul += vv * w;
        }
        for (int k = 0; k < 32; ++k) {
            int idx = ridx[k];
            float vv = rval[k];
            float w = (float)wdt[(size_t)idx * D_ + d];
            rec += vv * w;
            if (idx < 16384) {
                m1 += vv * w;
                if (idx < 4096) m0 += vv * w;
            }
        }
        size_t o = (size_t)b * D_ + d;
        o_recon[o]  = rec;
        o_multik[o] = mul;
        o_mat0[o]   = m0;
        o_mat1[o]   = m1;
    }
}

extern "C" void kernel_launch(void* const* d_in, const int* in_sizes, int n_in,
                              void* d_out, int out_size, void* d_ws, size_t ws_size,
                              hipStream_t stream)
{
    const float* x     = (const float*)d_in[0];
    const float* wenc  = (const float*)d_in[1];
    const float* wdec  = (const float*)d_in[2];
    const float* ib    = (const float*)d_in[3];
    const float* nb    = (const float*)d_in[4];
    const int*   steps = (const int*)d_in[5];
    float* out = (float*)d_out;

    char* ws = (char*)d_ws;
    _Float16*  preact  = (_Float16*)ws;                           // [0, 32MB)
    _Float16*  wdt     = (_Float16*)(ws + 67108864);              // [64MB, 128MB)
    _Float16*  xhf     = (_Float16*)(ws + 201326592);             // [192MB, +1MB)

    float* out_recon  = out;
    float* out_multik = out + 524288;
    float* out_mat0   = out + 1048576;
    float* out_mat1   = out + 1572864;
    float* out_tidx   = out + 2097152;
    float* out_tval   = out + 2097152 + 16384;
    float* out_aidx   = out + 2097152 + 32768;
    float* out_aval   = out + 2097152 + 32768 + 32768;

    split_x_k<<<dim3(512), dim3(256), 0, stream>>>(x, ib, xhf);
    enc_tr<<<dim3(4096), dim3(256), 0, stream>>>(xhf, wenc, nb, preact, wdec, wdt);
    selresdec<<<dim3(512), dim3(1024), 0, stream>>>(
        preact, steps, x, ib, wenc, nb, wdt,
        out_tidx, out_tval, out_aidx, out_aval,
        out_recon, out_multik, out_mat0, out_mat1);
}

// Round 12
// 479.977 us; speedup vs baseline: 1.7270x; 1.0164x over previous
//
#include <hip/hip_runtime.h>
#include <stdint.h>

#define B_ 512
#define D_ 1024
#define M_ 32768

typedef _Float16 half8 __attribute__((ext_vector_type(8)));
typedef _Float16 half4 __attribute__((ext_vector_type(4)));
typedef float f32x4 __attribute__((ext_vector_type(4)));

// ---------- sortable key helpers (monotonic float <-> u32) ----------
__device__ __forceinline__ unsigned f2k(float f) {
    unsigned b = __float_as_uint(f);
    return (b & 0x80000000u) ? ~b : (b | 0x80000000u);
}
__device__ __forceinline__ float k2f(unsigned k) {
    unsigned b = (k & 0x80000000u) ? (k & 0x7FFFFFFFu) : ~k;
    return __uint_as_float(b);
}
// monotonic double -> u64 key
__device__ __forceinline__ unsigned long long d2k(double d) {
    unsigned long long b = (unsigned long long)__double_as_longlong(d);
    return (b & 0x8000000000000000ull) ? ~b : (b | 0x8000000000000000ull);
}

// ---------- async global->LDS (16B per lane, wave-uniform base + lane*16) ----------
__device__ __forceinline__ void gld16(const void* g, void* l) {
    __builtin_amdgcn_global_load_lds(
        (__attribute__((address_space(1))) void*)(uintptr_t)g,
        (__attribute__((address_space(3))) void*)(unsigned)(uintptr_t)l,
        16, 0, 0);
}

// ---------- split x: xc = (x - ib) * 2048 -> fp16 hi ----------
__global__ __launch_bounds__(256) void split_x_k(
    const float* __restrict__ x, const float* __restrict__ ib,
    _Float16* __restrict__ xh)
{
    int i = blockIdx.x * 256 + threadIdx.x;   // float4 index, 131072 total
    float4 v = ((const float4*)x)[i];
    float4 bb = ((const float4*)ib)[i & 255];
    float a0 = (v.x - bb.x) * 2048.0f;
    float a1 = (v.y - bb.y) * 2048.0f;
    float a2 = (v.z - bb.z) * 2048.0f;
    float a3 = (v.w - bb.w) * 2048.0f;
    half4 hv = {(_Float16)a0, (_Float16)a1, (_Float16)a2, (_Float16)a3};
    ((half4*)xh)[i] = hv;
}

// ---------- fused encoder GEMM + W_dec transpose (grid role-split) ----------
// Round-12: GEMM j-tile widened 64 -> 128 (tile 128x128, 16 MFMA/step,
// 1024 GEMM blocks) -> 2x matrix work per barrier pair, half the barrier
// events. Grid 3072 = 12 chunks of 256: chunk%3==0 -> GEMM (4 chunks),
// else tr (8 chunks). K-order per output unchanged -> preact bit-identical.
__global__ __launch_bounds__(256, 3) void enc_tr(
    const _Float16* __restrict__ xhf,
    const float* __restrict__ wenc, const float* __restrict__ nb,
    _Float16* __restrict__ preact,
    const float* __restrict__ wdec, _Float16* __restrict__ wdt)
{
    __shared__ alignas(16) char smem[32768];   // GEMM: lA 16KB + lB 16KB; epi 32KB; tr 16.6KB

    const int tid = threadIdx.x;
    const int chunk = blockIdx.x >> 8;

    if (chunk % 3 != 0) {
        // ---------------- transpose role: 4 tiles of 64x64, fp16 out ----------------
        const int sub = (chunk - 1 - chunk / 3) * 256 + (blockIdx.x & 255);  // [0,2048)
        float* tile = (float*)smem;               // [64][65] floats
        const int r = tid >> 2;                   // [0,64)
        const int q4 = (tid & 3) * 16;            // 16-wide quarter
        for (int s = 0; s < 4; ++s) {
            int tix = sub * 4 + s;                // [0,8192)
            int x0 = (tix & 511) * 64;            // M coord
            int y0 = (tix >> 9) * 64;             // D coord
            const float* src = wdec + (size_t)(y0 + r) * M_ + x0 + q4;
            float4 v0 = *(const float4*)(src + 0);
            float4 v1 = *(const float4*)(src + 4);
            float4 v2 = *(const float4*)(src + 8);
            float4 v3 = *(const float4*)(src + 12);
            float* dst = &tile[r * 65 + q4];
            dst[0] = v0.x;  dst[1] = v0.y;  dst[2] = v0.z;  dst[3] = v0.w;
            dst[4] = v1.x;  dst[5] = v1.y;  dst[6] = v1.z;  dst[7] = v1.w;
            dst[8] = v2.x;  dst[9] = v2.y;  dst[10] = v2.z; dst[11] = v2.w;
            dst[12] = v3.x; dst[13] = v3.y; dst[14] = v3.z; dst[15] = v3.w;
            __syncthreads();
            half8 h0, h1;
#pragma unroll
            for (int i = 0; i < 8; ++i) h0[i] = (_Float16)tile[(q4 + i) * 65 + r];
#pragma unroll
            for (int i = 0; i < 8; ++i) h1[i] = (_Float16)tile[(q4 + 8 + i) * 65 + r];
            _Float16* od = wdt + (size_t)(x0 + r) * D_ + y0 + q4;
            *(half8*)(od + 0) = h0;
            *(half8*)(od + 8) = h1;
            __syncthreads();
        }
        return;
    }

    // ---------------- GEMM role: 128x128 tile ----------------
    _Float16* lA0 = (_Float16*)smem;            // [2][128*32] halfs (16KB)
    _Float16* lB0 = (_Float16*)(smem + 16384);  // [2][128*32] halfs (16KB)

    const int sub = (chunk / 3) * 256 + (blockIdx.x & 255);   // [0,1024)
    const int lane = tid & 63;
    const int wv = tid >> 6;
    const int wvr = wv >> 1;          // 0..1 -> M half (64 rows)
    const int wvc = wv & 1;           // 0..1 -> N half (64 cols)

    const int lb = sub >> 3;                      // [0,128)
    const int j0 = ((sub & 7) * 32 + (lb >> 2)) * 128;
    const int i0 = (lb & 3) * 128;

    const int ln15 = lane & 15;
    const int kq = (lane >> 4) * 8;   // half index of 16B chunk within 64B row

    f32x4 acc1[4][4];
#pragma unroll
    for (int r = 0; r < 4; ++r)
#pragma unroll
        for (int c = 0; c < 4; ++c)
            acc1[r][c] = (f32x4){0.f, 0.f, 0.f, 0.f};

    const int o0 = tid * 16;                // [0,4096)
    const int o1 = o0 + 4096;               // [4096,8192)
    const int rA0 = o0 >> 6, rA1 = o1 >> 6; // [0,64), [64,128)
    const int cA0s = (o0 & 63) ^ (((rA0 >> 1) & 3) << 4);
    const int cA1s = (o1 & 63) ^ (((rA1 >> 1) & 3) << 4);

    const int rW = tid >> 1;                 // [0,128)
    const int c16 = (tid & 1) * 16;          // half/float index within 32-wide k
    const int sw = ((rW >> 1) & 3) << 3;     // swizzle for 8-half groups
    const int g0 = c16 ^ sw;                 // swizzled group starts
    const int g1 = (c16 + 8) ^ sw;

    const int rowA = wvr * 64 + ln15;
    const int rowB = wvc * 64 + ln15;

#define STAGEA(k0, s)                                                                      \
    do {                                                                                   \
        gld16((const char*)(xhf + (size_t)(i0 + rA0) * 1024 + (k0)) + cA0s, (char*)lA0 + (s) * 8192 + o0); \
        gld16((const char*)(xhf + (size_t)(i0 + rA1) * 1024 + (k0)) + cA1s, (char*)lA0 + (s) * 8192 + o1); \
    } while (0)

#define LOADB(k0)                                                                          \
    do {                                                                                   \
        const float* wp = wenc + (size_t)(j0 + rW) * 1024 + (k0) + c16;                    \
        wv0 = *(const float4*)wp;                                                          \
        wv1 = *(const float4*)(wp + 4);                                                    \
        wv2 = *(const float4*)(wp + 8);                                                    \
        wv3 = *(const float4*)(wp + 12);                                                   \
    } while (0)

#define WRITEB(s)                                                                          \
    do {                                                                                   \
        half8 b0, b1;                                                                      \
        b0[0] = (_Float16)(wv0.x * 2048.0f); b0[1] = (_Float16)(wv0.y * 2048.0f);          \
        b0[2] = (_Float16)(wv0.z * 2048.0f); b0[3] = (_Float16)(wv0.w * 2048.0f);          \
        b0[4] = (_Float16)(wv1.x * 2048.0f); b0[5] = (_Float16)(wv1.y * 2048.0f);          \
        b0[6] = (_Float16)(wv1.z * 2048.0f); b0[7] = (_Float16)(wv1.w * 2048.0f);          \
        b1[0] = (_Float16)(wv2.x * 2048.0f); b1[1] = (_Float16)(wv2.y * 2048.0f);          \
        b1[2] = (_Float16)(wv2.z * 2048.0f); b1[3] = (_Float16)(wv2.w * 2048.0f);          \
        b1[4] = (_Float16)(wv3.x * 2048.0f); b1[5] = (_Float16)(wv3.y * 2048.0f);          \
        b1[6] = (_Float16)(wv3.z * 2048.0f); b1[7] = (_Float16)(wv3.w * 2048.0f);          \
        *(half8*)&lB0[(s) * 4096 + rW * 32 + g0] = b0;                                     \
        *(half8*)&lB0[(s) * 4096 + rW * 32 + g1] = b1;                                     \
    } while (0)

    float4 wv0, wv1, wv2, wv3;
    // ---- prologue: tiles 0,1 ----
    LOADB(0);
    asm volatile("s_waitcnt vmcnt(0)" ::: "memory");
    WRITEB(0);
    STAGEA(0, 0);
    LOADB(32);
    STAGEA(32, 1);
    asm volatile("s_waitcnt vmcnt(2)" ::: "memory");   // drains A(0)+B(32) regs; A(32) flying
    WRITEB(1);
    asm volatile("s_waitcnt lgkmcnt(0)" ::: "memory");
    __builtin_amdgcn_s_barrier();

    int cur = 0;
    for (int k0 = 0; k0 < 1024; k0 += 32) {
        if (k0 + 64 < 1024) LOADB(k0 + 64);   // B(k+2) reg-loads fly under MFMA

        half8 aH[4], bH[4];
#pragma unroll
        for (int r = 0; r < 4; ++r) {
            const int ra = rowA + r * 16;
            const int ka = kq ^ (((ra >> 1) & 3) << 3);
            aH[r] = *(const half8*)&lA0[cur * 4096 + ra * 32 + ka];
        }
#pragma unroll
        for (int c = 0; c < 4; ++c) {
            const int rb = rowB + c * 16;
            const int kb = kq ^ (((rb >> 1) & 3) << 3);
            bH[c] = *(const half8*)&lB0[cur * 4096 + rb * 32 + kb];
        }
#pragma unroll
        for (int r = 0; r < 4; ++r)
#pragma unroll
            for (int c = 0; c < 4; ++c)
                acc1[r][c] = __builtin_amdgcn_mfma_f32_16x16x32_f16(aH[r], bH[c], acc1[r][c], 0, 0, 0);

        if (k0 + 32 < 1024) {
            asm volatile("s_waitcnt lgkmcnt(0)" ::: "memory");
            __builtin_amdgcn_s_barrier();

            if (k0 + 64 < 1024) {
                STAGEA(k0 + 64, cur);                              // +2 glds
                asm volatile("s_waitcnt vmcnt(2)" ::: "memory");   // drain A(k+1) glds + B(k+2) regs
                WRITEB(cur);
            } else {
                asm volatile("s_waitcnt vmcnt(0)" ::: "memory");
            }
            asm volatile("s_waitcnt lgkmcnt(0)" ::: "memory");
            __builtin_amdgcn_s_barrier();
        }
        cur ^= 1;
    }
#undef STAGEA
#undef LOADB
#undef WRITEB

    // ---- epilogue: repack C-tile via LDS, 16B-per-thread coalesced stores ----
    asm volatile("s_waitcnt lgkmcnt(0)" ::: "memory");
    __builtin_amdgcn_s_barrier();                    // all waves done with lA/lB
    _Float16* ct = (_Float16*)smem;                  // [128][128] halfs, 32KB
    const float s1 = 0x1p-22f;
#pragma unroll
    for (int c = 0; c < 4; ++c) {
        int n = wvc * 64 + c * 16 + ln15;            // tile-local col
        float nbv = nb[j0 + n];
#pragma unroll
        for (int r = 0; r < 4; ++r) {
            int mb = wvr * 64 + r * 16 + (lane >> 4) * 4;   // tile-local row
#pragma unroll
            for (int e = 0; e < 4; ++e)
                ct[(mb + e) * 128 + n] = (_Float16)(acc1[r][c][e] * s1 + nbv);
        }
    }
    __syncthreads();
#pragma unroll
    for (int s = 0; s < 8; ++s) {
        int idx = s * 256 + tid;                     // [0,2048) 16B chunks
        int row = idx >> 4;                          // [0,128)
        int off8 = (idx & 15) * 8;                   // half offset within 128
        *(half8*)(preact + (size_t)(i0 + row) * M_ + j0 + off8) = *(half8*)&ct[row * 128 + off8];
    }
}

// ---------- fused select + f64-exact resolve + sparse decode (one block/row) ----------
// Round-12: resolve 8-way over 1024 threads, 128 candidates (48 U + 80 M;
// exact-top-32 within approx-top-48 and exact-top-64 within approx-top-80,
// margins ~16 ranks ~0.02-0.08 vs ~1.5e-3 approx error).
__global__ __launch_bounds__(1024, 2) void selresdec(
    const _Float16* __restrict__ preact, const int* __restrict__ steps,
    const float* __restrict__ x, const float* __restrict__ ib,
    const float* __restrict__ wenc, const float* __restrict__ nb,
    const _Float16* __restrict__ wdt,
    float* __restrict__ out_tidx, float* __restrict__ out_tval,
    float* __restrict__ out_aidx, float* __restrict__ out_aval,
    float* __restrict__ o_recon, float* __restrict__ o_multik,
    float* __restrict__ o_mat0, float* __restrict__ o_mat1)
{
    __shared__ unsigned histU[4096];
    __shared__ unsigned histM[4096];
    __shared__ unsigned coarseU[256];
    __shared__ unsigned coarseM[256];
    __shared__ unsigned long long candU[512];
    __shared__ unsigned long long candM[512];
    __shared__ double xcs[1024];
    __shared__ double part[128][8];
    __shared__ unsigned long long kU[64];
    __shared__ unsigned long long kM[128];
    __shared__ float vU[64];
    __shared__ float vM[128];
    __shared__ int sidx[128];
    __shared__ float sval[128];
    __shared__ int auxm[80];
    __shared__ int ridx[32];
    __shared__ float rval[32];
    __shared__ unsigned cntU, cntM, thrU, thrM, cbU, cbM, cumU, cumM;

    const int t = threadIdx.x;
    const int b = blockIdx.x;
    const half8* rowh = (const half8*)(preact + (size_t)b * M_);

    for (int i = t; i < 4096; i += 1024) { histU[i] = 0; histM[i] = 0; }
    if (t < 512) { candU[t] = 0ULL; candM[t] = 0ULL; }
    if (t == 0) { cntU = 0; cntM = 0; }
    xcs[t] = (double)x[(size_t)b * 1024 + t] - (double)ib[t];
    if (t < 64)  { kU[t] = 0ULL; vU[t] = 0.f; }
    if (t < 128) { kM[t] = 0ULL; vM[t] = 0.f; }
    __syncthreads();

    // ---- dead mask: bit p*8+e for m = (t + p*1024)*8 + e ----
    unsigned deadmask = 0;
#pragma unroll
    for (int p = 0; p < 4; ++p) {
        int base = 2 * t + 2048 * p;              // int4 index
        int4 s0 = ((const int4*)steps)[base];
        int4 s1 = ((const int4*)steps)[base + 1];
        unsigned mb = 0;
        if (s0.x + 1 > 256) mb |= 1u;
        if (s0.y + 1 > 256) mb |= 2u;
        if (s0.z + 1 > 256) mb |= 4u;
        if (s0.w + 1 > 256) mb |= 8u;
        if (s1.x + 1 > 256) mb |= 16u;
        if (s1.y + 1 > 256) mb |= 32u;
        if (s1.z + 1 > 256) mb |= 64u;
        if (s1.w + 1 > 256) mb |= 128u;
        deadmask |= mb << (p * 8);
    }

    // ---- single memory pass: load fp16 row into registers + histogram ----
    half8 v[4];
#pragma unroll
    for (int p = 0; p < 4; ++p) {
        v[p] = rowh[t + p * 1024];
#pragma unroll
        for (int e = 0; e < 8; ++e) {
            unsigned key = f2k((float)v[p][e]) >> 20;
            atomicAdd(&histU[key], 1u);
            if ((deadmask >> (p * 8 + e)) & 1u) atomicAdd(&histM[key], 1u);
        }
    }
    __syncthreads();

    // ---- coarse sums ----
    if (t < 256) {
        unsigned s = 0;
#pragma unroll
        for (int j = 0; j < 16; ++j) s += histU[t * 16 + j];
        coarseU[t] = s;
    } else if (t < 512) {
        int c = t - 256;
        unsigned s = 0;
#pragma unroll
        for (int j = 0; j < 16; ++j) s += histM[c * 16 + j];
        coarseM[c] = s;
    }
    __syncthreads();

    // ---- joint Hillis-Steele suffix scan ----
    for (int off = 1; off < 256; off <<= 1) {
        unsigned xv = 0;
        if (t < 256)      xv = coarseU[t] + (t + off < 256 ? coarseU[t + off] : 0u);
        else if (t < 512) { int c = t - 256; xv = coarseM[c] + (c + off < 256 ? coarseM[c + off] : 0u); }
        __syncthreads();
        if (t < 256)      coarseU[t] = xv;
        else if (t < 512) coarseM[t - 256] = xv;
        __syncthreads();
    }

    // ---- crossing bins ----
    if (t < 256) {
        unsigned S = coarseU[t];
        unsigned Sn = (t < 255) ? coarseU[t + 1] : 0u;
        if (S >= 128u && (t == 255 || Sn < 128u)) { cbU = (unsigned)t; cumU = Sn; }
    } else if (t < 512) {
        int c = t - 256;
        unsigned S = coarseM[c];
        unsigned Sn = (c < 255) ? coarseM[c + 1] : 0u;
        if (S >= 64u && (c == 255 || Sn < 64u)) { cbM = (unsigned)c; cumM = Sn; }
        if (c == 0 && S < 64u) { cbM = 0u; cumM = Sn; }
    }
    __syncthreads();

    // ---- fine scans ----
    if (t == 0) {
        unsigned cum = cumU;
        int base = (int)cbU * 16, tb = base;
        for (int f = base + 15; f >= base; --f) {
            unsigned h = histU[f];
            if (cum + h >= 128u) { tb = f; break; }
            cum += h;
        }
        thrU = (unsigned)tb;
    }
    if (t == 64) {
        unsigned cum = cumM;
        int base = (int)cbM * 16, tb = base;
        for (int f = base + 15; f >= base; --f) {
            unsigned h = histM[f];
            if (cum + h >= 64u) { tb = f; break; }
            cum += h;
        }
        thrM = (unsigned)(tb > 0 ? tb - 1 : 0);
    }
    __syncthreads();

    const unsigned TU = thrU, TM = thrM;

    // ---- candidate collection straight from registers ----
#pragma unroll
    for (int p = 0; p < 4; ++p) {
#pragma unroll
        for (int e = 0; e < 8; ++e) {
            float val = (float)v[p][e];
            unsigned key = f2k(val);
            int m = (t + p * 1024) * 8 + e;
            if ((key >> 20) >= TU) {
                unsigned pz = atomicAdd(&cntU, 1u);
                if (pz < 512u) candU[pz] = ((unsigned long long)key << 32) | (unsigned)(~m);
            }
            if (((deadmask >> (p * 8 + e)) & 1u) && (key >> 20) >= TM) {
                unsigned pz = atomicAdd(&cntM, 1u);
                if (pz < 512u) candM[pz] = ((unsigned long long)key << 32) | (unsigned)(~m);
            }
        }
    }
    __syncthreads();

    // ---- bitonic sort: threads 0-511 -> candU, 512-1023 -> candM ----
    {
        unsigned long long* arr = (t < 512) ? candU : candM;
        const unsigned i = (unsigned)t & 511u;
        for (unsigned kk = 2; kk <= 512; kk <<= 1) {
            for (unsigned j = kk >> 1; j > 0; j >>= 1) {
                unsigned ixj = i ^ j;
                if (ixj > i) {
                    bool desc = ((i & kk) == 0);
                    unsigned long long a = arr[i], c = arr[ixj];
                    if (desc ? (a < c) : (a > c)) { arr[i] = c; arr[ixj] = a; }
                }
                unsigned nj = (j > 1) ? (j >> 1) : ((kk << 1) <= 512u ? kk : 0u);
                if (j >= 64 || nj >= 64) __syncthreads();
                else asm volatile("s_waitcnt lgkmcnt(0)" ::: "memory");
            }
        }
    }
    __syncthreads();

    // ---- sel/aux into LDS ----
    if (t < 128) {
        unsigned long long c = candU[t];
        unsigned m = ~(unsigned)c;
        float vv = k2f((unsigned)(c >> 32));
        sidx[t] = (int)m;
        sval[t] = vv > 0.f ? vv : 0.f;
    }
    if (t < 80) {
        unsigned long long c = candM[t];
        auxm[t] = c ? (int)(~(unsigned)c) : -1;
    }
    __syncthreads();

    // ---- f64 resolve: 8-way d-split over all 1024 threads, 128 candidates ----
    {
        const int ci = t >> 3, q = t & 7;
        int m = (ci < 48) ? sidx[ci] : auxm[ci - 48];
        if (m >= 0) {
            const float* w = wenc + (size_t)m * 1024 + q * 128;
            const double* xq = xcs + q * 128;
            double a0 = 0.0, a1 = 0.0, a2 = 0.0, a3 = 0.0;
            for (int d = 0; d < 128; d += 4) {
                float4 wv = *(const float4*)(w + d);
                a0 = fma((double)wv.x, xq[d + 0], a0);
                a1 = fma((double)wv.y, xq[d + 1], a1);
                a2 = fma((double)wv.z, xq[d + 2], a2);
                a3 = fma((double)wv.w, xq[d + 3], a3);
            }
            part[ci][q] = ((a0 + a1) + (a2 + a3));
        }
    }
    __syncthreads();

    // ---- combine partials, build keys ----
    if (t < 128) {
        int m = (t < 48) ? sidx[t] : auxm[t - 48];
        if (m >= 0) {
            double vd = (((part[t][0] + part[t][1]) + (part[t][2] + part[t][3]))
                       + ((part[t][4] + part[t][5]) + (part[t][6] + part[t][7])))
                      + (double)nb[m];
            unsigned long long key = (d2k(vd) & 0xFFFFFFFFFFFF0000ull)
                                   | (unsigned long long)((~(unsigned)m) & 0xFFFFu);
            float vf = (float)vd;
            if (t < 48) { kU[t] = key; vU[t] = vf; }
            else        { kM[t - 48] = key; vM[t - 48] = vf; }
        }
    }
    __syncthreads();

    // ---- sort kU (64) and kM (128) ----
    for (unsigned kk = 2; kk <= 128; kk <<= 1) {
        for (unsigned j = kk >> 1; j > 0; j >>= 1) {
            unsigned i = (unsigned)t, ixj = i ^ j;
            if (kk <= 64 && i < 64 && ixj > i) {
                bool desc = ((i & kk) == 0);
                unsigned long long a = kU[i], c = kU[ixj];
                if (desc ? (a < c) : (a > c)) {
                    kU[i] = c; kU[ixj] = a;
                    float fa = vU[i]; vU[i] = vU[ixj]; vU[ixj] = fa;
                }
            }
            if (i < 128 && ixj > i) {
                bool desc = ((i & kk) == 0);
                unsigned long long a = kM[i], c = kM[ixj];
                if (desc ? (a < c) : (a > c)) {
                    kM[i] = c; kM[ixj] = a;
                    float fa = vM[i]; vM[i] = vM[ixj]; vM[ixj] = fa;
                }
            }
            __syncthreads();
        }
    }

    if (t < 32) {
        unsigned mm = (~(unsigned)kU[t]) & 0xFFFFu;
        float vv = vU[t];
        float rv = vv > 0.f ? vv : 0.f;
        ridx[t] = (int)mm;
        rval[t] = rv;
        out_tidx[b * 32 + t] = (float)mm;
        out_tval[b * 32 + t] = rv;
    }
    if (t < 64) {
        unsigned mm = (~(unsigned)kM[t]) & 0xFFFFu;
        float vv = vM[t];
        out_aidx[b * 64 + t] = (float)mm;
        out_aval[b * 64 + t] = vv > 0.f ? vv : 0.f;
    }
    __syncthreads();

    // ---- sparse decode: thread t owns output element d=t (k ascending) ----
    {
        const int d = t;
        float bias = ib[d];
        float mul = bias, rec = bias, m0 = bias, m1 = bias;
        for (int k = 0; k < 128; ++k) {
            float vv = sval[k];
            float w = (float)wdt[(size_t)sidx[k] * D_ + d];
            mul += vv * w;
        }
        for (int k = 0; k < 32; ++k) {
            int idx = ridx[k];
            float vv = rval[k];
            float w = (float)wdt[(size_t)idx * D_ + d];
            rec += vv * w;
            if (idx < 16384) {
                m1 += vv * w;
                if (idx < 4096) m0 += vv * w;
            }
        }
        size_t o = (size_t)b * D_ + d;
        o_recon[o]  = rec;
        o_multik[o] = mul;
        o_mat0[o]   = m0;
        o_mat1[o]   = m1;
    }
}

extern "C" void kernel_launch(void* const* d_in, const int* in_sizes, int n_in,
                              void* d_out, int out_size, void* d_ws, size_t ws_size,
                              hipStream_t stream)
{
    const float* x     = (const float*)d_in[0];
    const float* wenc  = (const float*)d_in[1];
    const float* wdec  = (const float*)d_in[2];
    const float* ib    = (const float*)d_in[3];
    const float* nb    = (const float*)d_in[4];
    const int*   steps = (const int*)d_in[5];
    float* out = (float*)d_out;

    char* ws = (char*)d_ws;
    _Float16*  preact  = (_Float16*)ws;                           // [0, 32MB)
    _Float16*  wdt     = (_Float16*)(ws + 67108864);              // [64MB, 128MB)
    _Float16*  xhf     = (_Float16*)(ws + 201326592);             // [192MB, +1MB)

    float* out_recon  = out;
    float* out_multik = out + 524288;
    float* out_mat0   = out + 1048576;
    float* out_mat1   = out + 1572864;
    float* out_tidx   = out + 2097152;
    float* out_tval   = out + 2097152 + 16384;
    float* out_aidx   = out + 2097152 + 32768;
    float* out_aval   = out + 2097152 + 32768 + 32768;

    split_x_k<<<dim3(512), dim3(256), 0, stream>>>(x, ib, xhf);
    enc_tr<<<dim3(3072), dim3(256), 0, stream>>>(xhf, wenc, nb, preact, wdec, wdt);
    selresdec<<<dim3(512), dim3(1024), 0, stream>>>(
        preact, steps, x, ib, wenc, nb, wdt,
        out_tidx, out_tval, out_aidx, out_aval,
        out_recon, out_multik, out_mat0, out_mat1);
}